// Round 11
// baseline (291.482 us; speedup 1.0000x reference)
//
#include <hip/hip_runtime.h>

// GCN 2-layer, round 11: fused AGG1+GEMM2 with minimal-work wave-local epilogue.
// r10 lesson: 64-iter readlane epilogue (~1100cyc/node, 64-deep FMA chain) +
// barrier AFTER gather halved effective gather BW (1.56TB/s). Fix:
//  - barrier moved to right after W2 staging (no post-gather sync at all);
//  - epilogue uses butterfly redundancy: lane (slot,fl) computes partials of
//    its OWN 8 features x 4 outputs (32 ds_read + 32 fma, 4 indep chains),
//    3x shfl_xor reduce over fl, fl==0 lanes store 4 bf16 (64B/wave);
//  - W2s[64][33] padding -> worst-case 2-way LDS conflict (free).
// Gather = r7's proven lean 2-deep, 1 node/wave, 25000 short blocks.
// CSR build unchanged (LDS-staged burst-flush scatter, zero global atomics).
// Transform-first identity: segsum(h[src]) @ W == segsum((h@W)[src]).

#define NN 100000
#define NE 3200000
#define NOUTF 30
#define TPB 256
#define TPBW 1024                          // hist blocks
#define TPBS 512                           // scatter blocks

// dst stream buckets
#define DSH 8
#define DCB 256
#define DNB ((NN + DCB - 1) / DCB)         // 391
// src stream buckets
#define SSH 10
#define SCB 1024
#define SNB ((NN + SCB - 1) / SCB)         // 98

#define CHUNK 8192
#define NBLK ((NE + CHUNK - 1) / CHUNK)    // 391
#define HLD (DNB * NBLK)                   // 152,881
#define HLS (SNB * NBLK)                   // 38,318
#define HLT (HLD + HLS)                    // 191,199
#define EPT (CHUNK / TPBS)                 // 16 edges per scatter thread

#define GCH 1024
#define NSC ((HLT + GCH - 1) / GCH)        // 187

#define POOL 9216                          // fine-sort staging (36KB LDS)

__device__ __forceinline__ unsigned short f2bf(float f) {  // round-nearest-even
  unsigned u = __float_as_uint(f);
  u = (u + 0x7FFFu + ((u >> 16) & 1u)) >> 16;
  return (unsigned short)u;
}

// accumulate 8 bf16 (one uint4) into 8 f32
__device__ __forceinline__ void acc8(float* a, const uint4& u) {
  a[0] += __uint_as_float(u.x << 16);
  a[1] += __uint_as_float(u.x & 0xFFFF0000u);
  a[2] += __uint_as_float(u.y << 16);
  a[3] += __uint_as_float(u.y & 0xFFFF0000u);
  a[4] += __uint_as_float(u.z << 16);
  a[5] += __uint_as_float(u.z & 0xFFFF0000u);
  a[6] += __uint_as_float(u.w << 16);
  a[7] += __uint_as_float(u.w & 0xFFFF0000u);
}

// bijective XCD swizzle (m204 variant): consecutive swizzled ids -> same XCD
__device__ __forceinline__ int xcd_swz(int orig, int n) {
  int q = n / 8, r = n % 8;
  int xcd = orig % 8, idx = orig / 8;
  return (xcd < r ? xcd * (q + 1) : r * (q + 1) + (xcd - r) * q) + idx;
}

// ------ A: dual coarse histogram (dst>>8 and src>>10, LDS only) -------------
__global__ __launch_bounds__(TPBW) void k_hist(const int* __restrict__ src,
                                               const int* __restrict__ dst,
                                               int* __restrict__ H) {
  __shared__ int hd[DNB], hs[SNB];
  int t = threadIdx.x, k = blockIdx.x;
  for (int b = t; b < DNB; b += TPBW) hd[b] = 0;
  for (int b = t; b < SNB; b += TPBW) hs[b] = 0;
  __syncthreads();
  int beg = k * CHUNK, end = min(NE, beg + CHUNK);
  for (int i = beg + t; i < end; i += TPBW) {
    atomicAdd(&hd[dst[i] >> DSH], 1);
    atomicAdd(&hs[src[i] >> SSH], 1);
  }
  __syncthreads();
  for (int b = t; b < DNB; b += TPBW) H[b * NBLK + k] = hd[b];
  for (int b = t; b < SNB; b += TPBW) H[HLD + b * NBLK + k] = hs[b];
}

// ------ B: 3-kernel exclusive scan over H[HLT] -------------------------------
__global__ __launch_bounds__(TPB) void g_scan1(const int* __restrict__ a,
                                               int* __restrict__ bsums) {
  int t = threadIdx.x;
  int base = blockIdx.x * GCH + t * 4;
  int s = 0;
#pragma unroll
  for (int j = 0; j < 4; ++j) { int idx = base + j; if (idx < HLT) s += a[idx]; }
  __shared__ int red[TPB];
  red[t] = s; __syncthreads();
  for (int off = TPB / 2; off > 0; off >>= 1) {
    if (t < off) red[t] += red[t + off];
    __syncthreads();
  }
  if (t == 0) bsums[blockIdx.x] = red[0];
}

__global__ __launch_bounds__(1024) void g_scan2(int* __restrict__ bsums) {
  int t = threadIdx.x;
  __shared__ int lds[1024];
  int v = (t < NSC) ? bsums[t] : 0;
  int acc = v; lds[t] = acc; __syncthreads();
  for (int off = 1; off < 1024; off <<= 1) {
    int add = (t >= off) ? lds[t - off] : 0; __syncthreads();
    acc += add; lds[t] = acc; __syncthreads();
  }
  if (t < NSC) bsums[t] = acc - v;  // exclusive
}

__global__ __launch_bounds__(TPB) void g_scan3(int* __restrict__ a,
                                               const int* __restrict__ bsums) {
  int t = threadIdx.x;
  int base = blockIdx.x * GCH + t * 4;
  int v[4]; int s = 0;
#pragma unroll
  for (int j = 0; j < 4; ++j) {
    int idx = base + j;
    v[j] = (idx < HLT) ? a[idx] : 0;
    s += v[j];
  }
  __shared__ int lds[TPB];
  int acc = s; lds[t] = acc; __syncthreads();
  for (int off = 1; off < TPB; off <<= 1) {
    int add = (t >= off) ? lds[t - off] : 0; __syncthreads();
    acc += add; lds[t] = acc; __syncthreads();
  }
  int run = bsums[blockIdx.x] + (acc - s);
#pragma unroll
  for (int j = 0; j < 4; ++j) {
    int idx = base + j;
    if (idx < HLT) a[idx] = run;  // in-place exclusive
    run += v[j];
  }
}

// ------ C: LDS-staged dual scatter with contiguous burst flush --------------
__global__ __launch_bounds__(TPBS) void k_scatter(const int* __restrict__ src,
                                                  const int* __restrict__ dst,
                                                  const int* __restrict__ Hsc,
                                                  int* __restrict__ packed,
                                                  unsigned short* __restrict__ ss) {
  __shared__ int pack_lds[CHUNK];            // 32KB
  __shared__ unsigned short ss_lds[CHUNK];   // 16KB
  __shared__ int baseD[DNB + 1], curD[DNB];
  __shared__ int baseS[SNB + 1], curS[SNB];
  __shared__ int scanbuf[TPBS];
  int t = threadIdx.x;
  int k = xcd_swz((int)blockIdx.x, NBLK);    // adjacent chunks -> same XCD
  int beg = k * CHUNK, end = min(NE, beg + CHUNK);
  int cnt = end - beg;

  // register-stage this chunk's edges (coalesced reads, read once)
  int es[EPT], ed[EPT];
#pragma unroll
  for (int j = 0; j < EPT; ++j) {
    int i = beg + j * TPBS + t;
    if (i < end) { es[j] = src[i]; ed[j] = dst[i]; }
    else { es[j] = -1; ed[j] = -1; }
  }

  // block-local histograms (curD/curS double as hist accumulators)
  for (int b = t; b < DNB; b += TPBS) curD[b] = 0;
  for (int b = t; b < SNB; b += TPBS) curS[b] = 0;
  __syncthreads();
#pragma unroll
  for (int j = 0; j < EPT; ++j) {
    if (ed[j] >= 0) {
      atomicAdd(&curD[ed[j] >> DSH], 1);
      atomicAdd(&curS[es[j] >> SSH], 1);
    }
  }
  __syncthreads();

  // exclusive scan of curD -> baseD (DNB=391 <= TPBS)
  {
    int v = (t < DNB) ? curD[t] : 0;
    int acc = v; scanbuf[t] = acc; __syncthreads();
    for (int off = 1; off < TPBS; off <<= 1) {
      int add = (t >= off) ? scanbuf[t - off] : 0; __syncthreads();
      acc += add; scanbuf[t] = acc; __syncthreads();
    }
    if (t < DNB) baseD[t] = acc - v;
    if (t == 0) baseD[DNB] = cnt;
  }
  __syncthreads();
  // exclusive scan of curS -> baseS (SNB=98)
  {
    int v = (t < SNB) ? curS[t] : 0;
    int acc = v; scanbuf[t] = acc; __syncthreads();
    for (int off = 1; off < TPBS; off <<= 1) {
      int add = (t >= off) ? scanbuf[t - off] : 0; __syncthreads();
      acc += add; scanbuf[t] = acc; __syncthreads();
    }
    if (t < SNB) baseS[t] = acc - v;
    if (t == 0) baseS[SNB] = cnt;
  }
  __syncthreads();
  // cursors start at local bases
  for (int b = t; b < DNB; b += TPBS) curD[b] = baseD[b];
  for (int b = t; b < SNB; b += TPBS) curS[b] = baseS[b];
  __syncthreads();

  // LDS scatter: block-local bucket-sorted staging
#pragma unroll
  for (int j = 0; j < EPT; ++j) {
    if (ed[j] >= 0) {
      int p = atomicAdd(&curD[ed[j] >> DSH], 1);
      pack_lds[p] = (es[j] << DSH) | (ed[j] & (DCB - 1));
      int q = atomicAdd(&curS[es[j] >> SSH], 1);
      ss_lds[q] = (unsigned short)(es[j] & (SCB - 1));
    }
  }
  __syncthreads();

  // burst flush: element i -> bucket via binary search on baseD/baseS;
  // consecutive i within a bucket hit consecutive global addresses.
  for (int i = t; i < cnt; i += TPBS) {
    int lo = 0, hi = DNB;
    while (hi - lo > 1) { int mid = (lo + hi) >> 1; if (baseD[mid] <= i) lo = mid; else hi = mid; }
    packed[Hsc[lo * NBLK + k] + (i - baseD[lo])] = pack_lds[i];
  }
  for (int i = t; i < cnt; i += TPBS) {
    int lo = 0, hi = SNB;
    while (hi - lo > 1) { int mid = (lo + hi) >> 1; if (baseS[mid] <= i) lo = mid; else hi = mid; }
    ss[Hsc[HLD + lo * NBLK + k] + (i - baseS[lo]) - NE] = ss_lds[i];
  }
}

// ------ D: per-bucket fine counting sort (dst) -> src_sorted/row_ptr/norm_in
__global__ __launch_bounds__(TPB) void k_fine_sort(const int* __restrict__ Hsc,
                                                   const int* __restrict__ packed,
                                                   int* __restrict__ src_sorted,
                                                   int* __restrict__ row_ptr,
                                                   float* __restrict__ norm_in) {
  __shared__ int hist[DCB], scn[DCB], cur[DCB];
  __shared__ int pool[POOL];
  int t = threadIdx.x, b = blockIdx.x;
  int seg_beg = Hsc[b * NBLK];
  int seg_end = (b + 1 < DNB) ? Hsc[(b + 1) * NBLK] : NE;
  int cnt = seg_end - seg_beg;
  hist[t] = 0;
  __syncthreads();
  for (int i = seg_beg + t; i < seg_end; i += TPB)
    atomicAdd(&hist[packed[i] & (DCB - 1)], 1);
  __syncthreads();
  scn[t] = hist[t];
  __syncthreads();
  for (int off = 1; off < DCB; off <<= 1) {   // Hillis-Steele inclusive (256=TPB)
    int add = (t >= off) ? scn[t - off] : 0;
    __syncthreads();
    scn[t] += add;
    __syncthreads();
  }
  {
    int excl = scn[t] - hist[t];
    cur[t] = excl;
    int node = b * DCB + t;
    if (node < NN) {
      row_ptr[node] = seg_beg + excl;
      norm_in[node] = (hist[t] > 0) ? rsqrtf((float)hist[t]) : 0.0f;
    }
  }
  if (b == DNB - 1 && t == 0) row_ptr[NN] = NE;
  __syncthreads();
  for (int i = seg_beg + t; i < seg_end; i += TPB) {
    int v = packed[i];
    int p = atomicAdd(&cur[v & (DCB - 1)], 1);
    int sv = v >> DSH;
    if (p < POOL) pool[p] = sv;
    else src_sorted[seg_beg + p] = sv;                 // overflow fallback (rare)
  }
  __syncthreads();
  int lim = min(cnt, POOL);
  for (int i = t; i < lim; i += TPB) src_sorted[seg_beg + i] = pool[i];
}

// ------ E: per-bucket fine count (src, 1024 bins) -> norm_out ---------------
__global__ __launch_bounds__(TPB) void k_fine_count(const int* __restrict__ Hsc,
                                                    const unsigned short* __restrict__ ss,
                                                    float* __restrict__ norm_out) {
  __shared__ int hist[SCB];
  int t = threadIdx.x, b = blockIdx.x;
  int seg_beg = Hsc[HLD + b * NBLK] - NE;
  int seg_end = (b + 1 < SNB) ? Hsc[HLD + (b + 1) * NBLK] - NE : NE;
  for (int i = t; i < SCB; i += TPB) hist[i] = 0;
  __syncthreads();
  for (int i = seg_beg + t; i < seg_end; i += TPB)
    atomicAdd(&hist[ss[i]], 1);
  __syncthreads();
  for (int i = t; i < SCB; i += TPB) {
    int node = b * SCB + i;
    if (node < NN)
      norm_out[node] = (hist[i] > 0) ? rsqrtf((float)hist[i]) : 0.0f;
  }
}

// ------ GEMM1: xt_b[n] = bf16( norm_out[n] * (x[n] @ W1) )  [64 -> 64] ------
__global__ __launch_bounds__(TPB) void k_gemm1(const float4* __restrict__ x4,
                                               const float* __restrict__ W1,
                                               const float* __restrict__ norm_out,
                                               unsigned short* __restrict__ xt_b) {
  int lane = threadIdx.x & 63;
  int wid = (blockIdx.x * TPB + threadIdx.x) >> 6;
  int nwaves = gridDim.x * (TPB / 64);
  float w[64];
#pragma unroll
  for (int k = 0; k < 64; ++k) w[k] = W1[k * 64 + lane];
  int m = lane >> 4, q = lane & 15;
  for (int grp = wid; grp < NN / 4; grp += nwaves) {
    int nbase = grp * 4;
    float4 rv = x4[(nbase + m) * 16 + q];
    int r0 = __float_as_int(rv.x), r1 = __float_as_int(rv.y);
    int r2 = __float_as_int(rv.z), r3 = __float_as_int(rv.w);
    float acc[4] = {0.f, 0.f, 0.f, 0.f};
#pragma unroll
    for (int mm = 0; mm < 4; ++mm) {
#pragma unroll
      for (int ql = 0; ql < 16; ++ql) {
        int sl = mm * 16 + ql;
        acc[mm] = fmaf(__int_as_float(__builtin_amdgcn_readlane(r0, sl)), w[ql * 4 + 0], acc[mm]);
        acc[mm] = fmaf(__int_as_float(__builtin_amdgcn_readlane(r1, sl)), w[ql * 4 + 1], acc[mm]);
        acc[mm] = fmaf(__int_as_float(__builtin_amdgcn_readlane(r2, sl)), w[ql * 4 + 2], acc[mm]);
        acc[mm] = fmaf(__int_as_float(__builtin_amdgcn_readlane(r3, sl)), w[ql * 4 + 3], acc[mm]);
      }
    }
#pragma unroll
    for (int mm = 0; mm < 4; ++mm) {
      int n = nbase + mm;
      xt_b[n * 64 + lane] = f2bf(norm_out[n] * acc[mm]);  // 128B/row coalesced
    }
  }
}

// -- AGG1+GEMM2 fused: 1 node/wave, 25000 short blocks, lean 2-deep gather,
// minimal-work wave-local epilogue (no barrier after staging). --------------
__global__ __launch_bounds__(TPB) void k_agg1f(const uint4* __restrict__ xt4,
                                               const int* __restrict__ src_sorted,
                                               const int* __restrict__ row_ptr,
                                               const float* __restrict__ norm_in,
                                               const float* __restrict__ norm_out,
                                               const float* __restrict__ b1,
                                               const float* __restrict__ W2,
                                               unsigned short* __restrict__ h1t_b) {
  __shared__ float W2s[64][33];                // padded: worst 2-way (free)
  int t = threadIdx.x;
  for (int i = t; i < 64 * 32; i += TPB) {     // col 32 is never-read pad
    int r = i >> 5, c = i & 31;
    W2s[r][c] = (c < NOUTF) ? W2[r * NOUTF + c] : 0.f;
  }
  __syncthreads();                             // ONLY barrier: before gather

  int lane = t & 63;
  int slot = lane >> 3;         // 0..7 (edge slot; later: output group)
  int fl = lane & 7;            // uint4 index within 128B row
  int node = blockIdx.x * 4 + (t >> 6);
  int beg = row_ptr[node];
  int end = row_ptr[node + 1];

  // per-lane bias slice for features fl*8 .. fl*8+7
  const float4* b1_4 = reinterpret_cast<const float4*>(b1);
  float4 bl = b1_4[fl * 2];
  float4 bh = b1_4[fl * 2 + 1];
  float b1r[8] = {bl.x, bl.y, bl.z, bl.w, bh.x, bh.y, bh.z, bh.w};

  float a[8] = {0.f, 0.f, 0.f, 0.f, 0.f, 0.f, 0.f, 0.f};
  int e = beg + slot;
  for (; e + 8 < end; e += 16) {               // lean 2-deep (r7-proven)
    int s0 = src_sorted[e];
    int s1 = src_sorted[e + 8];
    uint4 u0 = xt4[s0 * 8 + fl];
    uint4 u1 = xt4[s1 * 8 + fl];
    acc8(a, u0);
    acc8(a, u1);
  }
  if (e < end) {
    uint4 u0 = xt4[src_sorted[e] * 8 + fl];
    acc8(a, u0);
  }
#pragma unroll
  for (int off = 8; off <= 32; off <<= 1) {    // all fl-equal lanes now hold
#pragma unroll
    for (int j = 0; j < 8; ++j) a[j] += __shfl_xor(a[j], off);
  }                                            // identical full fl-group sums
  float ni = norm_in[node];
  float no = norm_out[node];
#pragma unroll
  for (int j = 0; j < 8; ++j)                  // bias + relu in-lane
    a[j] = fmaxf(fmaf(a[j], ni, b1r[j]), 0.f);

  // h1 @ W2 partials: lane (slot,fl) covers its OWN features fl*8..fl*8+7
  // for output cols ocg..ocg+3. 4 independent FMA chains, 32 LDS reads.
  int ocg = slot * 4;
  float p0 = 0.f, p1 = 0.f, p2 = 0.f, p3 = 0.f;
#pragma unroll
  for (int j = 0; j < 8; ++j) {
    int f = fl * 8 + j;
    p0 = fmaf(a[j], W2s[f][ocg],     p0);
    p1 = fmaf(a[j], W2s[f][ocg + 1], p1);
    p2 = fmaf(a[j], W2s[f][ocg + 2], p2);
    p3 = fmaf(a[j], W2s[f][ocg + 3], p3);
  }
#pragma unroll
  for (int off = 1; off <= 4; off <<= 1) {     // reduce over fl (low 3 bits)
    p0 += __shfl_xor(p0, off);
    p1 += __shfl_xor(p1, off);
    p2 += __shfl_xor(p2, off);
    p3 += __shfl_xor(p3, off);
  }
  if (fl == 0) {                               // 8 lanes store 8B each: 64B/wave
    uint2 v;
    v.x = (unsigned)f2bf(no * p0) | ((unsigned)f2bf(no * p1) << 16);
    v.y = (unsigned)f2bf(no * p2) | ((unsigned)f2bf(no * p3) << 16);
    reinterpret_cast<uint2*>(h1t_b)[node * 8 + slot] = v;
  }
}

// -- AGG2: out[n] = norm_in[n]*segsum(h1t_b[src]) + b2; bf16 in, f32 out -----
__global__ __launch_bounds__(TPB) void k_agg2(const uint4* __restrict__ h1t4,
                                              const int* __restrict__ src_sorted,
                                              const int* __restrict__ row_ptr,
                                              const float* __restrict__ norm_in,
                                              const float* __restrict__ b2,
                                              float* __restrict__ out) {
  int node = (blockIdx.x * TPB + threadIdx.x) >> 6;
  int lane = threadIdx.x & 63;
  int slot = lane >> 2;  // 0..15
  int fl = lane & 3;     // uint4 index within 64B row
  int beg = row_ptr[node];
  int end = row_ptr[node + 1];
  float a[8] = {0.f, 0.f, 0.f, 0.f, 0.f, 0.f, 0.f, 0.f};
  int e = beg + slot;
  for (; e + 16 < end; e += 32) {
    int s0 = src_sorted[e];
    int s1 = src_sorted[e + 16];
    uint4 u0 = h1t4[s0 * 4 + fl];
    uint4 u1 = h1t4[s1 * 4 + fl];
    acc8(a, u0);
    acc8(a, u1);
  }
  if (e < end) {
    uint4 u0 = h1t4[src_sorted[e] * 4 + fl];
    acc8(a, u0);
  }
#pragma unroll
  for (int off = 4; off <= 32; off <<= 1) {
#pragma unroll
    for (int j = 0; j < 8; ++j) a[j] += __shfl_xor(a[j], off);
  }
  if (slot == 0) {
    float ni = norm_in[node];
    int f0 = fl * 8;
    float2* ob = (float2*)(out + (size_t)node * NOUTF);  // rows 120B, 8B-aligned
#pragma unroll
    for (int p = 0; p < 4; ++p) {
      int f = f0 + p * 2;
      if (f < NOUTF) {
        float2 v;
        v.x = fmaf(a[p * 2], ni, b2[f]);
        v.y = fmaf(a[p * 2 + 1], ni, b2[f + 1]);
        ob[f >> 1] = v;
      }
    }
  }
}

extern "C" void kernel_launch(void* const* d_in, const int* in_sizes, int n_in,
                              void* d_out, int out_size, void* d_ws, size_t ws_size,
                              hipStream_t stream) {
  (void)in_sizes; (void)n_in; (void)out_size; (void)ws_size;
  const float* x = (const float*)d_in[0];
  const int* src = (const int*)d_in[1];
  const int* dst = (const int*)d_in[2];
  const float* W1 = (const float*)d_in[3];
  const float* b1 = (const float*)d_in[4];
  const float* W2 = (const float*)d_in[5];
  const float* b2 = (const float*)d_in[6];
  float* out = (float*)d_out;

  // Workspace layout (bytes); offsets 16B-aligned.
  // packed (12.8MB) dead after k_fine_sort -> h1t_b (6.4MB bf16) aliases it
  // (h1t_b must NOT alias xt_b: k_agg1f reads xt_b while writing h1t_b).
  char* ws = (char*)d_ws;
  int* row_ptr = (int*)(ws + 0);                           //    400,128
  float* norm_out = (float*)(ws + 400128);                 //    400,000
  float* norm_in = (float*)(ws + 800128);                  //    400,000
  int* H = (int*)(ws + 1200128);                           //    764,800 (HLT ints pad)
  int* bsums = (int*)(ws + 1964928);                       //        768 (NSC ints pad)
  unsigned short* ss = (unsigned short*)(ws + 1965696);    //  6,400,000
  int* src_sorted = (int*)(ws + 8365696);                  // 12,800,000
  int* packed = (int*)(ws + 21165696);                     // 12,800,000
  unsigned short* h1t_b = (unsigned short*)(ws + 21165696);// 6,400,000 (aliases packed)
  unsigned short* xt_b = (unsigned short*)(ws + 46765696); // 12,800,000

  k_hist<<<NBLK, TPBW, 0, stream>>>(src, dst, H);
  g_scan1<<<NSC, TPB, 0, stream>>>(H, bsums);
  g_scan2<<<1, 1024, 0, stream>>>(bsums);
  g_scan3<<<NSC, TPB, 0, stream>>>(H, bsums);
  k_scatter<<<NBLK, TPBS, 0, stream>>>(src, dst, H, packed, ss);
  k_fine_sort<<<DNB, TPB, 0, stream>>>(H, packed, src_sorted, row_ptr, norm_in);
  k_fine_count<<<SNB, TPB, 0, stream>>>(H, ss, norm_out);
  k_gemm1<<<1024, TPB, 0, stream>>>((const float4*)x, W1, norm_out, xt_b);
  k_agg1f<<<NN / 4, TPB, 0, stream>>>((const uint4*)xt_b, src_sorted, row_ptr,
                                      norm_in, norm_out, b1, W2, h1t_b);
  k_agg2<<<NN / 4, TPB, 0, stream>>>((const uint4*)h1t_b, src_sorted, row_ptr, norm_in, b2, out);
}

// Round 12
// 280.599 us; speedup vs baseline: 1.0388x; 1.0388x over previous
//
#include <hip/hip_runtime.h>

// GCN 2-layer, round 12: r11 + correct XOR bank swizzle on W2s (T2).
// r11 lesson: W2s[64][33] "padding" gave bank = (8fl+4slot+j) mod 32 -> only
// 8 banks -> 8-way conflict on all 32 epilogue reads (12M conflict cycles,
// LDS pipe saturated per-CU, gather starved to 1.4TB/s). Fix: store logical
// W2s[f][oc] at physical col oc ^ (f>>3), stride 32. Read bank
// ((4slot+c)^fl) mod 32 covers all 32 banks 2x per (j,c) -> free (m136).
// Everything else identical to r11: lean 2-deep gather, 1 node/wave, 25000
// short blocks, barrier only between staging and gather, minimal epilogue
// (32 fma / 4 chains, 3 shfl_xor rounds, fl==0 stores 8B).
// CSR build unchanged (LDS-staged burst-flush scatter, zero global atomics).
// Transform-first identity: segsum(h[src]) @ W == segsum((h@W)[src]).

#define NN 100000
#define NE 3200000
#define NOUTF 30
#define TPB 256
#define TPBW 1024                          // hist blocks
#define TPBS 512                           // scatter blocks

// dst stream buckets
#define DSH 8
#define DCB 256
#define DNB ((NN + DCB - 1) / DCB)         // 391
// src stream buckets
#define SSH 10
#define SCB 1024
#define SNB ((NN + SCB - 1) / SCB)         // 98

#define CHUNK 8192
#define NBLK ((NE + CHUNK - 1) / CHUNK)    // 391
#define HLD (DNB * NBLK)                   // 152,881
#define HLS (SNB * NBLK)                   // 38,318
#define HLT (HLD + HLS)                    // 191,199
#define EPT (CHUNK / TPBS)                 // 16 edges per scatter thread

#define GCH 1024
#define NSC ((HLT + GCH - 1) / GCH)        // 187

#define POOL 9216                          // fine-sort staging (36KB LDS)

__device__ __forceinline__ unsigned short f2bf(float f) {  // round-nearest-even
  unsigned u = __float_as_uint(f);
  u = (u + 0x7FFFu + ((u >> 16) & 1u)) >> 16;
  return (unsigned short)u;
}

// accumulate 8 bf16 (one uint4) into 8 f32
__device__ __forceinline__ void acc8(float* a, const uint4& u) {
  a[0] += __uint_as_float(u.x << 16);
  a[1] += __uint_as_float(u.x & 0xFFFF0000u);
  a[2] += __uint_as_float(u.y << 16);
  a[3] += __uint_as_float(u.y & 0xFFFF0000u);
  a[4] += __uint_as_float(u.z << 16);
  a[5] += __uint_as_float(u.z & 0xFFFF0000u);
  a[6] += __uint_as_float(u.w << 16);
  a[7] += __uint_as_float(u.w & 0xFFFF0000u);
}

// bijective XCD swizzle (m204 variant): consecutive swizzled ids -> same XCD
__device__ __forceinline__ int xcd_swz(int orig, int n) {
  int q = n / 8, r = n % 8;
  int xcd = orig % 8, idx = orig / 8;
  return (xcd < r ? xcd * (q + 1) : r * (q + 1) + (xcd - r) * q) + idx;
}

// ------ A: dual coarse histogram (dst>>8 and src>>10, LDS only) -------------
__global__ __launch_bounds__(TPBW) void k_hist(const int* __restrict__ src,
                                               const int* __restrict__ dst,
                                               int* __restrict__ H) {
  __shared__ int hd[DNB], hs[SNB];
  int t = threadIdx.x, k = blockIdx.x;
  for (int b = t; b < DNB; b += TPBW) hd[b] = 0;
  for (int b = t; b < SNB; b += TPBW) hs[b] = 0;
  __syncthreads();
  int beg = k * CHUNK, end = min(NE, beg + CHUNK);
  for (int i = beg + t; i < end; i += TPBW) {
    atomicAdd(&hd[dst[i] >> DSH], 1);
    atomicAdd(&hs[src[i] >> SSH], 1);
  }
  __syncthreads();
  for (int b = t; b < DNB; b += TPBW) H[b * NBLK + k] = hd[b];
  for (int b = t; b < SNB; b += TPBW) H[HLD + b * NBLK + k] = hs[b];
}

// ------ B: 3-kernel exclusive scan over H[HLT] -------------------------------
__global__ __launch_bounds__(TPB) void g_scan1(const int* __restrict__ a,
                                               int* __restrict__ bsums) {
  int t = threadIdx.x;
  int base = blockIdx.x * GCH + t * 4;
  int s = 0;
#pragma unroll
  for (int j = 0; j < 4; ++j) { int idx = base + j; if (idx < HLT) s += a[idx]; }
  __shared__ int red[TPB];
  red[t] = s; __syncthreads();
  for (int off = TPB / 2; off > 0; off >>= 1) {
    if (t < off) red[t] += red[t + off];
    __syncthreads();
  }
  if (t == 0) bsums[blockIdx.x] = red[0];
}

__global__ __launch_bounds__(1024) void g_scan2(int* __restrict__ bsums) {
  int t = threadIdx.x;
  __shared__ int lds[1024];
  int v = (t < NSC) ? bsums[t] : 0;
  int acc = v; lds[t] = acc; __syncthreads();
  for (int off = 1; off < 1024; off <<= 1) {
    int add = (t >= off) ? lds[t - off] : 0; __syncthreads();
    acc += add; lds[t] = acc; __syncthreads();
  }
  if (t < NSC) bsums[t] = acc - v;  // exclusive
}

__global__ __launch_bounds__(TPB) void g_scan3(int* __restrict__ a,
                                               const int* __restrict__ bsums) {
  int t = threadIdx.x;
  int base = blockIdx.x * GCH + t * 4;
  int v[4]; int s = 0;
#pragma unroll
  for (int j = 0; j < 4; ++j) {
    int idx = base + j;
    v[j] = (idx < HLT) ? a[idx] : 0;
    s += v[j];
  }
  __shared__ int lds[TPB];
  int acc = s; lds[t] = acc; __syncthreads();
  for (int off = 1; off < TPB; off <<= 1) {
    int add = (t >= off) ? lds[t - off] : 0; __syncthreads();
    acc += add; lds[t] = acc; __syncthreads();
  }
  int run = bsums[blockIdx.x] + (acc - s);
#pragma unroll
  for (int j = 0; j < 4; ++j) {
    int idx = base + j;
    if (idx < HLT) a[idx] = run;  // in-place exclusive
    run += v[j];
  }
}

// ------ C: LDS-staged dual scatter with contiguous burst flush --------------
__global__ __launch_bounds__(TPBS) void k_scatter(const int* __restrict__ src,
                                                  const int* __restrict__ dst,
                                                  const int* __restrict__ Hsc,
                                                  int* __restrict__ packed,
                                                  unsigned short* __restrict__ ss) {
  __shared__ int pack_lds[CHUNK];            // 32KB
  __shared__ unsigned short ss_lds[CHUNK];   // 16KB
  __shared__ int baseD[DNB + 1], curD[DNB];
  __shared__ int baseS[SNB + 1], curS[SNB];
  __shared__ int scanbuf[TPBS];
  int t = threadIdx.x;
  int k = xcd_swz((int)blockIdx.x, NBLK);    // adjacent chunks -> same XCD
  int beg = k * CHUNK, end = min(NE, beg + CHUNK);
  int cnt = end - beg;

  // register-stage this chunk's edges (coalesced reads, read once)
  int es[EPT], ed[EPT];
#pragma unroll
  for (int j = 0; j < EPT; ++j) {
    int i = beg + j * TPBS + t;
    if (i < end) { es[j] = src[i]; ed[j] = dst[i]; }
    else { es[j] = -1; ed[j] = -1; }
  }

  // block-local histograms (curD/curS double as hist accumulators)
  for (int b = t; b < DNB; b += TPBS) curD[b] = 0;
  for (int b = t; b < SNB; b += TPBS) curS[b] = 0;
  __syncthreads();
#pragma unroll
  for (int j = 0; j < EPT; ++j) {
    if (ed[j] >= 0) {
      atomicAdd(&curD[ed[j] >> DSH], 1);
      atomicAdd(&curS[es[j] >> SSH], 1);
    }
  }
  __syncthreads();

  // exclusive scan of curD -> baseD (DNB=391 <= TPBS)
  {
    int v = (t < DNB) ? curD[t] : 0;
    int acc = v; scanbuf[t] = acc; __syncthreads();
    for (int off = 1; off < TPBS; off <<= 1) {
      int add = (t >= off) ? scanbuf[t - off] : 0; __syncthreads();
      acc += add; scanbuf[t] = acc; __syncthreads();
    }
    if (t < DNB) baseD[t] = acc - v;
    if (t == 0) baseD[DNB] = cnt;
  }
  __syncthreads();
  // exclusive scan of curS -> baseS (SNB=98)
  {
    int v = (t < SNB) ? curS[t] : 0;
    int acc = v; scanbuf[t] = acc; __syncthreads();
    for (int off = 1; off < TPBS; off <<= 1) {
      int add = (t >= off) ? scanbuf[t - off] : 0; __syncthreads();
      acc += add; scanbuf[t] = acc; __syncthreads();
    }
    if (t < SNB) baseS[t] = acc - v;
    if (t == 0) baseS[SNB] = cnt;
  }
  __syncthreads();
  // cursors start at local bases
  for (int b = t; b < DNB; b += TPBS) curD[b] = baseD[b];
  for (int b = t; b < SNB; b += TPBS) curS[b] = baseS[b];
  __syncthreads();

  // LDS scatter: block-local bucket-sorted staging
#pragma unroll
  for (int j = 0; j < EPT; ++j) {
    if (ed[j] >= 0) {
      int p = atomicAdd(&curD[ed[j] >> DSH], 1);
      pack_lds[p] = (es[j] << DSH) | (ed[j] & (DCB - 1));
      int q = atomicAdd(&curS[es[j] >> SSH], 1);
      ss_lds[q] = (unsigned short)(es[j] & (SCB - 1));
    }
  }
  __syncthreads();

  // burst flush: element i -> bucket via binary search on baseD/baseS;
  // consecutive i within a bucket hit consecutive global addresses.
  for (int i = t; i < cnt; i += TPBS) {
    int lo = 0, hi = DNB;
    while (hi - lo > 1) { int mid = (lo + hi) >> 1; if (baseD[mid] <= i) lo = mid; else hi = mid; }
    packed[Hsc[lo * NBLK + k] + (i - baseD[lo])] = pack_lds[i];
  }
  for (int i = t; i < cnt; i += TPBS) {
    int lo = 0, hi = SNB;
    while (hi - lo > 1) { int mid = (lo + hi) >> 1; if (baseS[mid] <= i) lo = mid; else hi = mid; }
    ss[Hsc[HLD + lo * NBLK + k] + (i - baseS[lo]) - NE] = ss_lds[i];
  }
}

// ------ D: per-bucket fine counting sort (dst) -> src_sorted/row_ptr/norm_in
__global__ __launch_bounds__(TPB) void k_fine_sort(const int* __restrict__ Hsc,
                                                   const int* __restrict__ packed,
                                                   int* __restrict__ src_sorted,
                                                   int* __restrict__ row_ptr,
                                                   float* __restrict__ norm_in) {
  __shared__ int hist[DCB], scn[DCB], cur[DCB];
  __shared__ int pool[POOL];
  int t = threadIdx.x, b = blockIdx.x;
  int seg_beg = Hsc[b * NBLK];
  int seg_end = (b + 1 < DNB) ? Hsc[(b + 1) * NBLK] : NE;
  int cnt = seg_end - seg_beg;
  hist[t] = 0;
  __syncthreads();
  for (int i = seg_beg + t; i < seg_end; i += TPB)
    atomicAdd(&hist[packed[i] & (DCB - 1)], 1);
  __syncthreads();
  scn[t] = hist[t];
  __syncthreads();
  for (int off = 1; off < DCB; off <<= 1) {   // Hillis-Steele inclusive (256=TPB)
    int add = (t >= off) ? scn[t - off] : 0;
    __syncthreads();
    scn[t] += add;
    __syncthreads();
  }
  {
    int excl = scn[t] - hist[t];
    cur[t] = excl;
    int node = b * DCB + t;
    if (node < NN) {
      row_ptr[node] = seg_beg + excl;
      norm_in[node] = (hist[t] > 0) ? rsqrtf((float)hist[t]) : 0.0f;
    }
  }
  if (b == DNB - 1 && t == 0) row_ptr[NN] = NE;
  __syncthreads();
  for (int i = seg_beg + t; i < seg_end; i += TPB) {
    int v = packed[i];
    int p = atomicAdd(&cur[v & (DCB - 1)], 1);
    int sv = v >> DSH;
    if (p < POOL) pool[p] = sv;
    else src_sorted[seg_beg + p] = sv;                 // overflow fallback (rare)
  }
  __syncthreads();
  int lim = min(cnt, POOL);
  for (int i = t; i < lim; i += TPB) src_sorted[seg_beg + i] = pool[i];
}

// ------ E: per-bucket fine count (src, 1024 bins) -> norm_out ---------------
__global__ __launch_bounds__(TPB) void k_fine_count(const int* __restrict__ Hsc,
                                                    const unsigned short* __restrict__ ss,
                                                    float* __restrict__ norm_out) {
  __shared__ int hist[SCB];
  int t = threadIdx.x, b = blockIdx.x;
  int seg_beg = Hsc[HLD + b * NBLK] - NE;
  int seg_end = (b + 1 < SNB) ? Hsc[HLD + (b + 1) * NBLK] - NE : NE;
  for (int i = t; i < SCB; i += TPB) hist[i] = 0;
  __syncthreads();
  for (int i = seg_beg + t; i < seg_end; i += TPB)
    atomicAdd(&hist[ss[i]], 1);
  __syncthreads();
  for (int i = t; i < SCB; i += TPB) {
    int node = b * SCB + i;
    if (node < NN)
      norm_out[node] = (hist[i] > 0) ? rsqrtf((float)hist[i]) : 0.0f;
  }
}

// ------ GEMM1: xt_b[n] = bf16( norm_out[n] * (x[n] @ W1) )  [64 -> 64] ------
__global__ __launch_bounds__(TPB) void k_gemm1(const float4* __restrict__ x4,
                                               const float* __restrict__ W1,
                                               const float* __restrict__ norm_out,
                                               unsigned short* __restrict__ xt_b) {
  int lane = threadIdx.x & 63;
  int wid = (blockIdx.x * TPB + threadIdx.x) >> 6;
  int nwaves = gridDim.x * (TPB / 64);
  float w[64];
#pragma unroll
  for (int k = 0; k < 64; ++k) w[k] = W1[k * 64 + lane];
  int m = lane >> 4, q = lane & 15;
  for (int grp = wid; grp < NN / 4; grp += nwaves) {
    int nbase = grp * 4;
    float4 rv = x4[(nbase + m) * 16 + q];
    int r0 = __float_as_int(rv.x), r1 = __float_as_int(rv.y);
    int r2 = __float_as_int(rv.z), r3 = __float_as_int(rv.w);
    float acc[4] = {0.f, 0.f, 0.f, 0.f};
#pragma unroll
    for (int mm = 0; mm < 4; ++mm) {
#pragma unroll
      for (int ql = 0; ql < 16; ++ql) {
        int sl = mm * 16 + ql;
        acc[mm] = fmaf(__int_as_float(__builtin_amdgcn_readlane(r0, sl)), w[ql * 4 + 0], acc[mm]);
        acc[mm] = fmaf(__int_as_float(__builtin_amdgcn_readlane(r1, sl)), w[ql * 4 + 1], acc[mm]);
        acc[mm] = fmaf(__int_as_float(__builtin_amdgcn_readlane(r2, sl)), w[ql * 4 + 2], acc[mm]);
        acc[mm] = fmaf(__int_as_float(__builtin_amdgcn_readlane(r3, sl)), w[ql * 4 + 3], acc[mm]);
      }
    }
#pragma unroll
    for (int mm = 0; mm < 4; ++mm) {
      int n = nbase + mm;
      xt_b[n * 64 + lane] = f2bf(norm_out[n] * acc[mm]);  // 128B/row coalesced
    }
  }
}

// -- AGG1+GEMM2 fused: 1 node/wave, 25000 short blocks, lean 2-deep gather,
// minimal epilogue with XOR-swizzled W2s (2-way banks = free). --------------
__global__ __launch_bounds__(TPB) void k_agg1f(const uint4* __restrict__ xt4,
                                               const int* __restrict__ src_sorted,
                                               const int* __restrict__ row_ptr,
                                               const float* __restrict__ norm_in,
                                               const float* __restrict__ norm_out,
                                               const float* __restrict__ b1,
                                               const float* __restrict__ W2,
                                               unsigned short* __restrict__ h1t_b) {
  __shared__ float W2s[64][32];                // logical [f][oc] at col oc^(f>>3)
  int t = threadIdx.x;
  for (int i = t; i < 64 * 32; i += TPB) {
    int r = i >> 5, c = i & 31;                // c = logical column
    W2s[r][c ^ (r >> 3)] = (c < NOUTF) ? W2[r * NOUTF + c] : 0.f;
  }
  __syncthreads();                             // ONLY barrier: before gather

  int lane = t & 63;
  int slot = lane >> 3;         // 0..7 (edge slot; later: output group)
  int fl = lane & 7;            // uint4 index within 128B row
  int node = blockIdx.x * 4 + (t >> 6);
  int beg = row_ptr[node];
  int end = row_ptr[node + 1];

  // per-lane bias slice for features fl*8 .. fl*8+7
  const float4* b1_4 = reinterpret_cast<const float4*>(b1);
  float4 bl = b1_4[fl * 2];
  float4 bh = b1_4[fl * 2 + 1];
  float b1r[8] = {bl.x, bl.y, bl.z, bl.w, bh.x, bh.y, bh.z, bh.w};

  float a[8] = {0.f, 0.f, 0.f, 0.f, 0.f, 0.f, 0.f, 0.f};
  int e = beg + slot;
  for (; e + 8 < end; e += 16) {               // lean 2-deep (r7-proven)
    int s0 = src_sorted[e];
    int s1 = src_sorted[e + 8];
    uint4 u0 = xt4[s0 * 8 + fl];
    uint4 u1 = xt4[s1 * 8 + fl];
    acc8(a, u0);
    acc8(a, u1);
  }
  if (e < end) {
    uint4 u0 = xt4[src_sorted[e] * 8 + fl];
    acc8(a, u0);
  }
#pragma unroll
  for (int off = 8; off <= 32; off <<= 1) {    // all fl-equal lanes now hold
#pragma unroll
    for (int j = 0; j < 8; ++j) a[j] += __shfl_xor(a[j], off);
  }                                            // identical full fl-group sums
  float ni = norm_in[node];
  float no = norm_out[node];
#pragma unroll
  for (int j = 0; j < 8; ++j)                  // bias + relu in-lane
    a[j] = fmaxf(fmaf(a[j], ni, b1r[j]), 0.f);

  // h1 @ W2 partials: lane (slot,fl) covers its OWN features fl*8..fl*8+7
  // for output cols ocg..ocg+3 (physical cols XOR fl -> 2-way banks, free).
  int ocg = slot * 4;
  int c0 = (ocg + 0) ^ fl, c1 = (ocg + 1) ^ fl;
  int c2 = (ocg + 2) ^ fl, c3 = (ocg + 3) ^ fl;
  float p0 = 0.f, p1 = 0.f, p2 = 0.f, p3 = 0.f;
#pragma unroll
  for (int j = 0; j < 8; ++j) {
    int f = fl * 8 + j;
    p0 = fmaf(a[j], W2s[f][c0], p0);
    p1 = fmaf(a[j], W2s[f][c1], p1);
    p2 = fmaf(a[j], W2s[f][c2], p2);
    p3 = fmaf(a[j], W2s[f][c3], p3);
  }
#pragma unroll
  for (int off = 1; off <= 4; off <<= 1) {     // reduce over fl (low 3 bits)
    p0 += __shfl_xor(p0, off);
    p1 += __shfl_xor(p1, off);
    p2 += __shfl_xor(p2, off);
    p3 += __shfl_xor(p3, off);
  }
  if (fl == 0) {                               // 8 lanes store 8B each: 64B/wave
    uint2 v;
    v.x = (unsigned)f2bf(no * p0) | ((unsigned)f2bf(no * p1) << 16);
    v.y = (unsigned)f2bf(no * p2) | ((unsigned)f2bf(no * p3) << 16);
    reinterpret_cast<uint2*>(h1t_b)[node * 8 + slot] = v;
  }
}

// -- AGG2: out[n] = norm_in[n]*segsum(h1t_b[src]) + b2; bf16 in, f32 out -----
__global__ __launch_bounds__(TPB) void k_agg2(const uint4* __restrict__ h1t4,
                                              const int* __restrict__ src_sorted,
                                              const int* __restrict__ row_ptr,
                                              const float* __restrict__ norm_in,
                                              const float* __restrict__ b2,
                                              float* __restrict__ out) {
  int node = (blockIdx.x * TPB + threadIdx.x) >> 6;
  int lane = threadIdx.x & 63;
  int slot = lane >> 2;  // 0..15
  int fl = lane & 3;     // uint4 index within 64B row
  int beg = row_ptr[node];
  int end = row_ptr[node + 1];
  float a[8] = {0.f, 0.f, 0.f, 0.f, 0.f, 0.f, 0.f, 0.f};
  int e = beg + slot;
  for (; e + 16 < end; e += 32) {
    int s0 = src_sorted[e];
    int s1 = src_sorted[e + 16];
    uint4 u0 = h1t4[s0 * 4 + fl];
    uint4 u1 = h1t4[s1 * 4 + fl];
    acc8(a, u0);
    acc8(a, u1);
  }
  if (e < end) {
    uint4 u0 = h1t4[src_sorted[e] * 4 + fl];
    acc8(a, u0);
  }
#pragma unroll
  for (int off = 4; off <= 32; off <<= 1) {
#pragma unroll
    for (int j = 0; j < 8; ++j) a[j] += __shfl_xor(a[j], off);
  }
  if (slot == 0) {
    float ni = norm_in[node];
    int f0 = fl * 8;
    float2* ob = (float2*)(out + (size_t)node * NOUTF);  // rows 120B, 8B-aligned
#pragma unroll
    for (int p = 0; p < 4; ++p) {
      int f = f0 + p * 2;
      if (f < NOUTF) {
        float2 v;
        v.x = fmaf(a[p * 2], ni, b2[f]);
        v.y = fmaf(a[p * 2 + 1], ni, b2[f + 1]);
        ob[f >> 1] = v;
      }
    }
  }
}

extern "C" void kernel_launch(void* const* d_in, const int* in_sizes, int n_in,
                              void* d_out, int out_size, void* d_ws, size_t ws_size,
                              hipStream_t stream) {
  (void)in_sizes; (void)n_in; (void)out_size; (void)ws_size;
  const float* x = (const float*)d_in[0];
  const int* src = (const int*)d_in[1];
  const int* dst = (const int*)d_in[2];
  const float* W1 = (const float*)d_in[3];
  const float* b1 = (const float*)d_in[4];
  const float* W2 = (const float*)d_in[5];
  const float* b2 = (const float*)d_in[6];
  float* out = (float*)d_out;

  // Workspace layout (bytes); offsets 16B-aligned.
  // packed (12.8MB) dead after k_fine_sort -> h1t_b (6.4MB bf16) aliases it
  // (h1t_b must NOT alias xt_b: k_agg1f reads xt_b while writing h1t_b).
  char* ws = (char*)d_ws;
  int* row_ptr = (int*)(ws + 0);                           //    400,128
  float* norm_out = (float*)(ws + 400128);                 //    400,000
  float* norm_in = (float*)(ws + 800128);                  //    400,000
  int* H = (int*)(ws + 1200128);                           //    764,800 (HLT ints pad)
  int* bsums = (int*)(ws + 1964928);                       //        768 (NSC ints pad)
  unsigned short* ss = (unsigned short*)(ws + 1965696);    //  6,400,000
  int* src_sorted = (int*)(ws + 8365696);                  // 12,800,000
  int* packed = (int*)(ws + 21165696);                     // 12,800,000
  unsigned short* h1t_b = (unsigned short*)(ws + 21165696);// 6,400,000 (aliases packed)
  unsigned short* xt_b = (unsigned short*)(ws + 46765696); // 12,800,000

  k_hist<<<NBLK, TPBW, 0, stream>>>(src, dst, H);
  g_scan1<<<NSC, TPB, 0, stream>>>(H, bsums);
  g_scan2<<<1, 1024, 0, stream>>>(bsums);
  g_scan3<<<NSC, TPB, 0, stream>>>(H, bsums);
  k_scatter<<<NBLK, TPBS, 0, stream>>>(src, dst, H, packed, ss);
  k_fine_sort<<<DNB, TPB, 0, stream>>>(H, packed, src_sorted, row_ptr, norm_in);
  k_fine_count<<<SNB, TPB, 0, stream>>>(H, ss, norm_out);
  k_gemm1<<<1024, TPB, 0, stream>>>((const float4*)x, W1, norm_out, xt_b);
  k_agg1f<<<NN / 4, TPB, 0, stream>>>((const uint4*)xt_b, src_sorted, row_ptr,
                                      norm_in, norm_out, b1, W2, h1t_b);
  k_agg2<<<NN / 4, TPB, 0, stream>>>((const uint4*)h1t_b, src_sorted, row_ptr, norm_in, b2, out);
}

// Round 13
// 269.869 us; speedup vs baseline: 1.0801x; 1.0398x over previous
//
#include <hip/hip_runtime.h>

// GCN 2-layer, round 13: UNFUSED layer-2 transform with bf16 h1.
// r8-r12 lesson: every fused AGG1+GEMM2 variant costs +22..45us over the
// bare r7 gather (57.7us) -- W2 staging stalls each of 25K blocks behind a
// barrier before the gather, and the epilogue must move >=7.7KB of W2
// through LDS per node. Unfused wins: agg1 = r7's lean kernel emitting h1
// as bf16 (halves gemm2 input); gemm2b = gemm1-style register-resident W2
// (64 VGPR/lane), readlane broadcasts, no LDS, no barriers, W2 load
// amortized over ~24 nodes/wave.
// CSR build unchanged (LDS-staged burst-flush scatter, zero global atomics).
// Transform-first identity: segsum(h[src]) @ W == segsum((h@W)[src]).

#define NN 100000
#define NE 3200000
#define NOUTF 30
#define TPB 256
#define TPBW 1024                          // hist blocks
#define TPBS 512                           // scatter blocks

// dst stream buckets
#define DSH 8
#define DCB 256
#define DNB ((NN + DCB - 1) / DCB)         // 391
// src stream buckets
#define SSH 10
#define SCB 1024
#define SNB ((NN + SCB - 1) / SCB)         // 98

#define CHUNK 8192
#define NBLK ((NE + CHUNK - 1) / CHUNK)    // 391
#define HLD (DNB * NBLK)                   // 152,881
#define HLS (SNB * NBLK)                   // 38,318
#define HLT (HLD + HLS)                    // 191,199
#define EPT (CHUNK / TPBS)                 // 16 edges per scatter thread

#define GCH 1024
#define NSC ((HLT + GCH - 1) / GCH)        // 187

#define POOL 9216                          // fine-sort staging (36KB LDS)

__device__ __forceinline__ unsigned short f2bf(float f) {  // round-nearest-even
  unsigned u = __float_as_uint(f);
  u = (u + 0x7FFFu + ((u >> 16) & 1u)) >> 16;
  return (unsigned short)u;
}

// accumulate 8 bf16 (one uint4) into 8 f32
__device__ __forceinline__ void acc8(float* a, const uint4& u) {
  a[0] += __uint_as_float(u.x << 16);
  a[1] += __uint_as_float(u.x & 0xFFFF0000u);
  a[2] += __uint_as_float(u.y << 16);
  a[3] += __uint_as_float(u.y & 0xFFFF0000u);
  a[4] += __uint_as_float(u.z << 16);
  a[5] += __uint_as_float(u.z & 0xFFFF0000u);
  a[6] += __uint_as_float(u.w << 16);
  a[7] += __uint_as_float(u.w & 0xFFFF0000u);
}

// bijective XCD swizzle (m204 variant): consecutive swizzled ids -> same XCD
__device__ __forceinline__ int xcd_swz(int orig, int n) {
  int q = n / 8, r = n % 8;
  int xcd = orig % 8, idx = orig / 8;
  return (xcd < r ? xcd * (q + 1) : r * (q + 1) + (xcd - r) * q) + idx;
}

// ------ A: dual coarse histogram (dst>>8 and src>>10, LDS only) -------------
__global__ __launch_bounds__(TPBW) void k_hist(const int* __restrict__ src,
                                               const int* __restrict__ dst,
                                               int* __restrict__ H) {
  __shared__ int hd[DNB], hs[SNB];
  int t = threadIdx.x, k = blockIdx.x;
  for (int b = t; b < DNB; b += TPBW) hd[b] = 0;
  for (int b = t; b < SNB; b += TPBW) hs[b] = 0;
  __syncthreads();
  int beg = k * CHUNK, end = min(NE, beg + CHUNK);
  for (int i = beg + t; i < end; i += TPBW) {
    atomicAdd(&hd[dst[i] >> DSH], 1);
    atomicAdd(&hs[src[i] >> SSH], 1);
  }
  __syncthreads();
  for (int b = t; b < DNB; b += TPBW) H[b * NBLK + k] = hd[b];
  for (int b = t; b < SNB; b += TPBW) H[HLD + b * NBLK + k] = hs[b];
}

// ------ B: 3-kernel exclusive scan over H[HLT] -------------------------------
__global__ __launch_bounds__(TPB) void g_scan1(const int* __restrict__ a,
                                               int* __restrict__ bsums) {
  int t = threadIdx.x;
  int base = blockIdx.x * GCH + t * 4;
  int s = 0;
#pragma unroll
  for (int j = 0; j < 4; ++j) { int idx = base + j; if (idx < HLT) s += a[idx]; }
  __shared__ int red[TPB];
  red[t] = s; __syncthreads();
  for (int off = TPB / 2; off > 0; off >>= 1) {
    if (t < off) red[t] += red[t + off];
    __syncthreads();
  }
  if (t == 0) bsums[blockIdx.x] = red[0];
}

__global__ __launch_bounds__(1024) void g_scan2(int* __restrict__ bsums) {
  int t = threadIdx.x;
  __shared__ int lds[1024];
  int v = (t < NSC) ? bsums[t] : 0;
  int acc = v; lds[t] = acc; __syncthreads();
  for (int off = 1; off < 1024; off <<= 1) {
    int add = (t >= off) ? lds[t - off] : 0; __syncthreads();
    acc += add; lds[t] = acc; __syncthreads();
  }
  if (t < NSC) bsums[t] = acc - v;  // exclusive
}

__global__ __launch_bounds__(TPB) void g_scan3(int* __restrict__ a,
                                               const int* __restrict__ bsums) {
  int t = threadIdx.x;
  int base = blockIdx.x * GCH + t * 4;
  int v[4]; int s = 0;
#pragma unroll
  for (int j = 0; j < 4; ++j) {
    int idx = base + j;
    v[j] = (idx < HLT) ? a[idx] : 0;
    s += v[j];
  }
  __shared__ int lds[TPB];
  int acc = s; lds[t] = acc; __syncthreads();
  for (int off = 1; off < TPB; off <<= 1) {
    int add = (t >= off) ? lds[t - off] : 0; __syncthreads();
    acc += add; lds[t] = acc; __syncthreads();
  }
  int run = bsums[blockIdx.x] + (acc - s);
#pragma unroll
  for (int j = 0; j < 4; ++j) {
    int idx = base + j;
    if (idx < HLT) a[idx] = run;  // in-place exclusive
    run += v[j];
  }
}

// ------ C: LDS-staged dual scatter with contiguous burst flush --------------
__global__ __launch_bounds__(TPBS) void k_scatter(const int* __restrict__ src,
                                                  const int* __restrict__ dst,
                                                  const int* __restrict__ Hsc,
                                                  int* __restrict__ packed,
                                                  unsigned short* __restrict__ ss) {
  __shared__ int pack_lds[CHUNK];            // 32KB
  __shared__ unsigned short ss_lds[CHUNK];   // 16KB
  __shared__ int baseD[DNB + 1], curD[DNB];
  __shared__ int baseS[SNB + 1], curS[SNB];
  __shared__ int scanbuf[TPBS];
  int t = threadIdx.x;
  int k = xcd_swz((int)blockIdx.x, NBLK);    // adjacent chunks -> same XCD
  int beg = k * CHUNK, end = min(NE, beg + CHUNK);
  int cnt = end - beg;

  // register-stage this chunk's edges (coalesced reads, read once)
  int es[EPT], ed[EPT];
#pragma unroll
  for (int j = 0; j < EPT; ++j) {
    int i = beg + j * TPBS + t;
    if (i < end) { es[j] = src[i]; ed[j] = dst[i]; }
    else { es[j] = -1; ed[j] = -1; }
  }

  // block-local histograms (curD/curS double as hist accumulators)
  for (int b = t; b < DNB; b += TPBS) curD[b] = 0;
  for (int b = t; b < SNB; b += TPBS) curS[b] = 0;
  __syncthreads();
#pragma unroll
  for (int j = 0; j < EPT; ++j) {
    if (ed[j] >= 0) {
      atomicAdd(&curD[ed[j] >> DSH], 1);
      atomicAdd(&curS[es[j] >> SSH], 1);
    }
  }
  __syncthreads();

  // exclusive scan of curD -> baseD (DNB=391 <= TPBS)
  {
    int v = (t < DNB) ? curD[t] : 0;
    int acc = v; scanbuf[t] = acc; __syncthreads();
    for (int off = 1; off < TPBS; off <<= 1) {
      int add = (t >= off) ? scanbuf[t - off] : 0; __syncthreads();
      acc += add; scanbuf[t] = acc; __syncthreads();
    }
    if (t < DNB) baseD[t] = acc - v;
    if (t == 0) baseD[DNB] = cnt;
  }
  __syncthreads();
  // exclusive scan of curS -> baseS (SNB=98)
  {
    int v = (t < SNB) ? curS[t] : 0;
    int acc = v; scanbuf[t] = acc; __syncthreads();
    for (int off = 1; off < TPBS; off <<= 1) {
      int add = (t >= off) ? scanbuf[t - off] : 0; __syncthreads();
      acc += add; scanbuf[t] = acc; __syncthreads();
    }
    if (t < SNB) baseS[t] = acc - v;
    if (t == 0) baseS[SNB] = cnt;
  }
  __syncthreads();
  // cursors start at local bases
  for (int b = t; b < DNB; b += TPBS) curD[b] = baseD[b];
  for (int b = t; b < SNB; b += TPBS) curS[b] = baseS[b];
  __syncthreads();

  // LDS scatter: block-local bucket-sorted staging
#pragma unroll
  for (int j = 0; j < EPT; ++j) {
    if (ed[j] >= 0) {
      int p = atomicAdd(&curD[ed[j] >> DSH], 1);
      pack_lds[p] = (es[j] << DSH) | (ed[j] & (DCB - 1));
      int q = atomicAdd(&curS[es[j] >> SSH], 1);
      ss_lds[q] = (unsigned short)(es[j] & (SCB - 1));
    }
  }
  __syncthreads();

  // burst flush: element i -> bucket via binary search on baseD/baseS;
  // consecutive i within a bucket hit consecutive global addresses.
  for (int i = t; i < cnt; i += TPBS) {
    int lo = 0, hi = DNB;
    while (hi - lo > 1) { int mid = (lo + hi) >> 1; if (baseD[mid] <= i) lo = mid; else hi = mid; }
    packed[Hsc[lo * NBLK + k] + (i - baseD[lo])] = pack_lds[i];
  }
  for (int i = t; i < cnt; i += TPBS) {
    int lo = 0, hi = SNB;
    while (hi - lo > 1) { int mid = (lo + hi) >> 1; if (baseS[mid] <= i) lo = mid; else hi = mid; }
    ss[Hsc[HLD + lo * NBLK + k] + (i - baseS[lo]) - NE] = ss_lds[i];
  }
}

// ------ D: per-bucket fine counting sort (dst) -> src_sorted/row_ptr/norm_in
__global__ __launch_bounds__(TPB) void k_fine_sort(const int* __restrict__ Hsc,
                                                   const int* __restrict__ packed,
                                                   int* __restrict__ src_sorted,
                                                   int* __restrict__ row_ptr,
                                                   float* __restrict__ norm_in) {
  __shared__ int hist[DCB], scn[DCB], cur[DCB];
  __shared__ int pool[POOL];
  int t = threadIdx.x, b = blockIdx.x;
  int seg_beg = Hsc[b * NBLK];
  int seg_end = (b + 1 < DNB) ? Hsc[(b + 1) * NBLK] : NE;
  int cnt = seg_end - seg_beg;
  hist[t] = 0;
  __syncthreads();
  for (int i = seg_beg + t; i < seg_end; i += TPB)
    atomicAdd(&hist[packed[i] & (DCB - 1)], 1);
  __syncthreads();
  scn[t] = hist[t];
  __syncthreads();
  for (int off = 1; off < DCB; off <<= 1) {   // Hillis-Steele inclusive (256=TPB)
    int add = (t >= off) ? scn[t - off] : 0;
    __syncthreads();
    scn[t] += add;
    __syncthreads();
  }
  {
    int excl = scn[t] - hist[t];
    cur[t] = excl;
    int node = b * DCB + t;
    if (node < NN) {
      row_ptr[node] = seg_beg + excl;
      norm_in[node] = (hist[t] > 0) ? rsqrtf((float)hist[t]) : 0.0f;
    }
  }
  if (b == DNB - 1 && t == 0) row_ptr[NN] = NE;
  __syncthreads();
  for (int i = seg_beg + t; i < seg_end; i += TPB) {
    int v = packed[i];
    int p = atomicAdd(&cur[v & (DCB - 1)], 1);
    int sv = v >> DSH;
    if (p < POOL) pool[p] = sv;
    else src_sorted[seg_beg + p] = sv;                 // overflow fallback (rare)
  }
  __syncthreads();
  int lim = min(cnt, POOL);
  for (int i = t; i < lim; i += TPB) src_sorted[seg_beg + i] = pool[i];
}

// ------ E: per-bucket fine count (src, 1024 bins) -> norm_out ---------------
__global__ __launch_bounds__(TPB) void k_fine_count(const int* __restrict__ Hsc,
                                                    const unsigned short* __restrict__ ss,
                                                    float* __restrict__ norm_out) {
  __shared__ int hist[SCB];
  int t = threadIdx.x, b = blockIdx.x;
  int seg_beg = Hsc[HLD + b * NBLK] - NE;
  int seg_end = (b + 1 < SNB) ? Hsc[HLD + (b + 1) * NBLK] - NE : NE;
  for (int i = t; i < SCB; i += TPB) hist[i] = 0;
  __syncthreads();
  for (int i = seg_beg + t; i < seg_end; i += TPB)
    atomicAdd(&hist[ss[i]], 1);
  __syncthreads();
  for (int i = t; i < SCB; i += TPB) {
    int node = b * SCB + i;
    if (node < NN)
      norm_out[node] = (hist[i] > 0) ? rsqrtf((float)hist[i]) : 0.0f;
  }
}

// ------ GEMM1: xt_b[n] = bf16( norm_out[n] * (x[n] @ W1) )  [64 -> 64] ------
__global__ __launch_bounds__(TPB) void k_gemm1(const float4* __restrict__ x4,
                                               const float* __restrict__ W1,
                                               const float* __restrict__ norm_out,
                                               unsigned short* __restrict__ xt_b) {
  int lane = threadIdx.x & 63;
  int wid = (blockIdx.x * TPB + threadIdx.x) >> 6;
  int nwaves = gridDim.x * (TPB / 64);
  float w[64];
#pragma unroll
  for (int k = 0; k < 64; ++k) w[k] = W1[k * 64 + lane];
  int m = lane >> 4, q = lane & 15;
  for (int grp = wid; grp < NN / 4; grp += nwaves) {
    int nbase = grp * 4;
    float4 rv = x4[(nbase + m) * 16 + q];
    int r0 = __float_as_int(rv.x), r1 = __float_as_int(rv.y);
    int r2 = __float_as_int(rv.z), r3 = __float_as_int(rv.w);
    float acc[4] = {0.f, 0.f, 0.f, 0.f};
#pragma unroll
    for (int mm = 0; mm < 4; ++mm) {
#pragma unroll
      for (int ql = 0; ql < 16; ++ql) {
        int sl = mm * 16 + ql;
        acc[mm] = fmaf(__int_as_float(__builtin_amdgcn_readlane(r0, sl)), w[ql * 4 + 0], acc[mm]);
        acc[mm] = fmaf(__int_as_float(__builtin_amdgcn_readlane(r1, sl)), w[ql * 4 + 1], acc[mm]);
        acc[mm] = fmaf(__int_as_float(__builtin_amdgcn_readlane(r2, sl)), w[ql * 4 + 2], acc[mm]);
        acc[mm] = fmaf(__int_as_float(__builtin_amdgcn_readlane(r3, sl)), w[ql * 4 + 3], acc[mm]);
      }
    }
#pragma unroll
    for (int mm = 0; mm < 4; ++mm) {
      int n = nbase + mm;
      xt_b[n * 64 + lane] = f2bf(norm_out[n] * acc[mm]);  // 128B/row coalesced
    }
  }
}

// -- AGG1 (r7 lean, bf16 out): h1_b[n] = bf16(relu(norm_in*segsum(xt_b[src])+b1))
__global__ __launch_bounds__(TPB) void k_agg1(const uint4* __restrict__ xt4,
                                              const int* __restrict__ src_sorted,
                                              const int* __restrict__ row_ptr,
                                              const float* __restrict__ norm_in,
                                              const float* __restrict__ b1,
                                              uint4* __restrict__ h1_b4) {
  int node = (blockIdx.x * TPB + threadIdx.x) >> 6;
  int lane = threadIdx.x & 63;
  int slot = lane >> 3;  // 0..7 edge slots
  int fl = lane & 7;     // uint4 index within 128B row
  int beg = row_ptr[node];
  int end = row_ptr[node + 1];
  float a[8] = {0.f, 0.f, 0.f, 0.f, 0.f, 0.f, 0.f, 0.f};
  int e = beg + slot;
  for (; e + 8 < end; e += 16) {               // lean 2-deep (r7-proven)
    int s0 = src_sorted[e];
    int s1 = src_sorted[e + 8];
    uint4 u0 = xt4[s0 * 8 + fl];
    uint4 u1 = xt4[s1 * 8 + fl];
    acc8(a, u0);
    acc8(a, u1);
  }
  if (e < end) {
    uint4 u0 = xt4[src_sorted[e] * 8 + fl];
    acc8(a, u0);
  }
#pragma unroll
  for (int off = 8; off <= 32; off <<= 1) {
#pragma unroll
    for (int j = 0; j < 8; ++j) a[j] += __shfl_xor(a[j], off);
  }
  if (slot == 0) {
    float ni = norm_in[node];
    const float4* b1_4 = reinterpret_cast<const float4*>(b1);
    float4 bl = b1_4[fl * 2];
    float4 bh = b1_4[fl * 2 + 1];
    float v0 = fmaxf(fmaf(a[0], ni, bl.x), 0.f);
    float v1 = fmaxf(fmaf(a[1], ni, bl.y), 0.f);
    float v2 = fmaxf(fmaf(a[2], ni, bl.z), 0.f);
    float v3 = fmaxf(fmaf(a[3], ni, bl.w), 0.f);
    float v4 = fmaxf(fmaf(a[4], ni, bh.x), 0.f);
    float v5 = fmaxf(fmaf(a[5], ni, bh.y), 0.f);
    float v6 = fmaxf(fmaf(a[6], ni, bh.z), 0.f);
    float v7 = fmaxf(fmaf(a[7], ni, bh.w), 0.f);
    uint4 o;
    o.x = (unsigned)f2bf(v0) | ((unsigned)f2bf(v1) << 16);
    o.y = (unsigned)f2bf(v2) | ((unsigned)f2bf(v3) << 16);
    o.z = (unsigned)f2bf(v4) | ((unsigned)f2bf(v5) << 16);
    o.w = (unsigned)f2bf(v6) | ((unsigned)f2bf(v7) << 16);
    h1_b4[node * 8 + fl] = o;                  // 128B/node coalesced
  }
}

// -- GEMM2b: h1t_b[n][0:32] = bf16(norm_out[n]*(h1_b[n] @ W2)); bf16 in -----
// gemm1-style: W2 column oc lives in 64 VGPRs/lane; wave loads 8 bf16 rows
// (1KB coalesced), readlane-broadcast + decode; halves redundant; lane<32
// stores. No LDS, no barriers; W2 load amortized over ~24 nodes/wave.
__global__ __launch_bounds__(TPB) void k_gemm2b(const uint4* __restrict__ h1b4,
                                                const float* __restrict__ W2,
                                                const float* __restrict__ norm_out,
                                                unsigned short* __restrict__ h1t_b) {
  int lane = threadIdx.x & 63;
  int wid = (blockIdx.x * TPB + threadIdx.x) >> 6;
  int nwaves = gridDim.x * (TPB / 64);
  int oc = lane & 31;
  float w[64];
#pragma unroll
  for (int k = 0; k < 64; ++k)
    w[k] = (oc < NOUTF) ? W2[k * NOUTF + oc] : 0.f;
  int r = lane >> 3, q = lane & 7;
  for (int grp = wid; grp < NN / 8; grp += nwaves) {
    int nbase = grp * 8;
    uint4 rv = h1b4[(nbase + r) * 8 + q];      // 1KB: 8 rows of 128B
    int v0 = (int)rv.x, v1 = (int)rv.y, v2 = (int)rv.z, v3 = (int)rv.w;
#pragma unroll
    for (int rr = 0; rr < 8; ++rr) {
      float acc0 = 0.f, acc1 = 0.f;
#pragma unroll
      for (int qq = 0; qq < 8; ++qq) {
        int sl = rr * 8 + qq;
        unsigned u0 = (unsigned)__builtin_amdgcn_readlane(v0, sl);
        unsigned u1 = (unsigned)__builtin_amdgcn_readlane(v1, sl);
        unsigned u2 = (unsigned)__builtin_amdgcn_readlane(v2, sl);
        unsigned u3 = (unsigned)__builtin_amdgcn_readlane(v3, sl);
        acc0 = fmaf(__uint_as_float(u0 << 16),          w[qq * 8 + 0], acc0);
        acc1 = fmaf(__uint_as_float(u0 & 0xFFFF0000u), w[qq * 8 + 1], acc1);
        acc0 = fmaf(__uint_as_float(u1 << 16),          w[qq * 8 + 2], acc0);
        acc1 = fmaf(__uint_as_float(u1 & 0xFFFF0000u), w[qq * 8 + 3], acc1);
        acc0 = fmaf(__uint_as_float(u2 << 16),          w[qq * 8 + 4], acc0);
        acc1 = fmaf(__uint_as_float(u2 & 0xFFFF0000u), w[qq * 8 + 5], acc1);
        acc0 = fmaf(__uint_as_float(u3 << 16),          w[qq * 8 + 6], acc0);
        acc1 = fmaf(__uint_as_float(u3 & 0xFFFF0000u), w[qq * 8 + 7], acc1);
      }
      int n = nbase + rr;
      if (lane < 32) {
        float acc = acc0 + acc1;
        unsigned short hv = (oc < NOUTF) ? f2bf(norm_out[n] * acc) : (unsigned short)0;
        h1t_b[n * 32 + oc] = hv;               // 64B/node coalesced
      }
    }
  }
}

// -- AGG2: out[n] = norm_in[n]*segsum(h1t_b[src]) + b2; bf16 in, f32 out -----
__global__ __launch_bounds__(TPB) void k_agg2(const uint4* __restrict__ h1t4,
                                              const int* __restrict__ src_sorted,
                                              const int* __restrict__ row_ptr,
                                              const float* __restrict__ norm_in,
                                              const float* __restrict__ b2,
                                              float* __restrict__ out) {
  int node = (blockIdx.x * TPB + threadIdx.x) >> 6;
  int lane = threadIdx.x & 63;
  int slot = lane >> 2;  // 0..15
  int fl = lane & 3;     // uint4 index within 64B row
  int beg = row_ptr[node];
  int end = row_ptr[node + 1];
  float a[8] = {0.f, 0.f, 0.f, 0.f, 0.f, 0.f, 0.f, 0.f};
  int e = beg + slot;
  for (; e + 16 < end; e += 32) {
    int s0 = src_sorted[e];
    int s1 = src_sorted[e + 16];
    uint4 u0 = h1t4[s0 * 4 + fl];
    uint4 u1 = h1t4[s1 * 4 + fl];
    acc8(a, u0);
    acc8(a, u1);
  }
  if (e < end) {
    uint4 u0 = h1t4[src_sorted[e] * 4 + fl];
    acc8(a, u0);
  }
#pragma unroll
  for (int off = 4; off <= 32; off <<= 1) {
#pragma unroll
    for (int j = 0; j < 8; ++j) a[j] += __shfl_xor(a[j], off);
  }
  if (slot == 0) {
    float ni = norm_in[node];
    int f0 = fl * 8;
    float2* ob = (float2*)(out + (size_t)node * NOUTF);  // rows 120B, 8B-aligned
#pragma unroll
    for (int p = 0; p < 4; ++p) {
      int f = f0 + p * 2;
      if (f < NOUTF) {
        float2 v;
        v.x = fmaf(a[p * 2], ni, b2[f]);
        v.y = fmaf(a[p * 2 + 1], ni, b2[f + 1]);
        ob[f >> 1] = v;
      }
    }
  }
}

extern "C" void kernel_launch(void* const* d_in, const int* in_sizes, int n_in,
                              void* d_out, int out_size, void* d_ws, size_t ws_size,
                              hipStream_t stream) {
  (void)in_sizes; (void)n_in; (void)out_size; (void)ws_size;
  const float* x = (const float*)d_in[0];
  const int* src = (const int*)d_in[1];
  const int* dst = (const int*)d_in[2];
  const float* W1 = (const float*)d_in[3];
  const float* b1 = (const float*)d_in[4];
  const float* W2 = (const float*)d_in[5];
  const float* b2 = (const float*)d_in[6];
  float* out = (float*)d_out;

  // Workspace layout (bytes); offsets 16B-aligned.
  // packed (12.8MB) dead after k_fine_sort -> h1_b (12.8MB bf16) aliases it.
  // xt_b (12.8MB) dead after k_agg1 -> h1t_b (6.4MB bf16) aliases its base
  // (gemm2b reads h1_b in packed region, writes h1t_b in xt region: disjoint).
  char* ws = (char*)d_ws;
  int* row_ptr = (int*)(ws + 0);                           //    400,128
  float* norm_out = (float*)(ws + 400128);                 //    400,000
  float* norm_in = (float*)(ws + 800128);                  //    400,000
  int* H = (int*)(ws + 1200128);                           //    764,800 (HLT ints pad)
  int* bsums = (int*)(ws + 1964928);                       //        768 (NSC ints pad)
  unsigned short* ss = (unsigned short*)(ws + 1965696);    //  6,400,000
  int* src_sorted = (int*)(ws + 8365696);                  // 12,800,000
  int* packed = (int*)(ws + 21165696);                     // 12,800,000
  uint4* h1_b4 = (uint4*)(ws + 21165696);                  // 12,800,000 (aliases packed)
  unsigned short* xt_b = (unsigned short*)(ws + 46765696); // 12,800,000
  unsigned short* h1t_b = (unsigned short*)(ws + 46765696);// 6,400,000 (aliases xt_b)

  k_hist<<<NBLK, TPBW, 0, stream>>>(src, dst, H);
  g_scan1<<<NSC, TPB, 0, stream>>>(H, bsums);
  g_scan2<<<1, 1024, 0, stream>>>(bsums);
  g_scan3<<<NSC, TPB, 0, stream>>>(H, bsums);
  k_scatter<<<NBLK, TPBS, 0, stream>>>(src, dst, H, packed, ss);
  k_fine_sort<<<DNB, TPB, 0, stream>>>(H, packed, src_sorted, row_ptr, norm_in);
  k_fine_count<<<SNB, TPB, 0, stream>>>(H, ss, norm_out);
  k_gemm1<<<1024, TPB, 0, stream>>>((const float4*)x, W1, norm_out, xt_b);
  k_agg1<<<NN / 4, TPB, 0, stream>>>((const uint4*)xt_b, src_sorted, row_ptr,
                                     norm_in, b1, h1_b4);
  k_gemm2b<<<1024, TPB, 0, stream>>>((const uint4*)h1_b4, W2, norm_out, h1t_b);
  k_agg2<<<NN / 4, TPB, 0, stream>>>((const uint4*)h1t_b, src_sorted, row_ptr, norm_in, b2, out);
}

// Round 14
// 248.816 us; speedup vs baseline: 1.1715x; 1.0846x over previous
//
#include <hip/hip_runtime.h>

// GCN 2-layer, round 14: right-sized fine-stage grids.
// r13 profile: agg1 back at its 57.3us gather floor; fused line retired.
// Remaining cost is spread across small kernels, two of which are GRID-
// starved: fine_sort 391 blocks (1.5/CU), fine_count 98 blocks (0.4/CU).
// Changes vs r13:
//  - DSH 8->7: dst buckets 128 nodes -> fine_sort 782 blocks, POOL 4608
//    (19.5KB LDS). Scatter's block-local dst scan now 782 bins -> 2/thread.
//  - SSH 10->8: src buckets 256 nodes -> fine_count 391 blocks; payload
//    src&255 fits 1 BYTE -> ss 6.4->3.2MB.
// Everything else identical to r13: lean bf16 gathers, register-resident-W2
// gemm2b, LDS-staged burst-flush scatter (zero global atomics).
// Transform-first identity: segsum(h[src]) @ W == segsum((h@W)[src]).

#define NN 100000
#define NE 3200000
#define NOUTF 30
#define TPB 256
#define TPBW 1024                          // hist blocks
#define TPBS 512                           // scatter blocks

// dst stream buckets
#define DSH 7
#define DCB 128
#define DNB ((NN + DCB - 1) / DCB)         // 782
// src stream buckets
#define SSH 8
#define SCB 256
#define SNB ((NN + SCB - 1) / SCB)         // 391

#define CHUNK 8192
#define NBLK ((NE + CHUNK - 1) / CHUNK)    // 391
#define HLD (DNB * NBLK)                   // 305,762
#define HLS (SNB * NBLK)                   // 152,881
#define HLT (HLD + HLS)                    // 458,643
#define EPT (CHUNK / TPBS)                 // 16 edges per scatter thread

#define GCH 1024
#define NSC ((HLT + GCH - 1) / GCH)        // 448

#define POOL 4608                          // fine-sort staging (18KB LDS)

__device__ __forceinline__ unsigned short f2bf(float f) {  // round-nearest-even
  unsigned u = __float_as_uint(f);
  u = (u + 0x7FFFu + ((u >> 16) & 1u)) >> 16;
  return (unsigned short)u;
}

// accumulate 8 bf16 (one uint4) into 8 f32
__device__ __forceinline__ void acc8(float* a, const uint4& u) {
  a[0] += __uint_as_float(u.x << 16);
  a[1] += __uint_as_float(u.x & 0xFFFF0000u);
  a[2] += __uint_as_float(u.y << 16);
  a[3] += __uint_as_float(u.y & 0xFFFF0000u);
  a[4] += __uint_as_float(u.z << 16);
  a[5] += __uint_as_float(u.z & 0xFFFF0000u);
  a[6] += __uint_as_float(u.w << 16);
  a[7] += __uint_as_float(u.w & 0xFFFF0000u);
}

// bijective XCD swizzle (m204 variant): consecutive swizzled ids -> same XCD
__device__ __forceinline__ int xcd_swz(int orig, int n) {
  int q = n / 8, r = n % 8;
  int xcd = orig % 8, idx = orig / 8;
  return (xcd < r ? xcd * (q + 1) : r * (q + 1) + (xcd - r) * q) + idx;
}

// ------ A: dual coarse histogram (dst>>7 and src>>8, LDS only) --------------
__global__ __launch_bounds__(TPBW) void k_hist(const int* __restrict__ src,
                                               const int* __restrict__ dst,
                                               int* __restrict__ H) {
  __shared__ int hd[DNB], hs[SNB];
  int t = threadIdx.x, k = blockIdx.x;
  for (int b = t; b < DNB; b += TPBW) hd[b] = 0;
  for (int b = t; b < SNB; b += TPBW) hs[b] = 0;
  __syncthreads();
  int beg = k * CHUNK, end = min(NE, beg + CHUNK);
  for (int i = beg + t; i < end; i += TPBW) {
    atomicAdd(&hd[dst[i] >> DSH], 1);
    atomicAdd(&hs[src[i] >> SSH], 1);
  }
  __syncthreads();
  for (int b = t; b < DNB; b += TPBW) H[b * NBLK + k] = hd[b];
  for (int b = t; b < SNB; b += TPBW) H[HLD + b * NBLK + k] = hs[b];
}

// ------ B: 3-kernel exclusive scan over H[HLT] -------------------------------
__global__ __launch_bounds__(TPB) void g_scan1(const int* __restrict__ a,
                                               int* __restrict__ bsums) {
  int t = threadIdx.x;
  int base = blockIdx.x * GCH + t * 4;
  int s = 0;
#pragma unroll
  for (int j = 0; j < 4; ++j) { int idx = base + j; if (idx < HLT) s += a[idx]; }
  __shared__ int red[TPB];
  red[t] = s; __syncthreads();
  for (int off = TPB / 2; off > 0; off >>= 1) {
    if (t < off) red[t] += red[t + off];
    __syncthreads();
  }
  if (t == 0) bsums[blockIdx.x] = red[0];
}

__global__ __launch_bounds__(1024) void g_scan2(int* __restrict__ bsums) {
  int t = threadIdx.x;
  __shared__ int lds[1024];
  int v = (t < NSC) ? bsums[t] : 0;
  int acc = v; lds[t] = acc; __syncthreads();
  for (int off = 1; off < 1024; off <<= 1) {
    int add = (t >= off) ? lds[t - off] : 0; __syncthreads();
    acc += add; lds[t] = acc; __syncthreads();
  }
  if (t < NSC) bsums[t] = acc - v;  // exclusive
}

__global__ __launch_bounds__(TPB) void g_scan3(int* __restrict__ a,
                                               const int* __restrict__ bsums) {
  int t = threadIdx.x;
  int base = blockIdx.x * GCH + t * 4;
  int v[4]; int s = 0;
#pragma unroll
  for (int j = 0; j < 4; ++j) {
    int idx = base + j;
    v[j] = (idx < HLT) ? a[idx] : 0;
    s += v[j];
  }
  __shared__ int lds[TPB];
  int acc = s; lds[t] = acc; __syncthreads();
  for (int off = 1; off < TPB; off <<= 1) {
    int add = (t >= off) ? lds[t - off] : 0; __syncthreads();
    acc += add; lds[t] = acc; __syncthreads();
  }
  int run = bsums[blockIdx.x] + (acc - s);
#pragma unroll
  for (int j = 0; j < 4; ++j) {
    int idx = base + j;
    if (idx < HLT) a[idx] = run;  // in-place exclusive
    run += v[j];
  }
}

// ------ C: LDS-staged dual scatter with contiguous burst flush --------------
__global__ __launch_bounds__(TPBS) void k_scatter(const int* __restrict__ src,
                                                  const int* __restrict__ dst,
                                                  const int* __restrict__ Hsc,
                                                  int* __restrict__ packed,
                                                  unsigned char* __restrict__ ss) {
  __shared__ int pack_lds[CHUNK];                // 32KB
  __shared__ unsigned char ss_lds[CHUNK];        //  8KB
  __shared__ int baseD[DNB + 1], curD[DNB];      // 782 bins
  __shared__ int baseS[SNB + 1], curS[SNB];      // 391 bins
  __shared__ int scanbuf[TPBS];
  int t = threadIdx.x;
  int k = xcd_swz((int)blockIdx.x, NBLK);        // adjacent chunks -> same XCD
  int beg = k * CHUNK, end = min(NE, beg + CHUNK);
  int cnt = end - beg;

  // register-stage this chunk's edges (coalesced reads, read once)
  int es[EPT], ed[EPT];
#pragma unroll
  for (int j = 0; j < EPT; ++j) {
    int i = beg + j * TPBS + t;
    if (i < end) { es[j] = src[i]; ed[j] = dst[i]; }
    else { es[j] = -1; ed[j] = -1; }
  }

  // block-local histograms (curD/curS double as hist accumulators)
  for (int b = t; b < DNB; b += TPBS) curD[b] = 0;
  for (int b = t; b < SNB; b += TPBS) curS[b] = 0;
  __syncthreads();
#pragma unroll
  for (int j = 0; j < EPT; ++j) {
    if (ed[j] >= 0) {
      atomicAdd(&curD[ed[j] >> DSH], 1);
      atomicAdd(&curS[es[j] >> SSH], 1);
    }
  }
  __syncthreads();

  // exclusive scan of curD -> baseD (DNB=782 > TPBS: 2 bins/thread)
  {
    int i0 = t * 2, i1 = t * 2 + 1;
    int v0 = (i0 < DNB) ? curD[i0] : 0;
    int v1 = (i1 < DNB) ? curD[i1] : 0;
    int s = v0 + v1;
    int acc = s; scanbuf[t] = acc; __syncthreads();
    for (int off = 1; off < TPBS; off <<= 1) {
      int add = (t >= off) ? scanbuf[t - off] : 0; __syncthreads();
      acc += add; scanbuf[t] = acc; __syncthreads();
    }
    int excl = acc - s;
    if (i0 < DNB) baseD[i0] = excl;
    if (i1 < DNB) baseD[i1] = excl + v0;
    if (t == 0) baseD[DNB] = cnt;
  }
  __syncthreads();
  // exclusive scan of curS -> baseS (SNB=391 <= TPBS)
  {
    int v = (t < SNB) ? curS[t] : 0;
    int acc = v; scanbuf[t] = acc; __syncthreads();
    for (int off = 1; off < TPBS; off <<= 1) {
      int add = (t >= off) ? scanbuf[t - off] : 0; __syncthreads();
      acc += add; scanbuf[t] = acc; __syncthreads();
    }
    if (t < SNB) baseS[t] = acc - v;
    if (t == 0) baseS[SNB] = cnt;
  }
  __syncthreads();
  // cursors start at local bases
  for (int b = t; b < DNB; b += TPBS) curD[b] = baseD[b];
  for (int b = t; b < SNB; b += TPBS) curS[b] = baseS[b];
  __syncthreads();

  // LDS scatter: block-local bucket-sorted staging
#pragma unroll
  for (int j = 0; j < EPT; ++j) {
    if (ed[j] >= 0) {
      int p = atomicAdd(&curD[ed[j] >> DSH], 1);
      pack_lds[p] = (es[j] << DSH) | (ed[j] & (DCB - 1));
      int q = atomicAdd(&curS[es[j] >> SSH], 1);
      ss_lds[q] = (unsigned char)(es[j] & (SCB - 1));
    }
  }
  __syncthreads();

  // burst flush: element i -> bucket via binary search on baseD/baseS;
  // consecutive i within a bucket hit consecutive global addresses.
  for (int i = t; i < cnt; i += TPBS) {
    int lo = 0, hi = DNB;
    while (hi - lo > 1) { int mid = (lo + hi) >> 1; if (baseD[mid] <= i) lo = mid; else hi = mid; }
    packed[Hsc[lo * NBLK + k] + (i - baseD[lo])] = pack_lds[i];
  }
  for (int i = t; i < cnt; i += TPBS) {
    int lo = 0, hi = SNB;
    while (hi - lo > 1) { int mid = (lo + hi) >> 1; if (baseS[mid] <= i) lo = mid; else hi = mid; }
    ss[Hsc[HLD + lo * NBLK + k] + (i - baseS[lo]) - NE] = ss_lds[i];
  }
}

// ------ D: per-bucket fine counting sort (dst) -> src_sorted/row_ptr/norm_in
__global__ __launch_bounds__(TPB) void k_fine_sort(const int* __restrict__ Hsc,
                                                   const int* __restrict__ packed,
                                                   int* __restrict__ src_sorted,
                                                   int* __restrict__ row_ptr,
                                                   float* __restrict__ norm_in) {
  __shared__ int hist[DCB], scn[DCB], cur[DCB];
  __shared__ int pool[POOL];
  int t = threadIdx.x, b = blockIdx.x;
  int seg_beg = Hsc[b * NBLK];
  int seg_end = (b + 1 < DNB) ? Hsc[(b + 1) * NBLK] : NE;
  int cnt = seg_end - seg_beg;
  if (t < DCB) hist[t] = 0;
  __syncthreads();
  for (int i = seg_beg + t; i < seg_end; i += TPB)
    atomicAdd(&hist[packed[i] & (DCB - 1)], 1);
  __syncthreads();
  if (t < DCB) scn[t] = hist[t];
  __syncthreads();
  for (int off = 1; off < DCB; off <<= 1) {   // Hillis-Steele inclusive, 128 bins
    int add = (t >= off && t < DCB) ? scn[t - off] : 0;
    __syncthreads();
    if (t < DCB) scn[t] += add;
    __syncthreads();
  }
  if (t < DCB) {
    int excl = scn[t] - hist[t];
    cur[t] = excl;
    int node = b * DCB + t;
    if (node < NN) {
      row_ptr[node] = seg_beg + excl;
      norm_in[node] = (hist[t] > 0) ? rsqrtf((float)hist[t]) : 0.0f;
    }
  }
  if (b == DNB - 1 && t == 0) row_ptr[NN] = NE;
  __syncthreads();
  for (int i = seg_beg + t; i < seg_end; i += TPB) {
    int v = packed[i];
    int p = atomicAdd(&cur[v & (DCB - 1)], 1);
    int sv = v >> DSH;
    if (p < POOL) pool[p] = sv;
    else src_sorted[seg_beg + p] = sv;                 // overflow fallback (rare)
  }
  __syncthreads();
  int lim = min(cnt, POOL);
  for (int i = t; i < lim; i += TPB) src_sorted[seg_beg + i] = pool[i];
}

// ------ E: per-bucket fine count (src, 256 bins, 1-byte payload) -> norm_out
__global__ __launch_bounds__(TPB) void k_fine_count(const int* __restrict__ Hsc,
                                                    const unsigned char* __restrict__ ss,
                                                    float* __restrict__ norm_out) {
  __shared__ int hist[SCB];
  int t = threadIdx.x, b = blockIdx.x;
  int seg_beg = Hsc[HLD + b * NBLK] - NE;
  int seg_end = (b + 1 < SNB) ? Hsc[HLD + (b + 1) * NBLK] - NE : NE;
  if (t < SCB) hist[t] = 0;
  __syncthreads();
  for (int i = seg_beg + t; i < seg_end; i += TPB)
    atomicAdd(&hist[ss[i]], 1);
  __syncthreads();
  if (t < SCB) {
    int node = b * SCB + t;
    if (node < NN)
      norm_out[node] = (hist[t] > 0) ? rsqrtf((float)hist[t]) : 0.0f;
  }
}

// ------ GEMM1: xt_b[n] = bf16( norm_out[n] * (x[n] @ W1) )  [64 -> 64] ------
__global__ __launch_bounds__(TPB) void k_gemm1(const float4* __restrict__ x4,
                                               const float* __restrict__ W1,
                                               const float* __restrict__ norm_out,
                                               unsigned short* __restrict__ xt_b) {
  int lane = threadIdx.x & 63;
  int wid = (blockIdx.x * TPB + threadIdx.x) >> 6;
  int nwaves = gridDim.x * (TPB / 64);
  float w[64];
#pragma unroll
  for (int k = 0; k < 64; ++k) w[k] = W1[k * 64 + lane];
  int m = lane >> 4, q = lane & 15;
  for (int grp = wid; grp < NN / 4; grp += nwaves) {
    int nbase = grp * 4;
    float4 rv = x4[(nbase + m) * 16 + q];
    int r0 = __float_as_int(rv.x), r1 = __float_as_int(rv.y);
    int r2 = __float_as_int(rv.z), r3 = __float_as_int(rv.w);
    float acc[4] = {0.f, 0.f, 0.f, 0.f};
#pragma unroll
    for (int mm = 0; mm < 4; ++mm) {
#pragma unroll
      for (int ql = 0; ql < 16; ++ql) {
        int sl = mm * 16 + ql;
        acc[mm] = fmaf(__int_as_float(__builtin_amdgcn_readlane(r0, sl)), w[ql * 4 + 0], acc[mm]);
        acc[mm] = fmaf(__int_as_float(__builtin_amdgcn_readlane(r1, sl)), w[ql * 4 + 1], acc[mm]);
        acc[mm] = fmaf(__int_as_float(__builtin_amdgcn_readlane(r2, sl)), w[ql * 4 + 2], acc[mm]);
        acc[mm] = fmaf(__int_as_float(__builtin_amdgcn_readlane(r3, sl)), w[ql * 4 + 3], acc[mm]);
      }
    }
#pragma unroll
    for (int mm = 0; mm < 4; ++mm) {
      int n = nbase + mm;
      xt_b[n * 64 + lane] = f2bf(norm_out[n] * acc[mm]);  // 128B/row coalesced
    }
  }
}

// -- AGG1 (r7 lean, bf16 out): h1_b[n] = bf16(relu(norm_in*segsum(xt_b[src])+b1))
__global__ __launch_bounds__(TPB) void k_agg1(const uint4* __restrict__ xt4,
                                              const int* __restrict__ src_sorted,
                                              const int* __restrict__ row_ptr,
                                              const float* __restrict__ norm_in,
                                              const float* __restrict__ b1,
                                              uint4* __restrict__ h1_b4) {
  int node = (blockIdx.x * TPB + threadIdx.x) >> 6;
  int lane = threadIdx.x & 63;
  int slot = lane >> 3;  // 0..7 edge slots
  int fl = lane & 7;     // uint4 index within 128B row
  int beg = row_ptr[node];
  int end = row_ptr[node + 1];
  float a[8] = {0.f, 0.f, 0.f, 0.f, 0.f, 0.f, 0.f, 0.f};
  int e = beg + slot;
  for (; e + 8 < end; e += 16) {               // lean 2-deep (r7-proven)
    int s0 = src_sorted[e];
    int s1 = src_sorted[e + 8];
    uint4 u0 = xt4[s0 * 8 + fl];
    uint4 u1 = xt4[s1 * 8 + fl];
    acc8(a, u0);
    acc8(a, u1);
  }
  if (e < end) {
    uint4 u0 = xt4[src_sorted[e] * 8 + fl];
    acc8(a, u0);
  }
#pragma unroll
  for (int off = 8; off <= 32; off <<= 1) {
#pragma unroll
    for (int j = 0; j < 8; ++j) a[j] += __shfl_xor(a[j], off);
  }
  if (slot == 0) {
    float ni = norm_in[node];
    const float4* b1_4 = reinterpret_cast<const float4*>(b1);
    float4 bl = b1_4[fl * 2];
    float4 bh = b1_4[fl * 2 + 1];
    float v0 = fmaxf(fmaf(a[0], ni, bl.x), 0.f);
    float v1 = fmaxf(fmaf(a[1], ni, bl.y), 0.f);
    float v2 = fmaxf(fmaf(a[2], ni, bl.z), 0.f);
    float v3 = fmaxf(fmaf(a[3], ni, bl.w), 0.f);
    float v4 = fmaxf(fmaf(a[4], ni, bh.x), 0.f);
    float v5 = fmaxf(fmaf(a[5], ni, bh.y), 0.f);
    float v6 = fmaxf(fmaf(a[6], ni, bh.z), 0.f);
    float v7 = fmaxf(fmaf(a[7], ni, bh.w), 0.f);
    uint4 o;
    o.x = (unsigned)f2bf(v0) | ((unsigned)f2bf(v1) << 16);
    o.y = (unsigned)f2bf(v2) | ((unsigned)f2bf(v3) << 16);
    o.z = (unsigned)f2bf(v4) | ((unsigned)f2bf(v5) << 16);
    o.w = (unsigned)f2bf(v6) | ((unsigned)f2bf(v7) << 16);
    h1_b4[node * 8 + fl] = o;                  // 128B/node coalesced
  }
}

// -- GEMM2b: h1t_b[n][0:32] = bf16(norm_out[n]*(h1_b[n] @ W2)); bf16 in -----
__global__ __launch_bounds__(TPB) void k_gemm2b(const uint4* __restrict__ h1b4,
                                                const float* __restrict__ W2,
                                                const float* __restrict__ norm_out,
                                                unsigned short* __restrict__ h1t_b) {
  int lane = threadIdx.x & 63;
  int wid = (blockIdx.x * TPB + threadIdx.x) >> 6;
  int nwaves = gridDim.x * (TPB / 64);
  int oc = lane & 31;
  float w[64];
#pragma unroll
  for (int k = 0; k < 64; ++k)
    w[k] = (oc < NOUTF) ? W2[k * NOUTF + oc] : 0.f;
  int r = lane >> 3, q = lane & 7;
  for (int grp = wid; grp < NN / 8; grp += nwaves) {
    int nbase = grp * 8;
    uint4 rv = h1b4[(nbase + r) * 8 + q];      // 1KB: 8 rows of 128B
    int v0 = (int)rv.x, v1 = (int)rv.y, v2 = (int)rv.z, v3 = (int)rv.w;
#pragma unroll
    for (int rr = 0; rr < 8; ++rr) {
      float acc0 = 0.f, acc1 = 0.f;
#pragma unroll
      for (int qq = 0; qq < 8; ++qq) {
        int sl = rr * 8 + qq;
        unsigned u0 = (unsigned)__builtin_amdgcn_readlane(v0, sl);
        unsigned u1 = (unsigned)__builtin_amdgcn_readlane(v1, sl);
        unsigned u2 = (unsigned)__builtin_amdgcn_readlane(v2, sl);
        unsigned u3 = (unsigned)__builtin_amdgcn_readlane(v3, sl);
        acc0 = fmaf(__uint_as_float(u0 << 16),          w[qq * 8 + 0], acc0);
        acc1 = fmaf(__uint_as_float(u0 & 0xFFFF0000u), w[qq * 8 + 1], acc1);
        acc0 = fmaf(__uint_as_float(u1 << 16),          w[qq * 8 + 2], acc0);
        acc1 = fmaf(__uint_as_float(u1 & 0xFFFF0000u), w[qq * 8 + 3], acc1);
        acc0 = fmaf(__uint_as_float(u2 << 16),          w[qq * 8 + 4], acc0);
        acc1 = fmaf(__uint_as_float(u2 & 0xFFFF0000u), w[qq * 8 + 5], acc1);
        acc0 = fmaf(__uint_as_float(u3 << 16),          w[qq * 8 + 6], acc0);
        acc1 = fmaf(__uint_as_float(u3 & 0xFFFF0000u), w[qq * 8 + 7], acc1);
      }
      int n = nbase + rr;
      if (lane < 32) {
        float acc = acc0 + acc1;
        unsigned short hv = (oc < NOUTF) ? f2bf(norm_out[n] * acc) : (unsigned short)0;
        h1t_b[n * 32 + oc] = hv;               // 64B/node coalesced
      }
    }
  }
}

// -- AGG2: out[n] = norm_in[n]*segsum(h1t_b[src]) + b2; bf16 in, f32 out -----
__global__ __launch_bounds__(TPB) void k_agg2(const uint4* __restrict__ h1t4,
                                              const int* __restrict__ src_sorted,
                                              const int* __restrict__ row_ptr,
                                              const float* __restrict__ norm_in,
                                              const float* __restrict__ b2,
                                              float* __restrict__ out) {
  int node = (blockIdx.x * TPB + threadIdx.x) >> 6;
  int lane = threadIdx.x & 63;
  int slot = lane >> 2;  // 0..15
  int fl = lane & 3;     // uint4 index within 64B row
  int beg = row_ptr[node];
  int end = row_ptr[node + 1];
  float a[8] = {0.f, 0.f, 0.f, 0.f, 0.f, 0.f, 0.f, 0.f};
  int e = beg + slot;
  for (; e + 16 < end; e += 32) {
    int s0 = src_sorted[e];
    int s1 = src_sorted[e + 16];
    uint4 u0 = h1t4[s0 * 4 + fl];
    uint4 u1 = h1t4[s1 * 4 + fl];
    acc8(a, u0);
    acc8(a, u1);
  }
  if (e < end) {
    uint4 u0 = h1t4[src_sorted[e] * 4 + fl];
    acc8(a, u0);
  }
#pragma unroll
  for (int off = 4; off <= 32; off <<= 1) {
#pragma unroll
    for (int j = 0; j < 8; ++j) a[j] += __shfl_xor(a[j], off);
  }
  if (slot == 0) {
    float ni = norm_in[node];
    int f0 = fl * 8;
    float2* ob = (float2*)(out + (size_t)node * NOUTF);  // rows 120B, 8B-aligned
#pragma unroll
    for (int p = 0; p < 4; ++p) {
      int f = f0 + p * 2;
      if (f < NOUTF) {
        float2 v;
        v.x = fmaf(a[p * 2], ni, b2[f]);
        v.y = fmaf(a[p * 2 + 1], ni, b2[f + 1]);
        ob[f >> 1] = v;
      }
    }
  }
}

extern "C" void kernel_launch(void* const* d_in, const int* in_sizes, int n_in,
                              void* d_out, int out_size, void* d_ws, size_t ws_size,
                              hipStream_t stream) {
  (void)in_sizes; (void)n_in; (void)out_size; (void)ws_size;
  const float* x = (const float*)d_in[0];
  const int* src = (const int*)d_in[1];
  const int* dst = (const int*)d_in[2];
  const float* W1 = (const float*)d_in[3];
  const float* b1 = (const float*)d_in[4];
  const float* W2 = (const float*)d_in[5];
  const float* b2 = (const float*)d_in[6];
  float* out = (float*)d_out;

  // Workspace layout (bytes); offsets 16B-aligned (same as r13; ss now uses
  // only 3.2MB of its 6.4MB slot; H uses 1.84MB of its region).
  // packed (12.8MB) dead after k_fine_sort -> h1_b (12.8MB bf16) aliases it.
  // xt_b (12.8MB) dead after k_agg1 -> h1t_b (6.4MB bf16) aliases its base.
  char* ws = (char*)d_ws;
  int* row_ptr = (int*)(ws + 0);                           //    400,128
  float* norm_out = (float*)(ws + 400128);                 //    400,000
  float* norm_in = (float*)(ws + 800128);                  //    400,000
  int* H = (int*)(ws + 1200128);                           //  1,834,572 used
  int* bsums = (int*)(ws + 3100128);                       //      1,792 (NSC ints)
  unsigned char* ss = (unsigned char*)(ws + 3101952);      //  3,200,000
  int* src_sorted = (int*)(ws + 8365696);                  // 12,800,000
  int* packed = (int*)(ws + 21165696);                     // 12,800,000
  uint4* h1_b4 = (uint4*)(ws + 21165696);                  // 12,800,000 (aliases packed)
  unsigned short* xt_b = (unsigned short*)(ws + 46765696); // 12,800,000
  unsigned short* h1t_b = (unsigned short*)(ws + 46765696);// 6,400,000 (aliases xt_b)

  k_hist<<<NBLK, TPBW, 0, stream>>>(src, dst, H);
  g_scan1<<<NSC, TPB, 0, stream>>>(H, bsums);
  g_scan2<<<1, 1024, 0, stream>>>(bsums);
  g_scan3<<<NSC, TPB, 0, stream>>>(H, bsums);
  k_scatter<<<NBLK, TPBS, 0, stream>>>(src, dst, H, packed, ss);
  k_fine_sort<<<DNB, TPB, 0, stream>>>(H, packed, src_sorted, row_ptr, norm_in);
  k_fine_count<<<SNB, TPB, 0, stream>>>(H, ss, norm_out);
  k_gemm1<<<1024, TPB, 0, stream>>>((const float4*)x, W1, norm_out, xt_b);
  k_agg1<<<NN / 4, TPB, 0, stream>>>((const uint4*)xt_b, src_sorted, row_ptr,
                                     norm_in, b1, h1_b4);
  k_gemm2b<<<1024, TPB, 0, stream>>>((const uint4*)h1_b4, W2, norm_out, h1t_b);
  k_agg2<<<NN / 4, TPB, 0, stream>>>((const uint4*)h1t_b, src_sorted, row_ptr, norm_in, b2, out);
}

// Round 15
// 245.502 us; speedup vs baseline: 1.1873x; 1.0135x over previous
//
#include <hip/hip_runtime.h>

// GCN 2-layer, round 15: permutation-staged scatter flush (no binary search)
// + TPBS 1024.
// r14 analysis: scatter's burst flush did a ~10-deep divergent LDS binary
// search per element per stream (~19 dependent LDS reads/edge) and ran only
// 12 waves/CU (391 blocks x 512). Fix: LDS stages a PERMUTATION (ushort
// local edge index); flush re-reads src/dst from the L2-hot chunk and gets
// the bucket directly from the value (d>>DSH / s>>SSH). Coalesced bucket-run
// writes unchanged. TPBS=1024 doubles resident waves on the fixed 391-block
// grid. Everything else identical to r14 (lean bf16 gathers at the agg1
// floor, register-W2 gemm2b, right-sized fine grids, zero global atomics).
// Transform-first identity: segsum(h[src]) @ W == segsum((h@W)[src]).

#define NN 100000
#define NE 3200000
#define NOUTF 30
#define TPB 256
#define TPBW 1024                          // hist blocks
#define TPBS 1024                          // scatter blocks (was 512)

// dst stream buckets
#define DSH 7
#define DCB 128
#define DNB ((NN + DCB - 1) / DCB)         // 782
// src stream buckets
#define SSH 8
#define SCB 256
#define SNB ((NN + SCB - 1) / SCB)         // 391

#define CHUNK 8192
#define NBLK ((NE + CHUNK - 1) / CHUNK)    // 391
#define HLD (DNB * NBLK)                   // 305,762
#define HLS (SNB * NBLK)                   // 152,881
#define HLT (HLD + HLS)                    // 458,643
#define EPT (CHUNK / TPBS)                 // 8 edges per scatter thread

#define GCH 1024
#define NSC ((HLT + GCH - 1) / GCH)        // 448

#define POOL 4608                          // fine-sort staging (18KB LDS)

__device__ __forceinline__ unsigned short f2bf(float f) {  // round-nearest-even
  unsigned u = __float_as_uint(f);
  u = (u + 0x7FFFu + ((u >> 16) & 1u)) >> 16;
  return (unsigned short)u;
}

// accumulate 8 bf16 (one uint4) into 8 f32
__device__ __forceinline__ void acc8(float* a, const uint4& u) {
  a[0] += __uint_as_float(u.x << 16);
  a[1] += __uint_as_float(u.x & 0xFFFF0000u);
  a[2] += __uint_as_float(u.y << 16);
  a[3] += __uint_as_float(u.y & 0xFFFF0000u);
  a[4] += __uint_as_float(u.z << 16);
  a[5] += __uint_as_float(u.z & 0xFFFF0000u);
  a[6] += __uint_as_float(u.w << 16);
  a[7] += __uint_as_float(u.w & 0xFFFF0000u);
}

// bijective XCD swizzle (m204 variant): consecutive swizzled ids -> same XCD
__device__ __forceinline__ int xcd_swz(int orig, int n) {
  int q = n / 8, r = n % 8;
  int xcd = orig % 8, idx = orig / 8;
  return (xcd < r ? xcd * (q + 1) : r * (q + 1) + (xcd - r) * q) + idx;
}

// ------ A: dual coarse histogram (dst>>7 and src>>8, LDS only) --------------
__global__ __launch_bounds__(TPBW) void k_hist(const int* __restrict__ src,
                                               const int* __restrict__ dst,
                                               int* __restrict__ H) {
  __shared__ int hd[DNB], hs[SNB];
  int t = threadIdx.x, k = blockIdx.x;
  for (int b = t; b < DNB; b += TPBW) hd[b] = 0;
  for (int b = t; b < SNB; b += TPBW) hs[b] = 0;
  __syncthreads();
  int beg = k * CHUNK, end = min(NE, beg + CHUNK);
  for (int i = beg + t; i < end; i += TPBW) {
    atomicAdd(&hd[dst[i] >> DSH], 1);
    atomicAdd(&hs[src[i] >> SSH], 1);
  }
  __syncthreads();
  for (int b = t; b < DNB; b += TPBW) H[b * NBLK + k] = hd[b];
  for (int b = t; b < SNB; b += TPBW) H[HLD + b * NBLK + k] = hs[b];
}

// ------ B: 3-kernel exclusive scan over H[HLT] -------------------------------
__global__ __launch_bounds__(TPB) void g_scan1(const int* __restrict__ a,
                                               int* __restrict__ bsums) {
  int t = threadIdx.x;
  int base = blockIdx.x * GCH + t * 4;
  int s = 0;
#pragma unroll
  for (int j = 0; j < 4; ++j) { int idx = base + j; if (idx < HLT) s += a[idx]; }
  __shared__ int red[TPB];
  red[t] = s; __syncthreads();
  for (int off = TPB / 2; off > 0; off >>= 1) {
    if (t < off) red[t] += red[t + off];
    __syncthreads();
  }
  if (t == 0) bsums[blockIdx.x] = red[0];
}

__global__ __launch_bounds__(1024) void g_scan2(int* __restrict__ bsums) {
  int t = threadIdx.x;
  __shared__ int lds[1024];
  int v = (t < NSC) ? bsums[t] : 0;
  int acc = v; lds[t] = acc; __syncthreads();
  for (int off = 1; off < 1024; off <<= 1) {
    int add = (t >= off) ? lds[t - off] : 0; __syncthreads();
    acc += add; lds[t] = acc; __syncthreads();
  }
  if (t < NSC) bsums[t] = acc - v;  // exclusive
}

__global__ __launch_bounds__(TPB) void g_scan3(int* __restrict__ a,
                                               const int* __restrict__ bsums) {
  int t = threadIdx.x;
  int base = blockIdx.x * GCH + t * 4;
  int v[4]; int s = 0;
#pragma unroll
  for (int j = 0; j < 4; ++j) {
    int idx = base + j;
    v[j] = (idx < HLT) ? a[idx] : 0;
    s += v[j];
  }
  __shared__ int lds[TPB];
  int acc = s; lds[t] = acc; __syncthreads();
  for (int off = 1; off < TPB; off <<= 1) {
    int add = (t >= off) ? lds[t - off] : 0; __syncthreads();
    acc += add; lds[t] = acc; __syncthreads();
  }
  int run = bsums[blockIdx.x] + (acc - s);
#pragma unroll
  for (int j = 0; j < 4; ++j) {
    int idx = base + j;
    if (idx < HLT) a[idx] = run;  // in-place exclusive
    run += v[j];
  }
}

// ------ C: perm-staged dual scatter with contiguous burst flush -------------
// LDS holds a PERMUTATION (local edge index) per stream; flush derives the
// bucket directly from the re-read edge value (no binary search, ~4 LDS
// reads/edge total vs ~19). Chunk src/dst re-reads are L2-hot.
__global__ __launch_bounds__(TPBS) void k_scatter(const int* __restrict__ src,
                                                  const int* __restrict__ dst,
                                                  const int* __restrict__ Hsc,
                                                  int* __restrict__ packed,
                                                  unsigned char* __restrict__ ss) {
  __shared__ unsigned short perm_d[CHUNK];       // 16KB
  __shared__ unsigned short perm_s[CHUNK];       // 16KB
  __shared__ int baseD[DNB + 1], curD[DNB];      // 782 bins
  __shared__ int baseS[SNB + 1], curS[SNB];      // 391 bins
  __shared__ int scanbuf[TPBS];                  // 4KB
  int t = threadIdx.x;
  int k = xcd_swz((int)blockIdx.x, NBLK);        // adjacent chunks -> same XCD
  int beg = k * CHUNK, end = min(NE, beg + CHUNK);
  int cnt = end - beg;

  // register-stage this chunk's edges (coalesced reads)
  int es[EPT], ed[EPT];
#pragma unroll
  for (int j = 0; j < EPT; ++j) {
    int i = beg + j * TPBS + t;
    if (i < end) { es[j] = src[i]; ed[j] = dst[i]; }
    else { es[j] = -1; ed[j] = -1; }
  }

  // block-local histograms (curD/curS double as hist accumulators)
  for (int b = t; b < DNB; b += TPBS) curD[b] = 0;
  for (int b = t; b < SNB; b += TPBS) curS[b] = 0;
  __syncthreads();
#pragma unroll
  for (int j = 0; j < EPT; ++j) {
    if (ed[j] >= 0) {
      atomicAdd(&curD[ed[j] >> DSH], 1);
      atomicAdd(&curS[es[j] >> SSH], 1);
    }
  }
  __syncthreads();

  // exclusive scan of curD -> baseD (DNB=782 <= TPBS=1024)
  {
    int v = (t < DNB) ? curD[t] : 0;
    int acc = v; scanbuf[t] = acc; __syncthreads();
    for (int off = 1; off < TPBS; off <<= 1) {
      int add = (t >= off) ? scanbuf[t - off] : 0; __syncthreads();
      acc += add; scanbuf[t] = acc; __syncthreads();
    }
    if (t < DNB) baseD[t] = acc - v;
    if (t == 0) baseD[DNB] = cnt;
  }
  __syncthreads();
  // exclusive scan of curS -> baseS (SNB=391)
  {
    int v = (t < SNB) ? curS[t] : 0;
    int acc = v; scanbuf[t] = acc; __syncthreads();
    for (int off = 1; off < TPBS; off <<= 1) {
      int add = (t >= off) ? scanbuf[t - off] : 0; __syncthreads();
      acc += add; scanbuf[t] = acc; __syncthreads();
    }
    if (t < SNB) baseS[t] = acc - v;
    if (t == 0) baseS[SNB] = cnt;
  }
  __syncthreads();
  // cursors start at local bases
  for (int b = t; b < DNB; b += TPBS) curD[b] = baseD[b];
  for (int b = t; b < SNB; b += TPBS) curS[b] = baseS[b];
  __syncthreads();

  // LDS scatter: stage the permutation (local edge index, fits ushort)
#pragma unroll
  for (int j = 0; j < EPT; ++j) {
    if (ed[j] >= 0) {
      int li = j * TPBS + t;
      int p = atomicAdd(&curD[ed[j] >> DSH], 1);
      perm_d[p] = (unsigned short)li;
      int q = atomicAdd(&curS[es[j] >> SSH], 1);
      perm_s[q] = (unsigned short)li;
    }
  }
  __syncthreads();

  // burst flush: bucket derived from the value itself; consecutive i within
  // a bucket hit consecutive global addresses (coalesced runs).
  for (int i = t; i < cnt; i += TPBS) {
    int gi = beg + perm_d[i];
    int d = dst[gi], s = src[gi];                // L2-hot chunk re-read
    int bkt = d >> DSH;
    packed[Hsc[bkt * NBLK + k] + (i - baseD[bkt])] = (s << DSH) | (d & (DCB - 1));
  }
  for (int i = t; i < cnt; i += TPBS) {
    int gi = beg + perm_s[i];
    int s = src[gi];
    int bkt = s >> SSH;
    ss[Hsc[HLD + bkt * NBLK + k] + (i - baseS[bkt]) - NE] = (unsigned char)(s & (SCB - 1));
  }
}

// ------ D: per-bucket fine counting sort (dst) -> src_sorted/row_ptr/norm_in
__global__ __launch_bounds__(TPB) void k_fine_sort(const int* __restrict__ Hsc,
                                                   const int* __restrict__ packed,
                                                   int* __restrict__ src_sorted,
                                                   int* __restrict__ row_ptr,
                                                   float* __restrict__ norm_in) {
  __shared__ int hist[DCB], scn[DCB], cur[DCB];
  __shared__ int pool[POOL];
  int t = threadIdx.x, b = blockIdx.x;
  int seg_beg = Hsc[b * NBLK];
  int seg_end = (b + 1 < DNB) ? Hsc[(b + 1) * NBLK] : NE;
  int cnt = seg_end - seg_beg;
  if (t < DCB) hist[t] = 0;
  __syncthreads();
  for (int i = seg_beg + t; i < seg_end; i += TPB)
    atomicAdd(&hist[packed[i] & (DCB - 1)], 1);
  __syncthreads();
  if (t < DCB) scn[t] = hist[t];
  __syncthreads();
  for (int off = 1; off < DCB; off <<= 1) {   // Hillis-Steele inclusive, 128 bins
    int add = (t >= off && t < DCB) ? scn[t - off] : 0;
    __syncthreads();
    if (t < DCB) scn[t] += add;
    __syncthreads();
  }
  if (t < DCB) {
    int excl = scn[t] - hist[t];
    cur[t] = excl;
    int node = b * DCB + t;
    if (node < NN) {
      row_ptr[node] = seg_beg + excl;
      norm_in[node] = (hist[t] > 0) ? rsqrtf((float)hist[t]) : 0.0f;
    }
  }
  if (b == DNB - 1 && t == 0) row_ptr[NN] = NE;
  __syncthreads();
  for (int i = seg_beg + t; i < seg_end; i += TPB) {
    int v = packed[i];
    int p = atomicAdd(&cur[v & (DCB - 1)], 1);
    int sv = v >> DSH;
    if (p < POOL) pool[p] = sv;
    else src_sorted[seg_beg + p] = sv;                 // overflow fallback (rare)
  }
  __syncthreads();
  int lim = min(cnt, POOL);
  for (int i = t; i < lim; i += TPB) src_sorted[seg_beg + i] = pool[i];
}

// ------ E: per-bucket fine count (src, 256 bins, 1-byte payload) -> norm_out
__global__ __launch_bounds__(TPB) void k_fine_count(const int* __restrict__ Hsc,
                                                    const unsigned char* __restrict__ ss,
                                                    float* __restrict__ norm_out) {
  __shared__ int hist[SCB];
  int t = threadIdx.x, b = blockIdx.x;
  int seg_beg = Hsc[HLD + b * NBLK] - NE;
  int seg_end = (b + 1 < SNB) ? Hsc[HLD + (b + 1) * NBLK] - NE : NE;
  if (t < SCB) hist[t] = 0;
  __syncthreads();
  for (int i = seg_beg + t; i < seg_end; i += TPB)
    atomicAdd(&hist[ss[i]], 1);
  __syncthreads();
  if (t < SCB) {
    int node = b * SCB + t;
    if (node < NN)
      norm_out[node] = (hist[t] > 0) ? rsqrtf((float)hist[t]) : 0.0f;
  }
}

// ------ GEMM1: xt_b[n] = bf16( norm_out[n] * (x[n] @ W1) )  [64 -> 64] ------
__global__ __launch_bounds__(TPB) void k_gemm1(const float4* __restrict__ x4,
                                               const float* __restrict__ W1,
                                               const float* __restrict__ norm_out,
                                               unsigned short* __restrict__ xt_b) {
  int lane = threadIdx.x & 63;
  int wid = (blockIdx.x * TPB + threadIdx.x) >> 6;
  int nwaves = gridDim.x * (TPB / 64);
  float w[64];
#pragma unroll
  for (int k = 0; k < 64; ++k) w[k] = W1[k * 64 + lane];
  int m = lane >> 4, q = lane & 15;
  for (int grp = wid; grp < NN / 4; grp += nwaves) {
    int nbase = grp * 4;
    float4 rv = x4[(nbase + m) * 16 + q];
    int r0 = __float_as_int(rv.x), r1 = __float_as_int(rv.y);
    int r2 = __float_as_int(rv.z), r3 = __float_as_int(rv.w);
    float acc[4] = {0.f, 0.f, 0.f, 0.f};
#pragma unroll
    for (int mm = 0; mm < 4; ++mm) {
#pragma unroll
      for (int ql = 0; ql < 16; ++ql) {
        int sl = mm * 16 + ql;
        acc[mm] = fmaf(__int_as_float(__builtin_amdgcn_readlane(r0, sl)), w[ql * 4 + 0], acc[mm]);
        acc[mm] = fmaf(__int_as_float(__builtin_amdgcn_readlane(r1, sl)), w[ql * 4 + 1], acc[mm]);
        acc[mm] = fmaf(__int_as_float(__builtin_amdgcn_readlane(r2, sl)), w[ql * 4 + 2], acc[mm]);
        acc[mm] = fmaf(__int_as_float(__builtin_amdgcn_readlane(r3, sl)), w[ql * 4 + 3], acc[mm]);
      }
    }
#pragma unroll
    for (int mm = 0; mm < 4; ++mm) {
      int n = nbase + mm;
      xt_b[n * 64 + lane] = f2bf(norm_out[n] * acc[mm]);  // 128B/row coalesced
    }
  }
}

// -- AGG1 (r7 lean, bf16 out): h1_b[n] = bf16(relu(norm_in*segsum(xt_b[src])+b1))
__global__ __launch_bounds__(TPB) void k_agg1(const uint4* __restrict__ xt4,
                                              const int* __restrict__ src_sorted,
                                              const int* __restrict__ row_ptr,
                                              const float* __restrict__ norm_in,
                                              const float* __restrict__ b1,
                                              uint4* __restrict__ h1_b4) {
  int node = (blockIdx.x * TPB + threadIdx.x) >> 6;
  int lane = threadIdx.x & 63;
  int slot = lane >> 3;  // 0..7 edge slots
  int fl = lane & 7;     // uint4 index within 128B row
  int beg = row_ptr[node];
  int end = row_ptr[node + 1];
  float a[8] = {0.f, 0.f, 0.f, 0.f, 0.f, 0.f, 0.f, 0.f};
  int e = beg + slot;
  for (; e + 8 < end; e += 16) {               // lean 2-deep (r7-proven)
    int s0 = src_sorted[e];
    int s1 = src_sorted[e + 8];
    uint4 u0 = xt4[s0 * 8 + fl];
    uint4 u1 = xt4[s1 * 8 + fl];
    acc8(a, u0);
    acc8(a, u1);
  }
  if (e < end) {
    uint4 u0 = xt4[src_sorted[e] * 8 + fl];
    acc8(a, u0);
  }
#pragma unroll
  for (int off = 8; off <= 32; off <<= 1) {
#pragma unroll
    for (int j = 0; j < 8; ++j) a[j] += __shfl_xor(a[j], off);
  }
  if (slot == 0) {
    float ni = norm_in[node];
    const float4* b1_4 = reinterpret_cast<const float4*>(b1);
    float4 bl = b1_4[fl * 2];
    float4 bh = b1_4[fl * 2 + 1];
    float v0 = fmaxf(fmaf(a[0], ni, bl.x), 0.f);
    float v1 = fmaxf(fmaf(a[1], ni, bl.y), 0.f);
    float v2 = fmaxf(fmaf(a[2], ni, bl.z), 0.f);
    float v3 = fmaxf(fmaf(a[3], ni, bl.w), 0.f);
    float v4 = fmaxf(fmaf(a[4], ni, bh.x), 0.f);
    float v5 = fmaxf(fmaf(a[5], ni, bh.y), 0.f);
    float v6 = fmaxf(fmaf(a[6], ni, bh.z), 0.f);
    float v7 = fmaxf(fmaf(a[7], ni, bh.w), 0.f);
    uint4 o;
    o.x = (unsigned)f2bf(v0) | ((unsigned)f2bf(v1) << 16);
    o.y = (unsigned)f2bf(v2) | ((unsigned)f2bf(v3) << 16);
    o.z = (unsigned)f2bf(v4) | ((unsigned)f2bf(v5) << 16);
    o.w = (unsigned)f2bf(v6) | ((unsigned)f2bf(v7) << 16);
    h1_b4[node * 8 + fl] = o;                  // 128B/node coalesced
  }
}

// -- GEMM2b: h1t_b[n][0:32] = bf16(norm_out[n]*(h1_b[n] @ W2)); bf16 in -----
__global__ __launch_bounds__(TPB) void k_gemm2b(const uint4* __restrict__ h1b4,
                                                const float* __restrict__ W2,
                                                const float* __restrict__ norm_out,
                                                unsigned short* __restrict__ h1t_b) {
  int lane = threadIdx.x & 63;
  int wid = (blockIdx.x * TPB + threadIdx.x) >> 6;
  int nwaves = gridDim.x * (TPB / 64);
  int oc = lane & 31;
  float w[64];
#pragma unroll
  for (int k = 0; k < 64; ++k)
    w[k] = (oc < NOUTF) ? W2[k * NOUTF + oc] : 0.f;
  int r = lane >> 3, q = lane & 7;
  for (int grp = wid; grp < NN / 8; grp += nwaves) {
    int nbase = grp * 8;
    uint4 rv = h1b4[(nbase + r) * 8 + q];      // 1KB: 8 rows of 128B
    int v0 = (int)rv.x, v1 = (int)rv.y, v2 = (int)rv.z, v3 = (int)rv.w;
#pragma unroll
    for (int rr = 0; rr < 8; ++rr) {
      float acc0 = 0.f, acc1 = 0.f;
#pragma unroll
      for (int qq = 0; qq < 8; ++qq) {
        int sl = rr * 8 + qq;
        unsigned u0 = (unsigned)__builtin_amdgcn_readlane(v0, sl);
        unsigned u1 = (unsigned)__builtin_amdgcn_readlane(v1, sl);
        unsigned u2 = (unsigned)__builtin_amdgcn_readlane(v2, sl);
        unsigned u3 = (unsigned)__builtin_amdgcn_readlane(v3, sl);
        acc0 = fmaf(__uint_as_float(u0 << 16),          w[qq * 8 + 0], acc0);
        acc1 = fmaf(__uint_as_float(u0 & 0xFFFF0000u), w[qq * 8 + 1], acc1);
        acc0 = fmaf(__uint_as_float(u1 << 16),          w[qq * 8 + 2], acc0);
        acc1 = fmaf(__uint_as_float(u1 & 0xFFFF0000u), w[qq * 8 + 3], acc1);
        acc0 = fmaf(__uint_as_float(u2 << 16),          w[qq * 8 + 4], acc0);
        acc1 = fmaf(__uint_as_float(u2 & 0xFFFF0000u), w[qq * 8 + 5], acc1);
        acc0 = fmaf(__uint_as_float(u3 << 16),          w[qq * 8 + 6], acc0);
        acc1 = fmaf(__uint_as_float(u3 & 0xFFFF0000u), w[qq * 8 + 7], acc1);
      }
      int n = nbase + rr;
      if (lane < 32) {
        float acc = acc0 + acc1;
        unsigned short hv = (oc < NOUTF) ? f2bf(norm_out[n] * acc) : (unsigned short)0;
        h1t_b[n * 32 + oc] = hv;               // 64B/node coalesced
      }
    }
  }
}

// -- AGG2: out[n] = norm_in[n]*segsum(h1t_b[src]) + b2; bf16 in, f32 out -----
__global__ __launch_bounds__(TPB) void k_agg2(const uint4* __restrict__ h1t4,
                                              const int* __restrict__ src_sorted,
                                              const int* __restrict__ row_ptr,
                                              const float* __restrict__ norm_in,
                                              const float* __restrict__ b2,
                                              float* __restrict__ out) {
  int node = (blockIdx.x * TPB + threadIdx.x) >> 6;
  int lane = threadIdx.x & 63;
  int slot = lane >> 2;  // 0..15
  int fl = lane & 3;     // uint4 index within 64B row
  int beg = row_ptr[node];
  int end = row_ptr[node + 1];
  float a[8] = {0.f, 0.f, 0.f, 0.f, 0.f, 0.f, 0.f, 0.f};
  int e = beg + slot;
  for (; e + 16 < end; e += 32) {
    int s0 = src_sorted[e];
    int s1 = src_sorted[e + 16];
    uint4 u0 = h1t4[s0 * 4 + fl];
    uint4 u1 = h1t4[s1 * 4 + fl];
    acc8(a, u0);
    acc8(a, u1);
  }
  if (e < end) {
    uint4 u0 = h1t4[src_sorted[e] * 4 + fl];
    acc8(a, u0);
  }
#pragma unroll
  for (int off = 4; off <= 32; off <<= 1) {
#pragma unroll
    for (int j = 0; j < 8; ++j) a[j] += __shfl_xor(a[j], off);
  }
  if (slot == 0) {
    float ni = norm_in[node];
    int f0 = fl * 8;
    float2* ob = (float2*)(out + (size_t)node * NOUTF);  // rows 120B, 8B-aligned
#pragma unroll
    for (int p = 0; p < 4; ++p) {
      int f = f0 + p * 2;
      if (f < NOUTF) {
        float2 v;
        v.x = fmaf(a[p * 2], ni, b2[f]);
        v.y = fmaf(a[p * 2 + 1], ni, b2[f + 1]);
        ob[f >> 1] = v;
      }
    }
  }
}

extern "C" void kernel_launch(void* const* d_in, const int* in_sizes, int n_in,
                              void* d_out, int out_size, void* d_ws, size_t ws_size,
                              hipStream_t stream) {
  (void)in_sizes; (void)n_in; (void)out_size; (void)ws_size;
  const float* x = (const float*)d_in[0];
  const int* src = (const int*)d_in[1];
  const int* dst = (const int*)d_in[2];
  const float* W1 = (const float*)d_in[3];
  const float* b1 = (const float*)d_in[4];
  const float* W2 = (const float*)d_in[5];
  const float* b2 = (const float*)d_in[6];
  float* out = (float*)d_out;

  // Workspace layout (bytes); offsets 16B-aligned (identical to r14).
  // packed (12.8MB) dead after k_fine_sort -> h1_b (12.8MB bf16) aliases it.
  // xt_b (12.8MB) dead after k_agg1 -> h1t_b (6.4MB bf16) aliases its base.
  char* ws = (char*)d_ws;
  int* row_ptr = (int*)(ws + 0);                           //    400,128
  float* norm_out = (float*)(ws + 400128);                 //    400,000
  float* norm_in = (float*)(ws + 800128);                  //    400,000
  int* H = (int*)(ws + 1200128);                           //  1,834,572 used
  int* bsums = (int*)(ws + 3100128);                       //      1,792 (NSC ints)
  unsigned char* ss = (unsigned char*)(ws + 3101952);      //  3,200,000
  int* src_sorted = (int*)(ws + 8365696);                  // 12,800,000
  int* packed = (int*)(ws + 21165696);                     // 12,800,000
  uint4* h1_b4 = (uint4*)(ws + 21165696);                  // 12,800,000 (aliases packed)
  unsigned short* xt_b = (unsigned short*)(ws + 46765696); // 12,800,000
  unsigned short* h1t_b = (unsigned short*)(ws + 46765696);// 6,400,000 (aliases xt_b)

  k_hist<<<NBLK, TPBW, 0, stream>>>(src, dst, H);
  g_scan1<<<NSC, TPB, 0, stream>>>(H, bsums);
  g_scan2<<<1, 1024, 0, stream>>>(bsums);
  g_scan3<<<NSC, TPB, 0, stream>>>(H, bsums);
  k_scatter<<<NBLK, TPBS, 0, stream>>>(src, dst, H, packed, ss);
  k_fine_sort<<<DNB, TPB, 0, stream>>>(H, packed, src_sorted, row_ptr, norm_in);
  k_fine_count<<<SNB, TPB, 0, stream>>>(H, ss, norm_out);
  k_gemm1<<<1024, TPB, 0, stream>>>((const float4*)x, W1, norm_out, xt_b);
  k_agg1<<<NN / 4, TPB, 0, stream>>>((const uint4*)xt_b, src_sorted, row_ptr,
                                     norm_in, b1, h1_b4);
  k_gemm2b<<<1024, TPB, 0, stream>>>((const uint4*)h1_b4, W2, norm_out, h1t_b);
  k_agg2<<<NN / 4, TPB, 0, stream>>>((const uint4*)h1t_b, src_sorted, row_ptr, norm_in, b2, out);
}

// Round 16
// 231.738 us; speedup vs baseline: 1.2578x; 1.0594x over previous
//
#include <hip/hip_runtime.h>

// GCN 2-layer, round 16: de-duplicate CSR-build work.
//  - k_scatter no longer histograms: per-(bucket,chunk) counts are derived
//    from adjacent diffs of the SCANNED Hsc (linear successor; boundary 2NE).
//    Local bases via block scan; adj[b] = global_start - local_base in LDS
//    -> flush address = adj[bkt] + i (no global Hsc reads, no hist atomics).
//  - g_scan2 deleted: each g_scan3 block locally scans the 448 raw bsums.
//  - fine_sort + fine_count fused into one launch (branch on blockIdx).
// Everything else identical to r15: lean bf16 gathers (agg1 at its 57us
// line-lookup floor), register-W2 gemm2b, zero global atomics.
// Transform-first identity: segsum(h[src]) @ W == segsum((h@W)[src]).

#define NN 100000
#define NE 3200000
#define NOUTF 30
#define TPB 256
#define TPBW 1024                          // hist blocks
#define TPBS 1024                          // scatter blocks

// dst stream buckets
#define DSH 7
#define DCB 128
#define DNB ((NN + DCB - 1) / DCB)         // 782
// src stream buckets
#define SSH 8
#define SCB 256
#define SNB ((NN + SCB - 1) / SCB)         // 391

#define CHUNK 8192
#define NBLK ((NE + CHUNK - 1) / CHUNK)    // 391
#define HLD (DNB * NBLK)                   // 305,762
#define HLS (SNB * NBLK)                   // 152,881
#define HLT (HLD + HLS)                    // 458,643

#define GCH 1024
#define NSC ((HLT + GCH - 1) / GCH)        // 448

#define POOL 4608                          // fine-sort staging (18KB LDS)

__device__ __forceinline__ unsigned short f2bf(float f) {  // round-nearest-even
  unsigned u = __float_as_uint(f);
  u = (u + 0x7FFFu + ((u >> 16) & 1u)) >> 16;
  return (unsigned short)u;
}

// accumulate 8 bf16 (one uint4) into 8 f32
__device__ __forceinline__ void acc8(float* a, const uint4& u) {
  a[0] += __uint_as_float(u.x << 16);
  a[1] += __uint_as_float(u.x & 0xFFFF0000u);
  a[2] += __uint_as_float(u.y << 16);
  a[3] += __uint_as_float(u.y & 0xFFFF0000u);
  a[4] += __uint_as_float(u.z << 16);
  a[5] += __uint_as_float(u.z & 0xFFFF0000u);
  a[6] += __uint_as_float(u.w << 16);
  a[7] += __uint_as_float(u.w & 0xFFFF0000u);
}

// bijective XCD swizzle (m204 variant): consecutive swizzled ids -> same XCD
__device__ __forceinline__ int xcd_swz(int orig, int n) {
  int q = n / 8, r = n % 8;
  int xcd = orig % 8, idx = orig / 8;
  return (xcd < r ? xcd * (q + 1) : r * (q + 1) + (xcd - r) * q) + idx;
}

// ------ A: dual coarse histogram (dst>>7 and src>>8, LDS only) --------------
__global__ __launch_bounds__(TPBW) void k_hist(const int* __restrict__ src,
                                               const int* __restrict__ dst,
                                               int* __restrict__ H) {
  __shared__ int hd[DNB], hs[SNB];
  int t = threadIdx.x, k = blockIdx.x;
  for (int b = t; b < DNB; b += TPBW) hd[b] = 0;
  for (int b = t; b < SNB; b += TPBW) hs[b] = 0;
  __syncthreads();
  int beg = k * CHUNK, end = min(NE, beg + CHUNK);
  for (int i = beg + t; i < end; i += TPBW) {
    atomicAdd(&hd[dst[i] >> DSH], 1);
    atomicAdd(&hs[src[i] >> SSH], 1);
  }
  __syncthreads();
  for (int b = t; b < DNB; b += TPBW) H[b * NBLK + k] = hd[b];
  for (int b = t; b < SNB; b += TPBW) H[HLD + b * NBLK + k] = hs[b];
}

// ------ B: scan. g_scan1 reduces per 1024-chunk; g_scan3 scans in-place
// (each block redundantly scans the raw bsums to get its prefix). ------------
__global__ __launch_bounds__(TPB) void g_scan1(const int* __restrict__ a,
                                               int* __restrict__ bsums) {
  int t = threadIdx.x;
  int base = blockIdx.x * GCH + t * 4;
  int s = 0;
#pragma unroll
  for (int j = 0; j < 4; ++j) { int idx = base + j; if (idx < HLT) s += a[idx]; }
  __shared__ int red[TPB];
  red[t] = s; __syncthreads();
  for (int off = TPB / 2; off > 0; off >>= 1) {
    if (t < off) red[t] += red[t + off];
    __syncthreads();
  }
  if (t == 0) bsums[blockIdx.x] = red[0];
}

__global__ __launch_bounds__(TPB) void g_scan3(int* __restrict__ a,
                                               const int* __restrict__ bsums) {
  __shared__ int lds[TPB];
  __shared__ int sc[512];
  int t = threadIdx.x;
  // local scan of RAW bsums -> this block's exclusive prefix
  {
    int i0 = 2 * t, i1 = 2 * t + 1;
    int v0 = (i0 < NSC) ? bsums[i0] : 0;
    int v1 = (i1 < NSC) ? bsums[i1] : 0;
    int s2 = v0 + v1;
    int acc = s2; lds[t] = acc; __syncthreads();
    for (int off = 1; off < TPB; off <<= 1) {
      int add = (t >= off) ? lds[t - off] : 0; __syncthreads();
      acc += add; lds[t] = acc; __syncthreads();
    }
    int excl = acc - s2;
    sc[i0] = excl;
    sc[i1] = excl + v0;
  }
  __syncthreads();
  int pref = sc[blockIdx.x];
  __syncthreads();                       // lds reused below
  int base = blockIdx.x * GCH + t * 4;
  int v[4]; int s = 0;
#pragma unroll
  for (int j = 0; j < 4; ++j) {
    int idx = base + j;
    v[j] = (idx < HLT) ? a[idx] : 0;
    s += v[j];
  }
  int acc = s; lds[t] = acc; __syncthreads();
  for (int off = 1; off < TPB; off <<= 1) {
    int add = (t >= off) ? lds[t - off] : 0; __syncthreads();
    acc += add; lds[t] = acc; __syncthreads();
  }
  int run = pref + (acc - s);
#pragma unroll
  for (int j = 0; j < 4; ++j) {
    int idx = base + j;
    if (idx < HLT) a[idx] = run;  // in-place exclusive
    run += v[j];
  }
}

// ------ C: perm-staged dual scatter; bases from Hsc diffs (no histogram) ----
__global__ __launch_bounds__(TPBS) void k_scatter(const int* __restrict__ src,
                                                  const int* __restrict__ dst,
                                                  const int* __restrict__ Hsc,
                                                  int* __restrict__ packed,
                                                  unsigned char* __restrict__ ss) {
  __shared__ unsigned short perm_d[CHUNK];       // 16KB
  __shared__ unsigned short perm_s[CHUNK];       // 16KB
  __shared__ int curD[DNB], adjD[DNB];           // 6.3KB
  __shared__ int curS[SNB], adjS[SNB];           // 3.2KB
  __shared__ int scanbuf[TPBS];                  // 4KB
  int t = threadIdx.x;
  int k = xcd_swz((int)blockIdx.x, NBLK);        // adjacent chunks -> same XCD
  int beg = k * CHUNK, end = min(NE, beg + CHUNK);
  int cnt = end - beg;

  // dst-stream: count from Hsc linear diff; local scan -> base; adj = start-base
  {
    int st = 0, c = 0;
    if (t < DNB) {
      int idx = t * NBLK + k;
      st = Hsc[idx];
      int en = (idx + 1 < HLT) ? Hsc[idx + 1] : 2 * NE;
      c = en - st;
    }
    int acc = c; scanbuf[t] = acc; __syncthreads();
    for (int off = 1; off < TPBS; off <<= 1) {
      int add = (t >= off) ? scanbuf[t - off] : 0; __syncthreads();
      acc += add; scanbuf[t] = acc; __syncthreads();
    }
    int excl = acc - c;
    if (t < DNB) { curD[t] = excl; adjD[t] = st - excl; }
  }
  __syncthreads();
  // src-stream (addresses are used minus NE)
  {
    int st = 0, c = 0;
    if (t < SNB) {
      int idx = HLD + t * NBLK + k;
      st = Hsc[idx];
      int en = (idx + 1 < HLT) ? Hsc[idx + 1] : 2 * NE;
      c = en - st;
    }
    int acc = c; scanbuf[t] = acc; __syncthreads();
    for (int off = 1; off < TPBS; off <<= 1) {
      int add = (t >= off) ? scanbuf[t - off] : 0; __syncthreads();
      acc += add; scanbuf[t] = acc; __syncthreads();
    }
    int excl = acc - c;
    if (t < SNB) { curS[t] = excl; adjS[t] = (st - NE) - excl; }
  }
  __syncthreads();

  // stage permutations (local edge index; coalesced src/dst reads)
  for (int i = beg + t; i < end; i += TPBS) {
    int s = src[i], d = dst[i];
    int li = i - beg;
    int p = atomicAdd(&curD[d >> DSH], 1);
    perm_d[p] = (unsigned short)li;
    int q = atomicAdd(&curS[s >> SSH], 1);
    perm_s[q] = (unsigned short)li;
  }
  __syncthreads();

  // burst flush: bucket from re-read value (L1-hot 64KB window); address =
  // adj[bkt] + i; consecutive i in a run -> consecutive global addresses.
  for (int i = t; i < cnt; i += TPBS) {
    int gi = beg + perm_d[i];
    int d = dst[gi], s = src[gi];
    packed[adjD[d >> DSH] + i] = (s << DSH) | (d & (DCB - 1));
  }
  for (int i = t; i < cnt; i += TPBS) {
    int s = src[beg + perm_s[i]];
    ss[adjS[s >> SSH] + i] = (unsigned char)(s & (SCB - 1));
  }
}

// ------ D+E fused: fine counting sort (dst) | fine count (src) --------------
__global__ __launch_bounds__(TPB) void k_fine(const int* __restrict__ Hsc,
                                              const int* __restrict__ packed,
                                              const unsigned char* __restrict__ ss,
                                              int* __restrict__ src_sorted,
                                              int* __restrict__ row_ptr,
                                              float* __restrict__ norm_in,
                                              float* __restrict__ norm_out) {
  __shared__ int hist[DCB], scn[DCB], cur[DCB];
  __shared__ int pool[POOL];
  __shared__ int histS[SCB];
  int t = threadIdx.x;
  if (blockIdx.x < DNB) {
    int b = blockIdx.x;
    int seg_beg = Hsc[b * NBLK];
    int seg_end = (b + 1 < DNB) ? Hsc[(b + 1) * NBLK] : NE;
    int cnt = seg_end - seg_beg;
    if (t < DCB) hist[t] = 0;
    __syncthreads();
    for (int i = seg_beg + t; i < seg_end; i += TPB)
      atomicAdd(&hist[packed[i] & (DCB - 1)], 1);
    __syncthreads();
    if (t < DCB) scn[t] = hist[t];
    __syncthreads();
    for (int off = 1; off < DCB; off <<= 1) {   // Hillis-Steele, 128 bins
      int add = (t >= off && t < DCB) ? scn[t - off] : 0;
      __syncthreads();
      if (t < DCB) scn[t] += add;
      __syncthreads();
    }
    if (t < DCB) {
      int excl = scn[t] - hist[t];
      cur[t] = excl;
      int node = b * DCB + t;
      if (node < NN) {
        row_ptr[node] = seg_beg + excl;
        norm_in[node] = (hist[t] > 0) ? rsqrtf((float)hist[t]) : 0.0f;
      }
    }
    if (b == DNB - 1 && t == 0) row_ptr[NN] = NE;
    __syncthreads();
    for (int i = seg_beg + t; i < seg_end; i += TPB) {
      int v = packed[i];
      int p = atomicAdd(&cur[v & (DCB - 1)], 1);
      int sv = v >> DSH;
      if (p < POOL) pool[p] = sv;
      else src_sorted[seg_beg + p] = sv;               // overflow fallback (rare)
    }
    __syncthreads();
    int lim = min(cnt, POOL);
    for (int i = t; i < lim; i += TPB) src_sorted[seg_beg + i] = pool[i];
  } else {
    int b = blockIdx.x - DNB;                          // src fine count
    int seg_beg = Hsc[HLD + b * NBLK] - NE;
    int seg_end = (b + 1 < SNB) ? Hsc[HLD + (b + 1) * NBLK] - NE : NE;
    if (t < SCB) histS[t] = 0;
    __syncthreads();
    for (int i = seg_beg + t; i < seg_end; i += TPB)
      atomicAdd(&histS[ss[i]], 1);
    __syncthreads();
    if (t < SCB) {
      int node = b * SCB + t;
      if (node < NN)
        norm_out[node] = (histS[t] > 0) ? rsqrtf((float)histS[t]) : 0.0f;
    }
  }
}

// ------ GEMM1: xt_b[n] = bf16( norm_out[n] * (x[n] @ W1) )  [64 -> 64] ------
__global__ __launch_bounds__(TPB) void k_gemm1(const float4* __restrict__ x4,
                                               const float* __restrict__ W1,
                                               const float* __restrict__ norm_out,
                                               unsigned short* __restrict__ xt_b) {
  int lane = threadIdx.x & 63;
  int wid = (blockIdx.x * TPB + threadIdx.x) >> 6;
  int nwaves = gridDim.x * (TPB / 64);
  float w[64];
#pragma unroll
  for (int k = 0; k < 64; ++k) w[k] = W1[k * 64 + lane];
  int m = lane >> 4, q = lane & 15;
  for (int grp = wid; grp < NN / 4; grp += nwaves) {
    int nbase = grp * 4;
    float4 rv = x4[(nbase + m) * 16 + q];
    int r0 = __float_as_int(rv.x), r1 = __float_as_int(rv.y);
    int r2 = __float_as_int(rv.z), r3 = __float_as_int(rv.w);
    float acc[4] = {0.f, 0.f, 0.f, 0.f};
#pragma unroll
    for (int mm = 0; mm < 4; ++mm) {
#pragma unroll
      for (int ql = 0; ql < 16; ++ql) {
        int sl = mm * 16 + ql;
        acc[mm] = fmaf(__int_as_float(__builtin_amdgcn_readlane(r0, sl)), w[ql * 4 + 0], acc[mm]);
        acc[mm] = fmaf(__int_as_float(__builtin_amdgcn_readlane(r1, sl)), w[ql * 4 + 1], acc[mm]);
        acc[mm] = fmaf(__int_as_float(__builtin_amdgcn_readlane(r2, sl)), w[ql * 4 + 2], acc[mm]);
        acc[mm] = fmaf(__int_as_float(__builtin_amdgcn_readlane(r3, sl)), w[ql * 4 + 3], acc[mm]);
      }
    }
#pragma unroll
    for (int mm = 0; mm < 4; ++mm) {
      int n = nbase + mm;
      xt_b[n * 64 + lane] = f2bf(norm_out[n] * acc[mm]);  // 128B/row coalesced
    }
  }
}

// -- AGG1 (r7 lean, bf16 out): h1_b[n] = bf16(relu(norm_in*segsum(xt_b[src])+b1))
__global__ __launch_bounds__(TPB) void k_agg1(const uint4* __restrict__ xt4,
                                              const int* __restrict__ src_sorted,
                                              const int* __restrict__ row_ptr,
                                              const float* __restrict__ norm_in,
                                              const float* __restrict__ b1,
                                              uint4* __restrict__ h1_b4) {
  int node = (blockIdx.x * TPB + threadIdx.x) >> 6;
  int lane = threadIdx.x & 63;
  int slot = lane >> 3;  // 0..7 edge slots
  int fl = lane & 7;     // uint4 index within 128B row
  int beg = row_ptr[node];
  int end = row_ptr[node + 1];
  float a[8] = {0.f, 0.f, 0.f, 0.f, 0.f, 0.f, 0.f, 0.f};
  int e = beg + slot;
  for (; e + 8 < end; e += 16) {               // lean 2-deep (r7-proven)
    int s0 = src_sorted[e];
    int s1 = src_sorted[e + 8];
    uint4 u0 = xt4[s0 * 8 + fl];
    uint4 u1 = xt4[s1 * 8 + fl];
    acc8(a, u0);
    acc8(a, u1);
  }
  if (e < end) {
    uint4 u0 = xt4[src_sorted[e] * 8 + fl];
    acc8(a, u0);
  }
#pragma unroll
  for (int off = 8; off <= 32; off <<= 1) {
#pragma unroll
    for (int j = 0; j < 8; ++j) a[j] += __shfl_xor(a[j], off);
  }
  if (slot == 0) {
    float ni = norm_in[node];
    const float4* b1_4 = reinterpret_cast<const float4*>(b1);
    float4 bl = b1_4[fl * 2];
    float4 bh = b1_4[fl * 2 + 1];
    float v0 = fmaxf(fmaf(a[0], ni, bl.x), 0.f);
    float v1 = fmaxf(fmaf(a[1], ni, bl.y), 0.f);
    float v2 = fmaxf(fmaf(a[2], ni, bl.z), 0.f);
    float v3 = fmaxf(fmaf(a[3], ni, bl.w), 0.f);
    float v4 = fmaxf(fmaf(a[4], ni, bh.x), 0.f);
    float v5 = fmaxf(fmaf(a[5], ni, bh.y), 0.f);
    float v6 = fmaxf(fmaf(a[6], ni, bh.z), 0.f);
    float v7 = fmaxf(fmaf(a[7], ni, bh.w), 0.f);
    uint4 o;
    o.x = (unsigned)f2bf(v0) | ((unsigned)f2bf(v1) << 16);
    o.y = (unsigned)f2bf(v2) | ((unsigned)f2bf(v3) << 16);
    o.z = (unsigned)f2bf(v4) | ((unsigned)f2bf(v5) << 16);
    o.w = (unsigned)f2bf(v6) | ((unsigned)f2bf(v7) << 16);
    h1_b4[node * 8 + fl] = o;                  // 128B/node coalesced
  }
}

// -- GEMM2b: h1t_b[n][0:32] = bf16(norm_out[n]*(h1_b[n] @ W2)); bf16 in -----
__global__ __launch_bounds__(TPB) void k_gemm2b(const uint4* __restrict__ h1b4,
                                                const float* __restrict__ W2,
                                                const float* __restrict__ norm_out,
                                                unsigned short* __restrict__ h1t_b) {
  int lane = threadIdx.x & 63;
  int wid = (blockIdx.x * TPB + threadIdx.x) >> 6;
  int nwaves = gridDim.x * (TPB / 64);
  int oc = lane & 31;
  float w[64];
#pragma unroll
  for (int k = 0; k < 64; ++k)
    w[k] = (oc < NOUTF) ? W2[k * NOUTF + oc] : 0.f;
  int r = lane >> 3, q = lane & 7;
  for (int grp = wid; grp < NN / 8; grp += nwaves) {
    int nbase = grp * 8;
    uint4 rv = h1b4[(nbase + r) * 8 + q];      // 1KB: 8 rows of 128B
    int v0 = (int)rv.x, v1 = (int)rv.y, v2 = (int)rv.z, v3 = (int)rv.w;
#pragma unroll
    for (int rr = 0; rr < 8; ++rr) {
      float acc0 = 0.f, acc1 = 0.f;
#pragma unroll
      for (int qq = 0; qq < 8; ++qq) {
        int sl = rr * 8 + qq;
        unsigned u0 = (unsigned)__builtin_amdgcn_readlane(v0, sl);
        unsigned u1 = (unsigned)__builtin_amdgcn_readlane(v1, sl);
        unsigned u2 = (unsigned)__builtin_amdgcn_readlane(v2, sl);
        unsigned u3 = (unsigned)__builtin_amdgcn_readlane(v3, sl);
        acc0 = fmaf(__uint_as_float(u0 << 16),          w[qq * 8 + 0], acc0);
        acc1 = fmaf(__uint_as_float(u0 & 0xFFFF0000u), w[qq * 8 + 1], acc1);
        acc0 = fmaf(__uint_as_float(u1 << 16),          w[qq * 8 + 2], acc0);
        acc1 = fmaf(__uint_as_float(u1 & 0xFFFF0000u), w[qq * 8 + 3], acc1);
        acc0 = fmaf(__uint_as_float(u2 << 16),          w[qq * 8 + 4], acc0);
        acc1 = fmaf(__uint_as_float(u2 & 0xFFFF0000u), w[qq * 8 + 5], acc1);
        acc0 = fmaf(__uint_as_float(u3 << 16),          w[qq * 8 + 6], acc0);
        acc1 = fmaf(__uint_as_float(u3 & 0xFFFF0000u), w[qq * 8 + 7], acc1);
      }
      int n = nbase + rr;
      if (lane < 32) {
        float acc = acc0 + acc1;
        unsigned short hv = (oc < NOUTF) ? f2bf(norm_out[n] * acc) : (unsigned short)0;
        h1t_b[n * 32 + oc] = hv;               // 64B/node coalesced
      }
    }
  }
}

// -- AGG2: out[n] = norm_in[n]*segsum(h1t_b[src]) + b2; bf16 in, f32 out -----
__global__ __launch_bounds__(TPB) void k_agg2(const uint4* __restrict__ h1t4,
                                              const int* __restrict__ src_sorted,
                                              const int* __restrict__ row_ptr,
                                              const float* __restrict__ norm_in,
                                              const float* __restrict__ b2,
                                              float* __restrict__ out) {
  int node = (blockIdx.x * TPB + threadIdx.x) >> 6;
  int lane = threadIdx.x & 63;
  int slot = lane >> 2;  // 0..15
  int fl = lane & 3;     // uint4 index within 64B row
  int beg = row_ptr[node];
  int end = row_ptr[node + 1];
  float a[8] = {0.f, 0.f, 0.f, 0.f, 0.f, 0.f, 0.f, 0.f};
  int e = beg + slot;
  for (; e + 16 < end; e += 32) {
    int s0 = src_sorted[e];
    int s1 = src_sorted[e + 16];
    uint4 u0 = h1t4[s0 * 4 + fl];
    uint4 u1 = h1t4[s1 * 4 + fl];
    acc8(a, u0);
    acc8(a, u1);
  }
  if (e < end) {
    uint4 u0 = h1t4[src_sorted[e] * 4 + fl];
    acc8(a, u0);
  }
#pragma unroll
  for (int off = 4; off <= 32; off <<= 1) {
#pragma unroll
    for (int j = 0; j < 8; ++j) a[j] += __shfl_xor(a[j], off);
  }
  if (slot == 0) {
    float ni = norm_in[node];
    int f0 = fl * 8;
    float2* ob = (float2*)(out + (size_t)node * NOUTF);  // rows 120B, 8B-aligned
#pragma unroll
    for (int p = 0; p < 4; ++p) {
      int f = f0 + p * 2;
      if (f < NOUTF) {
        float2 v;
        v.x = fmaf(a[p * 2], ni, b2[f]);
        v.y = fmaf(a[p * 2 + 1], ni, b2[f + 1]);
        ob[f >> 1] = v;
      }
    }
  }
}

extern "C" void kernel_launch(void* const* d_in, const int* in_sizes, int n_in,
                              void* d_out, int out_size, void* d_ws, size_t ws_size,
                              hipStream_t stream) {
  (void)in_sizes; (void)n_in; (void)out_size; (void)ws_size;
  const float* x = (const float*)d_in[0];
  const int* src = (const int*)d_in[1];
  const int* dst = (const int*)d_in[2];
  const float* W1 = (const float*)d_in[3];
  const float* b1 = (const float*)d_in[4];
  const float* W2 = (const float*)d_in[5];
  const float* b2 = (const float*)d_in[6];
  float* out = (float*)d_out;

  // Workspace layout (bytes); offsets 16B-aligned (identical to r15).
  // packed (12.8MB) dead after k_fine -> h1_b (12.8MB bf16) aliases it.
  // xt_b (12.8MB) dead after k_agg1 -> h1t_b (6.4MB bf16) aliases its base.
  char* ws = (char*)d_ws;
  int* row_ptr = (int*)(ws + 0);                           //    400,128
  float* norm_out = (float*)(ws + 400128);                 //    400,000
  float* norm_in = (float*)(ws + 800128);                  //    400,000
  int* H = (int*)(ws + 1200128);                           //  1,834,572 used
  int* bsums = (int*)(ws + 3100128);                       //      1,792 (NSC ints)
  unsigned char* ss = (unsigned char*)(ws + 3101952);      //  3,200,000
  int* src_sorted = (int*)(ws + 8365696);                  // 12,800,000
  int* packed = (int*)(ws + 21165696);                     // 12,800,000
  uint4* h1_b4 = (uint4*)(ws + 21165696);                  // 12,800,000 (aliases packed)
  unsigned short* xt_b = (unsigned short*)(ws + 46765696); // 12,800,000
  unsigned short* h1t_b = (unsigned short*)(ws + 46765696);// 6,400,000 (aliases xt_b)

  k_hist<<<NBLK, TPBW, 0, stream>>>(src, dst, H);
  g_scan1<<<NSC, TPB, 0, stream>>>(H, bsums);
  g_scan3<<<NSC, TPB, 0, stream>>>(H, bsums);
  k_scatter<<<NBLK, TPBS, 0, stream>>>(src, dst, H, packed, ss);
  k_fine<<<DNB + SNB, TPB, 0, stream>>>(H, packed, ss, src_sorted, row_ptr, norm_in, norm_out);
  k_gemm1<<<1024, TPB, 0, stream>>>((const float4*)x, W1, norm_out, xt_b);
  k_agg1<<<NN / 4, TPB, 0, stream>>>((const uint4*)xt_b, src_sorted, row_ptr,
                                     norm_in, b1, h1_b4);
  k_gemm2b<<<1024, TPB, 0, stream>>>((const uint4*)h1_b4, W2, norm_out, h1t_b);
  k_agg2<<<NN / 4, TPB, 0, stream>>>((const uint4*)h1t_b, src_sorted, row_ptr, norm_in, b2, out);
}

// Round 17
// 224.396 us; speedup vs baseline: 1.2990x; 1.0327x over previous
//
#include <hip/hip_runtime.h>

// GCN 2-layer, round 17: fully-streaming CSR build.
//  - k_scatter stages VALUES in LDS (payload+bucket for dst, full src for
//    src stream): flush = LDS read + coalesced-run global write, ZERO
//    scattered global reads (the 64KB chunk window didn't fit 32KB L1).
//    89KB LDS/block (gfx950 allows up to 160KB; m201 used 128KB).
//  - shfl-based block scans (3 barriers) replace 20-barrier Hillis-Steele
//    in scatter and g_scan1/g_scan3.
//  - k_fine reads packed ONCE: bucket staged into the pool during the hist
//    pass, permuted from LDS (overflow fallback kept).
//  - k_hist: int4 loads, 8 contiguous edges/thread.
// Unchanged: lean bf16 gathers (agg1 pinned at 57us L3 line-service floor),
// register-W2 gemm2b, zero global atomics, transform-first identity
// segsum(h[src]) @ W == segsum((h@W)[src]).

#define NN 100000
#define NE 3200000
#define NOUTF 30
#define TPB 256
#define TPBW 1024                          // hist blocks
#define TPBS 1024                          // scatter blocks

// dst stream buckets
#define DSH 7
#define DCB 128
#define DNB ((NN + DCB - 1) / DCB)         // 782
// src stream buckets
#define SSH 8
#define SCB 256
#define SNB ((NN + SCB - 1) / SCB)         // 391

#define CHUNK 8192
#define NBLK ((NE + CHUNK - 1) / CHUNK)    // 391
#define HLD (DNB * NBLK)                   // 305,762
#define HLS (SNB * NBLK)                   // 152,881
#define HLT (HLD + HLS)                    // 458,643

#define GCH 1024
#define NSC ((HLT + GCH - 1) / GCH)        // 448

#define POOL 4608                          // fine-sort staging (18KB LDS)

__device__ __forceinline__ unsigned short f2bf(float f) {  // round-nearest-even
  unsigned u = __float_as_uint(f);
  u = (u + 0x7FFFu + ((u >> 16) & 1u)) >> 16;
  return (unsigned short)u;
}

// accumulate 8 bf16 (one uint4) into 8 f32
__device__ __forceinline__ void acc8(float* a, const uint4& u) {
  a[0] += __uint_as_float(u.x << 16);
  a[1] += __uint_as_float(u.x & 0xFFFF0000u);
  a[2] += __uint_as_float(u.y << 16);
  a[3] += __uint_as_float(u.y & 0xFFFF0000u);
  a[4] += __uint_as_float(u.z << 16);
  a[5] += __uint_as_float(u.z & 0xFFFF0000u);
  a[6] += __uint_as_float(u.w << 16);
  a[7] += __uint_as_float(u.w & 0xFFFF0000u);
}

// bijective XCD swizzle (m204 variant): consecutive swizzled ids -> same XCD
__device__ __forceinline__ int xcd_swz(int orig, int n) {
  int q = n / 8, r = n % 8;
  int xcd = orig % 8, idx = orig / 8;
  return (xcd < r ? xcd * (q + 1) : r * (q + 1) + (xcd - r) * q) + idx;
}

// block-wide exclusive scan via wave shfl + cross-wave LDS (3 barriers)
template <int NT>
__device__ __forceinline__ int blk_exscan(int val, int* wsums, int t) {
  __syncthreads();                         // protect wsums reuse across calls
  int lane = t & 63;
  int inc = val;
#pragma unroll
  for (int off = 1; off < 64; off <<= 1) {
    int n = __shfl_up(inc, off);
    if (lane >= off) inc += n;
  }
  if (lane == 63) wsums[t >> 6] = inc;
  __syncthreads();
  constexpr int NW = NT / 64;
  if (t < NW) {
    int v = wsums[t];
    int acc = v;
#pragma unroll
    for (int off = 1; off < NW; off <<= 1) {
      int n = __shfl_up(acc, off);
      if (t >= off) acc += n;
    }
    wsums[t] = acc - v;                    // exclusive wave base
  }
  __syncthreads();
  return wsums[t >> 6] + inc - val;
}

// ------ A: dual coarse histogram (dst>>7 and src>>8), int4 loads ------------
__global__ __launch_bounds__(TPBW) void k_hist(const int* __restrict__ src,
                                               const int* __restrict__ dst,
                                               int* __restrict__ H) {
  __shared__ int hd[DNB], hs[SNB];
  int t = threadIdx.x, k = blockIdx.x;
  for (int b = t; b < DNB; b += TPBW) hd[b] = 0;
  for (int b = t; b < SNB; b += TPBW) hs[b] = 0;
  __syncthreads();
  int beg = k * CHUNK, end = min(NE, beg + CHUNK);
  int cnt = end - beg;
  int ebase = t * 8;
  if (ebase + 8 <= cnt) {
    const int4* s4 = (const int4*)(src + beg + ebase);
    const int4* d4 = (const int4*)(dst + beg + ebase);
    int4 a0 = s4[0], a1 = s4[1], b0 = d4[0], b1 = d4[1];
    int sv[8] = {a0.x, a0.y, a0.z, a0.w, a1.x, a1.y, a1.z, a1.w};
    int dv[8] = {b0.x, b0.y, b0.z, b0.w, b1.x, b1.y, b1.z, b1.w};
#pragma unroll
    for (int j = 0; j < 8; ++j) {
      atomicAdd(&hd[dv[j] >> DSH], 1);
      atomicAdd(&hs[sv[j] >> SSH], 1);
    }
  } else {
    for (int j = 0; j < 8 && ebase + j < cnt; ++j) {
      int i = beg + ebase + j;
      atomicAdd(&hd[dst[i] >> DSH], 1);
      atomicAdd(&hs[src[i] >> SSH], 1);
    }
  }
  __syncthreads();
  for (int b = t; b < DNB; b += TPBW) H[b * NBLK + k] = hd[b];
  for (int b = t; b < SNB; b += TPBW) H[HLD + b * NBLK + k] = hs[b];
}

// ------ B: scan. g_scan1 reduces per 1024-chunk; g_scan3 scans in-place. ----
__global__ __launch_bounds__(TPB) void g_scan1(const int* __restrict__ a,
                                               int* __restrict__ bsums) {
  int t = threadIdx.x;
  int base = blockIdx.x * GCH + t * 4;
  int s = 0;
#pragma unroll
  for (int j = 0; j < 4; ++j) { int idx = base + j; if (idx < HLT) s += a[idx]; }
#pragma unroll
  for (int off = 32; off >= 1; off >>= 1) s += __shfl_xor(s, off);
  __shared__ int red[4];
  if ((t & 63) == 0) red[t >> 6] = s;
  __syncthreads();
  if (t == 0) bsums[blockIdx.x] = red[0] + red[1] + red[2] + red[3];
}

__global__ __launch_bounds__(TPB) void g_scan3(int* __restrict__ a,
                                               const int* __restrict__ bsums) {
  __shared__ int sc[512];
  __shared__ int wsums[4];
  int t = threadIdx.x;
  // local scan of RAW bsums -> this block's exclusive prefix
  int i0 = 2 * t, i1 = 2 * t + 1;
  int v0 = (i0 < NSC) ? bsums[i0] : 0;
  int v1 = (i1 < NSC) ? bsums[i1] : 0;
  int ex2 = blk_exscan<TPB>(v0 + v1, wsums, t);
  sc[i0] = ex2;
  sc[i1] = ex2 + v0;
  __syncthreads();
  int pref = sc[blockIdx.x];
  int base = blockIdx.x * GCH + t * 4;
  int v[4]; int s = 0;
#pragma unroll
  for (int j = 0; j < 4; ++j) {
    int idx = base + j;
    v[j] = (idx < HLT) ? a[idx] : 0;
    s += v[j];
  }
  int ex = blk_exscan<TPB>(s, wsums, t);
  int run = pref + ex;
#pragma unroll
  for (int j = 0; j < 4; ++j) {
    int idx = base + j;
    if (idx < HLT) a[idx] = run;  // in-place exclusive
    run += v[j];
  }
}

// ------ C: value-staged dual scatter; flush = LDS read + coalesced write ----
__global__ __launch_bounds__(TPBS) void k_scatter(const int* __restrict__ src,
                                                  const int* __restrict__ dst,
                                                  const int* __restrict__ Hsc,
                                                  int* __restrict__ packed,
                                                  unsigned char* __restrict__ ss) {
  __shared__ int pay_lds[CHUNK];                 // 32KB: (s<<DSH)|(d&127), dst order
  __shared__ unsigned short bkt_lds[CHUNK];      // 16KB: dst bucket per slot
  __shared__ int s_lds[CHUNK];                   // 32KB: full src value, src order
  __shared__ int curD[DNB], adjD[DNB];           // 6.3KB
  __shared__ int curS[SNB], adjS[SNB];           // 3.1KB
  __shared__ int wsums[16];
  int t = threadIdx.x;
  int k = xcd_swz((int)blockIdx.x, NBLK);        // adjacent chunks -> same XCD
  int beg = k * CHUNK, end = min(NE, beg + CHUNK);
  int cnt = end - beg;

  // per-(bucket,chunk) counts from Hsc linear diffs; local bases via shfl scan
  int stD = 0, cD = 0;
  if (t < DNB) {
    int idx = t * NBLK + k;
    stD = Hsc[idx];
    int en = (idx + 1 < HLT) ? Hsc[idx + 1] : 2 * NE;
    cD = en - stD;
  }
  int exD = blk_exscan<TPBS>(cD, wsums, t);
  if (t < DNB) { curD[t] = exD; adjD[t] = stD - exD; }
  int stS = 0, cS = 0;
  if (t < SNB) {
    int idx = HLD + t * NBLK + k;
    stS = Hsc[idx];
    int en = (idx + 1 < HLT) ? Hsc[idx + 1] : 2 * NE;
    cS = en - stS;
  }
  int exS = blk_exscan<TPBS>(cS, wsums, t);
  if (t < SNB) { curS[t] = exS; adjS[t] = (stS - NE) - exS; }
  __syncthreads();

  // stage: 8 contiguous edges/thread (int4 loads), values into LDS
  int ebase = t * 8;
  if (ebase < cnt) {
    int sv[8], dv[8];
    int nv;
    if (ebase + 8 <= cnt) {
      const int4* s4 = (const int4*)(src + beg + ebase);
      const int4* d4 = (const int4*)(dst + beg + ebase);
      int4 a0 = s4[0], a1 = s4[1], b0 = d4[0], b1 = d4[1];
      sv[0] = a0.x; sv[1] = a0.y; sv[2] = a0.z; sv[3] = a0.w;
      sv[4] = a1.x; sv[5] = a1.y; sv[6] = a1.z; sv[7] = a1.w;
      dv[0] = b0.x; dv[1] = b0.y; dv[2] = b0.z; dv[3] = b0.w;
      dv[4] = b1.x; dv[5] = b1.y; dv[6] = b1.z; dv[7] = b1.w;
      nv = 8;
    } else {
      nv = cnt - ebase;
      for (int j = 0; j < nv; ++j) { sv[j] = src[beg + ebase + j]; dv[j] = dst[beg + ebase + j]; }
    }
    for (int j = 0; j < nv; ++j) {
      int bk = dv[j] >> DSH;
      int p = atomicAdd(&curD[bk], 1);
      pay_lds[p] = (sv[j] << DSH) | (dv[j] & (DCB - 1));
      bkt_lds[p] = (unsigned short)bk;
      int q = atomicAdd(&curS[sv[j] >> SSH], 1);
      s_lds[q] = sv[j];
    }
  }
  __syncthreads();

  // flush: pure LDS reads + coalesced bucket-run global writes
  for (int i = t; i < cnt; i += TPBS)
    packed[adjD[bkt_lds[i]] + i] = pay_lds[i];
  for (int i = t; i < cnt; i += TPBS) {
    int s = s_lds[i];
    ss[adjS[s >> SSH] + i] = (unsigned char)(s & (SCB - 1));
  }
}

// ------ D+E fused: fine counting sort (dst, single packed read) | fine count
__global__ __launch_bounds__(TPB) void k_fine(const int* __restrict__ Hsc,
                                              const int* __restrict__ packed,
                                              const unsigned char* __restrict__ ss,
                                              int* __restrict__ src_sorted,
                                              int* __restrict__ row_ptr,
                                              float* __restrict__ norm_in,
                                              float* __restrict__ norm_out) {
  __shared__ int hist[DCB], scn[DCB], cur[DCB];
  __shared__ int pool[POOL];
  __shared__ int histS[SCB];
  int t = threadIdx.x;
  if (blockIdx.x < DNB) {
    int b = blockIdx.x;
    int seg_beg = Hsc[b * NBLK];
    int seg_end = (b + 1 < DNB) ? Hsc[(b + 1) * NBLK] : NE;
    int cnt = seg_end - seg_beg;
    int lim = min(cnt, POOL);
    if (t < DCB) hist[t] = 0;
    __syncthreads();
    for (int i = t; i < lim; i += TPB) {         // stage + hist in one pass
      int v = packed[seg_beg + i];
      pool[i] = v;
      atomicAdd(&hist[v & (DCB - 1)], 1);
    }
    for (int i = lim + t; i < cnt; i += TPB)     // overflow (rare)
      atomicAdd(&hist[packed[seg_beg + i] & (DCB - 1)], 1);
    __syncthreads();
    if (t < DCB) scn[t] = hist[t];
    __syncthreads();
    for (int off = 1; off < DCB; off <<= 1) {    // Hillis-Steele, 128 bins
      int add = (t >= off && t < DCB) ? scn[t - off] : 0;
      __syncthreads();
      if (t < DCB) scn[t] += add;
      __syncthreads();
    }
    if (t < DCB) {
      int excl = scn[t] - hist[t];
      cur[t] = excl;
      int node = b * DCB + t;
      if (node < NN) {
        row_ptr[node] = seg_beg + excl;
        norm_in[node] = (hist[t] > 0) ? rsqrtf((float)hist[t]) : 0.0f;
      }
    }
    if (b == DNB - 1 && t == 0) row_ptr[NN] = NE;
    __syncthreads();
    for (int i = t; i < lim; i += TPB) {         // permute from LDS
      int v = pool[i];
      int p = atomicAdd(&cur[v & (DCB - 1)], 1);
      src_sorted[seg_beg + p] = v >> DSH;        // dense 16KB window
    }
    for (int i = lim + t; i < cnt; i += TPB) {   // overflow from global
      int v = packed[seg_beg + i];
      int p = atomicAdd(&cur[v & (DCB - 1)], 1);
      src_sorted[seg_beg + p] = v >> DSH;
    }
  } else {
    int b = blockIdx.x - DNB;                    // src fine count
    int seg_beg = Hsc[HLD + b * NBLK] - NE;
    int seg_end = (b + 1 < SNB) ? Hsc[HLD + (b + 1) * NBLK] - NE : NE;
    if (t < SCB) histS[t] = 0;
    __syncthreads();
    for (int i = seg_beg + t; i < seg_end; i += TPB)
      atomicAdd(&histS[ss[i]], 1);
    __syncthreads();
    if (t < SCB) {
      int node = b * SCB + t;
      if (node < NN)
        norm_out[node] = (histS[t] > 0) ? rsqrtf((float)histS[t]) : 0.0f;
    }
  }
}

// ------ GEMM1: xt_b[n] = bf16( norm_out[n] * (x[n] @ W1) )  [64 -> 64] ------
__global__ __launch_bounds__(TPB) void k_gemm1(const float4* __restrict__ x4,
                                               const float* __restrict__ W1,
                                               const float* __restrict__ norm_out,
                                               unsigned short* __restrict__ xt_b) {
  int lane = threadIdx.x & 63;
  int wid = (blockIdx.x * TPB + threadIdx.x) >> 6;
  int nwaves = gridDim.x * (TPB / 64);
  float w[64];
#pragma unroll
  for (int k = 0; k < 64; ++k) w[k] = W1[k * 64 + lane];
  int m = lane >> 4, q = lane & 15;
  for (int grp = wid; grp < NN / 4; grp += nwaves) {
    int nbase = grp * 4;
    float4 rv = x4[(nbase + m) * 16 + q];
    int r0 = __float_as_int(rv.x), r1 = __float_as_int(rv.y);
    int r2 = __float_as_int(rv.z), r3 = __float_as_int(rv.w);
    float acc[4] = {0.f, 0.f, 0.f, 0.f};
#pragma unroll
    for (int mm = 0; mm < 4; ++mm) {
#pragma unroll
      for (int ql = 0; ql < 16; ++ql) {
        int sl = mm * 16 + ql;
        acc[mm] = fmaf(__int_as_float(__builtin_amdgcn_readlane(r0, sl)), w[ql * 4 + 0], acc[mm]);
        acc[mm] = fmaf(__int_as_float(__builtin_amdgcn_readlane(r1, sl)), w[ql * 4 + 1], acc[mm]);
        acc[mm] = fmaf(__int_as_float(__builtin_amdgcn_readlane(r2, sl)), w[ql * 4 + 2], acc[mm]);
        acc[mm] = fmaf(__int_as_float(__builtin_amdgcn_readlane(r3, sl)), w[ql * 4 + 3], acc[mm]);
      }
    }
#pragma unroll
    for (int mm = 0; mm < 4; ++mm) {
      int n = nbase + mm;
      xt_b[n * 64 + lane] = f2bf(norm_out[n] * acc[mm]);  // 128B/row coalesced
    }
  }
}

// -- AGG1 (r7 lean, bf16 out): h1_b[n] = bf16(relu(norm_in*segsum(xt_b[src])+b1))
__global__ __launch_bounds__(TPB) void k_agg1(const uint4* __restrict__ xt4,
                                              const int* __restrict__ src_sorted,
                                              const int* __restrict__ row_ptr,
                                              const float* __restrict__ norm_in,
                                              const float* __restrict__ b1,
                                              uint4* __restrict__ h1_b4) {
  int node = (blockIdx.x * TPB + threadIdx.x) >> 6;
  int lane = threadIdx.x & 63;
  int slot = lane >> 3;  // 0..7 edge slots
  int fl = lane & 7;     // uint4 index within 128B row
  int beg = row_ptr[node];
  int end = row_ptr[node + 1];
  float a[8] = {0.f, 0.f, 0.f, 0.f, 0.f, 0.f, 0.f, 0.f};
  int e = beg + slot;
  for (; e + 8 < end; e += 16) {               // lean 2-deep (r7-proven)
    int s0 = src_sorted[e];
    int s1 = src_sorted[e + 8];
    uint4 u0 = xt4[s0 * 8 + fl];
    uint4 u1 = xt4[s1 * 8 + fl];
    acc8(a, u0);
    acc8(a, u1);
  }
  if (e < end) {
    uint4 u0 = xt4[src_sorted[e] * 8 + fl];
    acc8(a, u0);
  }
#pragma unroll
  for (int off = 8; off <= 32; off <<= 1) {
#pragma unroll
    for (int j = 0; j < 8; ++j) a[j] += __shfl_xor(a[j], off);
  }
  if (slot == 0) {
    float ni = norm_in[node];
    const float4* b1_4 = reinterpret_cast<const float4*>(b1);
    float4 bl = b1_4[fl * 2];
    float4 bh = b1_4[fl * 2 + 1];
    float v0 = fmaxf(fmaf(a[0], ni, bl.x), 0.f);
    float v1 = fmaxf(fmaf(a[1], ni, bl.y), 0.f);
    float v2 = fmaxf(fmaf(a[2], ni, bl.z), 0.f);
    float v3 = fmaxf(fmaf(a[3], ni, bl.w), 0.f);
    float v4 = fmaxf(fmaf(a[4], ni, bh.x), 0.f);
    float v5 = fmaxf(fmaf(a[5], ni, bh.y), 0.f);
    float v6 = fmaxf(fmaf(a[6], ni, bh.z), 0.f);
    float v7 = fmaxf(fmaf(a[7], ni, bh.w), 0.f);
    uint4 o;
    o.x = (unsigned)f2bf(v0) | ((unsigned)f2bf(v1) << 16);
    o.y = (unsigned)f2bf(v2) | ((unsigned)f2bf(v3) << 16);
    o.z = (unsigned)f2bf(v4) | ((unsigned)f2bf(v5) << 16);
    o.w = (unsigned)f2bf(v6) | ((unsigned)f2bf(v7) << 16);
    h1_b4[node * 8 + fl] = o;                  // 128B/node coalesced
  }
}

// -- GEMM2b: h1t_b[n][0:32] = bf16(norm_out[n]*(h1_b[n] @ W2)); bf16 in -----
__global__ __launch_bounds__(TPB) void k_gemm2b(const uint4* __restrict__ h1b4,
                                                const float* __restrict__ W2,
                                                const float* __restrict__ norm_out,
                                                unsigned short* __restrict__ h1t_b) {
  int lane = threadIdx.x & 63;
  int wid = (blockIdx.x * TPB + threadIdx.x) >> 6;
  int nwaves = gridDim.x * (TPB / 64);
  int oc = lane & 31;
  float w[64];
#pragma unroll
  for (int k = 0; k < 64; ++k)
    w[k] = (oc < NOUTF) ? W2[k * NOUTF + oc] : 0.f;
  int r = lane >> 3, q = lane & 7;
  for (int grp = wid; grp < NN / 8; grp += nwaves) {
    int nbase = grp * 8;
    uint4 rv = h1b4[(nbase + r) * 8 + q];      // 1KB: 8 rows of 128B
    int v0 = (int)rv.x, v1 = (int)rv.y, v2 = (int)rv.z, v3 = (int)rv.w;
#pragma unroll
    for (int rr = 0; rr < 8; ++rr) {
      float acc0 = 0.f, acc1 = 0.f;
#pragma unroll
      for (int qq = 0; qq < 8; ++qq) {
        int sl = rr * 8 + qq;
        unsigned u0 = (unsigned)__builtin_amdgcn_readlane(v0, sl);
        unsigned u1 = (unsigned)__builtin_amdgcn_readlane(v1, sl);
        unsigned u2 = (unsigned)__builtin_amdgcn_readlane(v2, sl);
        unsigned u3 = (unsigned)__builtin_amdgcn_readlane(v3, sl);
        acc0 = fmaf(__uint_as_float(u0 << 16),          w[qq * 8 + 0], acc0);
        acc1 = fmaf(__uint_as_float(u0 & 0xFFFF0000u), w[qq * 8 + 1], acc1);
        acc0 = fmaf(__uint_as_float(u1 << 16),          w[qq * 8 + 2], acc0);
        acc1 = fmaf(__uint_as_float(u1 & 0xFFFF0000u), w[qq * 8 + 3], acc1);
        acc0 = fmaf(__uint_as_float(u2 << 16),          w[qq * 8 + 4], acc0);
        acc1 = fmaf(__uint_as_float(u2 & 0xFFFF0000u), w[qq * 8 + 5], acc1);
        acc0 = fmaf(__uint_as_float(u3 << 16),          w[qq * 8 + 6], acc0);
        acc1 = fmaf(__uint_as_float(u3 & 0xFFFF0000u), w[qq * 8 + 7], acc1);
      }
      int n = nbase + rr;
      if (lane < 32) {
        float acc = acc0 + acc1;
        unsigned short hv = (oc < NOUTF) ? f2bf(norm_out[n] * acc) : (unsigned short)0;
        h1t_b[n * 32 + oc] = hv;               // 64B/node coalesced
      }
    }
  }
}

// -- AGG2: out[n] = norm_in[n]*segsum(h1t_b[src]) + b2; bf16 in, f32 out -----
__global__ __launch_bounds__(TPB) void k_agg2(const uint4* __restrict__ h1t4,
                                              const int* __restrict__ src_sorted,
                                              const int* __restrict__ row_ptr,
                                              const float* __restrict__ norm_in,
                                              const float* __restrict__ b2,
                                              float* __restrict__ out) {
  int node = (blockIdx.x * TPB + threadIdx.x) >> 6;
  int lane = threadIdx.x & 63;
  int slot = lane >> 2;  // 0..15
  int fl = lane & 3;     // uint4 index within 64B row
  int beg = row_ptr[node];
  int end = row_ptr[node + 1];
  float a[8] = {0.f, 0.f, 0.f, 0.f, 0.f, 0.f, 0.f, 0.f};
  int e = beg + slot;
  for (; e + 16 < end; e += 32) {
    int s0 = src_sorted[e];
    int s1 = src_sorted[e + 16];
    uint4 u0 = h1t4[s0 * 4 + fl];
    uint4 u1 = h1t4[s1 * 4 + fl];
    acc8(a, u0);
    acc8(a, u1);
  }
  if (e < end) {
    uint4 u0 = h1t4[src_sorted[e] * 4 + fl];
    acc8(a, u0);
  }
#pragma unroll
  for (int off = 4; off <= 32; off <<= 1) {
#pragma unroll
    for (int j = 0; j < 8; ++j) a[j] += __shfl_xor(a[j], off);
  }
  if (slot == 0) {
    float ni = norm_in[node];
    int f0 = fl * 8;
    float2* ob = (float2*)(out + (size_t)node * NOUTF);  // rows 120B, 8B-aligned
#pragma unroll
    for (int p = 0; p < 4; ++p) {
      int f = f0 + p * 2;
      if (f < NOUTF) {
        float2 v;
        v.x = fmaf(a[p * 2], ni, b2[f]);
        v.y = fmaf(a[p * 2 + 1], ni, b2[f + 1]);
        ob[f >> 1] = v;
      }
    }
  }
}

extern "C" void kernel_launch(void* const* d_in, const int* in_sizes, int n_in,
                              void* d_out, int out_size, void* d_ws, size_t ws_size,
                              hipStream_t stream) {
  (void)in_sizes; (void)n_in; (void)out_size; (void)ws_size;
  const float* x = (const float*)d_in[0];
  const int* src = (const int*)d_in[1];
  const int* dst = (const int*)d_in[2];
  const float* W1 = (const float*)d_in[3];
  const float* b1 = (const float*)d_in[4];
  const float* W2 = (const float*)d_in[5];
  const float* b2 = (const float*)d_in[6];
  float* out = (float*)d_out;

  // Workspace layout (bytes); offsets 16B-aligned (identical to r16).
  // packed (12.8MB) dead after k_fine -> h1_b (12.8MB bf16) aliases it.
  // xt_b (12.8MB) dead after k_agg1 -> h1t_b (6.4MB bf16) aliases its base.
  char* ws = (char*)d_ws;
  int* row_ptr = (int*)(ws + 0);                           //    400,128
  float* norm_out = (float*)(ws + 400128);                 //    400,000
  float* norm_in = (float*)(ws + 800128);                  //    400,000
  int* H = (int*)(ws + 1200128);                           //  1,834,572 used
  int* bsums = (int*)(ws + 3100128);                       //      1,792 (NSC ints)
  unsigned char* ss = (unsigned char*)(ws + 3101952);      //  3,200,000
  int* src_sorted = (int*)(ws + 8365696);                  // 12,800,000
  int* packed = (int*)(ws + 21165696);                     // 12,800,000
  uint4* h1_b4 = (uint4*)(ws + 21165696);                  // 12,800,000 (aliases packed)
  unsigned short* xt_b = (unsigned short*)(ws + 46765696); // 12,800,000
  unsigned short* h1t_b = (unsigned short*)(ws + 46765696);// 6,400,000 (aliases xt_b)

  k_hist<<<NBLK, TPBW, 0, stream>>>(src, dst, H);
  g_scan1<<<NSC, TPB, 0, stream>>>(H, bsums);
  g_scan3<<<NSC, TPB, 0, stream>>>(H, bsums);
  k_scatter<<<NBLK, TPBS, 0, stream>>>(src, dst, H, packed, ss);
  k_fine<<<DNB + SNB, TPB, 0, stream>>>(H, packed, ss, src_sorted, row_ptr, norm_in, norm_out);
  k_gemm1<<<1024, TPB, 0, stream>>>((const float4*)x, W1, norm_out, xt_b);
  k_agg1<<<NN / 4, TPB, 0, stream>>>((const uint4*)xt_b, src_sorted, row_ptr,
                                     norm_in, b1, h1_b4);
  k_gemm2b<<<1024, TPB, 0, stream>>>((const uint4*)h1_b4, W2, norm_out, h1t_b);
  k_agg2<<<NN / 4, TPB, 0, stream>>>((const uint4*)h1t_b, src_sorted, row_ptr, norm_in, b2, out);
}

// Round 18
// 221.420 us; speedup vs baseline: 1.3164x; 1.0134x over previous
//
#include <hip/hip_runtime.h>

// GCN 2-layer, round 18: scatter LDS diet -> 2 blocks/CU.
// r17 scatter used ~90KB LDS (1 block/CU, 16 waves). Changes:
//  - src stream staged as uchar payload (8KB) + ushort bucket (16KB), not int;
//  - cur/adj merged into ONE array per stream (thread t owns bucket t; st/ex
//    kept in registers, adj overwrites cur after staging; +2 barriers).
// Total 77.9KB < 80KB -> 2 blocks/CU (32 waves), doubling latency hiding for
// the stage loop's serialized LDS ops and the flush writes.
// Everything else identical to r17: streaming value-staged scatter (zero
// scattered global reads), shfl scans, single-read k_fine, int4 hist, lean
// bf16 gathers (agg1 pinned at 57us L3 line-service floor), register-W2
// gemm2b, zero global atomics. Transform-first identity:
// segsum(h[src]) @ W == segsum((h@W)[src]).

#define NN 100000
#define NE 3200000
#define NOUTF 30
#define TPB 256
#define TPBW 1024                          // hist blocks
#define TPBS 1024                          // scatter blocks

// dst stream buckets
#define DSH 7
#define DCB 128
#define DNB ((NN + DCB - 1) / DCB)         // 782
// src stream buckets
#define SSH 8
#define SCB 256
#define SNB ((NN + SCB - 1) / SCB)         // 391

#define CHUNK 8192
#define NBLK ((NE + CHUNK - 1) / CHUNK)    // 391
#define HLD (DNB * NBLK)                   // 305,762
#define HLS (SNB * NBLK)                   // 152,881
#define HLT (HLD + HLS)                    // 458,643

#define GCH 1024
#define NSC ((HLT + GCH - 1) / GCH)        // 448

#define POOL 4608                          // fine-sort staging (18KB LDS)

__device__ __forceinline__ unsigned short f2bf(float f) {  // round-nearest-even
  unsigned u = __float_as_uint(f);
  u = (u + 0x7FFFu + ((u >> 16) & 1u)) >> 16;
  return (unsigned short)u;
}

// accumulate 8 bf16 (one uint4) into 8 f32
__device__ __forceinline__ void acc8(float* a, const uint4& u) {
  a[0] += __uint_as_float(u.x << 16);
  a[1] += __uint_as_float(u.x & 0xFFFF0000u);
  a[2] += __uint_as_float(u.y << 16);
  a[3] += __uint_as_float(u.y & 0xFFFF0000u);
  a[4] += __uint_as_float(u.z << 16);
  a[5] += __uint_as_float(u.z & 0xFFFF0000u);
  a[6] += __uint_as_float(u.w << 16);
  a[7] += __uint_as_float(u.w & 0xFFFF0000u);
}

// bijective XCD swizzle (m204 variant): consecutive swizzled ids -> same XCD
__device__ __forceinline__ int xcd_swz(int orig, int n) {
  int q = n / 8, r = n % 8;
  int xcd = orig % 8, idx = orig / 8;
  return (xcd < r ? xcd * (q + 1) : r * (q + 1) + (xcd - r) * q) + idx;
}

// block-wide exclusive scan via wave shfl + cross-wave LDS (3 barriers)
template <int NT>
__device__ __forceinline__ int blk_exscan(int val, int* wsums, int t) {
  __syncthreads();                         // protect wsums reuse across calls
  int lane = t & 63;
  int inc = val;
#pragma unroll
  for (int off = 1; off < 64; off <<= 1) {
    int n = __shfl_up(inc, off);
    if (lane >= off) inc += n;
  }
  if (lane == 63) wsums[t >> 6] = inc;
  __syncthreads();
  constexpr int NW = NT / 64;
  if (t < NW) {
    int v = wsums[t];
    int acc = v;
#pragma unroll
    for (int off = 1; off < NW; off <<= 1) {
      int n = __shfl_up(acc, off);
      if (t >= off) acc += n;
    }
    wsums[t] = acc - v;                    // exclusive wave base
  }
  __syncthreads();
  return wsums[t >> 6] + inc - val;
}

// ------ A: dual coarse histogram (dst>>7 and src>>8), int4 loads ------------
__global__ __launch_bounds__(TPBW) void k_hist(const int* __restrict__ src,
                                               const int* __restrict__ dst,
                                               int* __restrict__ H) {
  __shared__ int hd[DNB], hs[SNB];
  int t = threadIdx.x, k = blockIdx.x;
  for (int b = t; b < DNB; b += TPBW) hd[b] = 0;
  for (int b = t; b < SNB; b += TPBW) hs[b] = 0;
  __syncthreads();
  int beg = k * CHUNK, end = min(NE, beg + CHUNK);
  int cnt = end - beg;
  int ebase = t * 8;
  if (ebase + 8 <= cnt) {
    const int4* s4 = (const int4*)(src + beg + ebase);
    const int4* d4 = (const int4*)(dst + beg + ebase);
    int4 a0 = s4[0], a1 = s4[1], b0 = d4[0], b1 = d4[1];
    int sv[8] = {a0.x, a0.y, a0.z, a0.w, a1.x, a1.y, a1.z, a1.w};
    int dv[8] = {b0.x, b0.y, b0.z, b0.w, b1.x, b1.y, b1.z, b1.w};
#pragma unroll
    for (int j = 0; j < 8; ++j) {
      atomicAdd(&hd[dv[j] >> DSH], 1);
      atomicAdd(&hs[sv[j] >> SSH], 1);
    }
  } else {
    for (int j = 0; j < 8 && ebase + j < cnt; ++j) {
      int i = beg + ebase + j;
      atomicAdd(&hd[dst[i] >> DSH], 1);
      atomicAdd(&hs[src[i] >> SSH], 1);
    }
  }
  __syncthreads();
  for (int b = t; b < DNB; b += TPBW) H[b * NBLK + k] = hd[b];
  for (int b = t; b < SNB; b += TPBW) H[HLD + b * NBLK + k] = hs[b];
}

// ------ B: scan. g_scan1 reduces per 1024-chunk; g_scan3 scans in-place. ----
__global__ __launch_bounds__(TPB) void g_scan1(const int* __restrict__ a,
                                               int* __restrict__ bsums) {
  int t = threadIdx.x;
  int base = blockIdx.x * GCH + t * 4;
  int s = 0;
#pragma unroll
  for (int j = 0; j < 4; ++j) { int idx = base + j; if (idx < HLT) s += a[idx]; }
#pragma unroll
  for (int off = 32; off >= 1; off >>= 1) s += __shfl_xor(s, off);
  __shared__ int red[4];
  if ((t & 63) == 0) red[t >> 6] = s;
  __syncthreads();
  if (t == 0) bsums[blockIdx.x] = red[0] + red[1] + red[2] + red[3];
}

__global__ __launch_bounds__(TPB) void g_scan3(int* __restrict__ a,
                                               const int* __restrict__ bsums) {
  __shared__ int sc[512];
  __shared__ int wsums[4];
  int t = threadIdx.x;
  // local scan of RAW bsums -> this block's exclusive prefix
  int i0 = 2 * t, i1 = 2 * t + 1;
  int v0 = (i0 < NSC) ? bsums[i0] : 0;
  int v1 = (i1 < NSC) ? bsums[i1] : 0;
  int ex2 = blk_exscan<TPB>(v0 + v1, wsums, t);
  sc[i0] = ex2;
  sc[i1] = ex2 + v0;
  __syncthreads();
  int pref = sc[blockIdx.x];
  int base = blockIdx.x * GCH + t * 4;
  int v[4]; int s = 0;
#pragma unroll
  for (int j = 0; j < 4; ++j) {
    int idx = base + j;
    v[j] = (idx < HLT) ? a[idx] : 0;
    s += v[j];
  }
  int ex = blk_exscan<TPB>(s, wsums, t);
  int run = pref + ex;
#pragma unroll
  for (int j = 0; j < 4; ++j) {
    int idx = base + j;
    if (idx < HLT) a[idx] = run;  // in-place exclusive
    run += v[j];
  }
}

// ------ C: value-staged dual scatter, 77.9KB LDS -> 2 blocks/CU -------------
__global__ __launch_bounds__(TPBS) void k_scatter(const int* __restrict__ src,
                                                  const int* __restrict__ dst,
                                                  const int* __restrict__ Hsc,
                                                  int* __restrict__ packed,
                                                  unsigned char* __restrict__ ss) {
  __shared__ int pay_lds[CHUNK];                 // 32KB: (s<<DSH)|(d&127), dst order
  __shared__ unsigned short bkt_lds[CHUNK];      // 16KB: dst bucket per slot
  __shared__ unsigned char spay_lds[CHUNK];      //  8KB: s&255, src order
  __shared__ unsigned short sbkt_lds[CHUNK];     // 16KB: src bucket per slot
  __shared__ int cadD[DNB];                      // 3.1KB: cursor, then adj
  __shared__ int cadS[SNB];                      // 1.6KB: cursor, then adj
  __shared__ int wsums[16];
  int t = threadIdx.x;
  int k = xcd_swz((int)blockIdx.x, NBLK);        // adjacent chunks -> same XCD
  int beg = k * CHUNK, end = min(NE, beg + CHUNK);
  int cnt = end - beg;

  // per-(bucket,chunk) counts from Hsc linear diffs; local bases via shfl scan
  int stD = 0, cD = 0;
  if (t < DNB) {
    int idx = t * NBLK + k;
    stD = Hsc[idx];
    int en = (idx + 1 < HLT) ? Hsc[idx + 1] : 2 * NE;
    cD = en - stD;
  }
  int exD = blk_exscan<TPBS>(cD, wsums, t);
  if (t < DNB) cadD[t] = exD;                    // cursor phase
  int stS = 0, cS = 0;
  if (t < SNB) {
    int idx = HLD + t * NBLK + k;
    stS = Hsc[idx];
    int en = (idx + 1 < HLT) ? Hsc[idx + 1] : 2 * NE;
    cS = en - stS;
  }
  int exS = blk_exscan<TPBS>(cS, wsums, t);
  if (t < SNB) cadS[t] = exS;                    // cursor phase
  __syncthreads();

  // stage: 8 contiguous edges/thread (int4 loads), values into LDS
  int ebase = t * 8;
  if (ebase < cnt) {
    int sv[8], dv[8];
    int nv;
    if (ebase + 8 <= cnt) {
      const int4* s4 = (const int4*)(src + beg + ebase);
      const int4* d4 = (const int4*)(dst + beg + ebase);
      int4 a0 = s4[0], a1 = s4[1], b0 = d4[0], b1 = d4[1];
      sv[0] = a0.x; sv[1] = a0.y; sv[2] = a0.z; sv[3] = a0.w;
      sv[4] = a1.x; sv[5] = a1.y; sv[6] = a1.z; sv[7] = a1.w;
      dv[0] = b0.x; dv[1] = b0.y; dv[2] = b0.z; dv[3] = b0.w;
      dv[4] = b1.x; dv[5] = b1.y; dv[6] = b1.z; dv[7] = b1.w;
      nv = 8;
    } else {
      nv = cnt - ebase;
      for (int j = 0; j < nv; ++j) { sv[j] = src[beg + ebase + j]; dv[j] = dst[beg + ebase + j]; }
    }
    for (int j = 0; j < nv; ++j) {
      int bk = dv[j] >> DSH;
      int p = atomicAdd(&cadD[bk], 1);
      pay_lds[p] = (sv[j] << DSH) | (dv[j] & (DCB - 1));
      bkt_lds[p] = (unsigned short)bk;
      int sb = sv[j] >> SSH;
      int q = atomicAdd(&cadS[sb], 1);
      spay_lds[q] = (unsigned char)(sv[j] & (SCB - 1));
      sbkt_lds[q] = (unsigned short)sb;
    }
  }
  __syncthreads();
  // cursor arrays become adj arrays (st/ex held in registers of owner thread)
  if (t < DNB) cadD[t] = stD - exD;
  if (t < SNB) cadS[t] = (stS - NE) - exS;
  __syncthreads();

  // flush: pure LDS reads + coalesced bucket-run global writes
  for (int i = t; i < cnt; i += TPBS)
    packed[cadD[bkt_lds[i]] + i] = pay_lds[i];
  for (int i = t; i < cnt; i += TPBS)
    ss[cadS[sbkt_lds[i]] + i] = spay_lds[i];
}

// ------ D+E fused: fine counting sort (dst, single packed read) | fine count
__global__ __launch_bounds__(TPB) void k_fine(const int* __restrict__ Hsc,
                                              const int* __restrict__ packed,
                                              const unsigned char* __restrict__ ss,
                                              int* __restrict__ src_sorted,
                                              int* __restrict__ row_ptr,
                                              float* __restrict__ norm_in,
                                              float* __restrict__ norm_out) {
  __shared__ int hist[DCB], scn[DCB], cur[DCB];
  __shared__ int pool[POOL];
  __shared__ int histS[SCB];
  int t = threadIdx.x;
  if (blockIdx.x < DNB) {
    int b = blockIdx.x;
    int seg_beg = Hsc[b * NBLK];
    int seg_end = (b + 1 < DNB) ? Hsc[(b + 1) * NBLK] : NE;
    int cnt = seg_end - seg_beg;
    int lim = min(cnt, POOL);
    if (t < DCB) hist[t] = 0;
    __syncthreads();
    for (int i = t; i < lim; i += TPB) {         // stage + hist in one pass
      int v = packed[seg_beg + i];
      pool[i] = v;
      atomicAdd(&hist[v & (DCB - 1)], 1);
    }
    for (int i = lim + t; i < cnt; i += TPB)     // overflow (rare)
      atomicAdd(&hist[packed[seg_beg + i] & (DCB - 1)], 1);
    __syncthreads();
    if (t < DCB) scn[t] = hist[t];
    __syncthreads();
    for (int off = 1; off < DCB; off <<= 1) {    // Hillis-Steele, 128 bins
      int add = (t >= off && t < DCB) ? scn[t - off] : 0;
      __syncthreads();
      if (t < DCB) scn[t] += add;
      __syncthreads();
    }
    if (t < DCB) {
      int excl = scn[t] - hist[t];
      cur[t] = excl;
      int node = b * DCB + t;
      if (node < NN) {
        row_ptr[node] = seg_beg + excl;
        norm_in[node] = (hist[t] > 0) ? rsqrtf((float)hist[t]) : 0.0f;
      }
    }
    if (b == DNB - 1 && t == 0) row_ptr[NN] = NE;
    __syncthreads();
    for (int i = t; i < lim; i += TPB) {         // permute from LDS
      int v = pool[i];
      int p = atomicAdd(&cur[v & (DCB - 1)], 1);
      src_sorted[seg_beg + p] = v >> DSH;        // dense 16KB window
    }
    for (int i = lim + t; i < cnt; i += TPB) {   // overflow from global
      int v = packed[seg_beg + i];
      int p = atomicAdd(&cur[v & (DCB - 1)], 1);
      src_sorted[seg_beg + p] = v >> DSH;
    }
  } else {
    int b = blockIdx.x - DNB;                    // src fine count
    int seg_beg = Hsc[HLD + b * NBLK] - NE;
    int seg_end = (b + 1 < SNB) ? Hsc[HLD + (b + 1) * NBLK] - NE : NE;
    if (t < SCB) histS[t] = 0;
    __syncthreads();
    for (int i = seg_beg + t; i < seg_end; i += TPB)
      atomicAdd(&histS[ss[i]], 1);
    __syncthreads();
    if (t < SCB) {
      int node = b * SCB + t;
      if (node < NN)
        norm_out[node] = (histS[t] > 0) ? rsqrtf((float)histS[t]) : 0.0f;
    }
  }
}

// ------ GEMM1: xt_b[n] = bf16( norm_out[n] * (x[n] @ W1) )  [64 -> 64] ------
__global__ __launch_bounds__(TPB) void k_gemm1(const float4* __restrict__ x4,
                                               const float* __restrict__ W1,
                                               const float* __restrict__ norm_out,
                                               unsigned short* __restrict__ xt_b) {
  int lane = threadIdx.x & 63;
  int wid = (blockIdx.x * TPB + threadIdx.x) >> 6;
  int nwaves = gridDim.x * (TPB / 64);
  float w[64];
#pragma unroll
  for (int k = 0; k < 64; ++k) w[k] = W1[k * 64 + lane];
  int m = lane >> 4, q = lane & 15;
  for (int grp = wid; grp < NN / 4; grp += nwaves) {
    int nbase = grp * 4;
    float4 rv = x4[(nbase + m) * 16 + q];
    int r0 = __float_as_int(rv.x), r1 = __float_as_int(rv.y);
    int r2 = __float_as_int(rv.z), r3 = __float_as_int(rv.w);
    float acc[4] = {0.f, 0.f, 0.f, 0.f};
#pragma unroll
    for (int mm = 0; mm < 4; ++mm) {
#pragma unroll
      for (int ql = 0; ql < 16; ++ql) {
        int sl = mm * 16 + ql;
        acc[mm] = fmaf(__int_as_float(__builtin_amdgcn_readlane(r0, sl)), w[ql * 4 + 0], acc[mm]);
        acc[mm] = fmaf(__int_as_float(__builtin_amdgcn_readlane(r1, sl)), w[ql * 4 + 1], acc[mm]);
        acc[mm] = fmaf(__int_as_float(__builtin_amdgcn_readlane(r2, sl)), w[ql * 4 + 2], acc[mm]);
        acc[mm] = fmaf(__int_as_float(__builtin_amdgcn_readlane(r3, sl)), w[ql * 4 + 3], acc[mm]);
      }
    }
#pragma unroll
    for (int mm = 0; mm < 4; ++mm) {
      int n = nbase + mm;
      xt_b[n * 64 + lane] = f2bf(norm_out[n] * acc[mm]);  // 128B/row coalesced
    }
  }
}

// -- AGG1 (r7 lean, bf16 out): h1_b[n] = bf16(relu(norm_in*segsum(xt_b[src])+b1))
__global__ __launch_bounds__(TPB) void k_agg1(const uint4* __restrict__ xt4,
                                              const int* __restrict__ src_sorted,
                                              const int* __restrict__ row_ptr,
                                              const float* __restrict__ norm_in,
                                              const float* __restrict__ b1,
                                              uint4* __restrict__ h1_b4) {
  int node = (blockIdx.x * TPB + threadIdx.x) >> 6;
  int lane = threadIdx.x & 63;
  int slot = lane >> 3;  // 0..7 edge slots
  int fl = lane & 7;     // uint4 index within 128B row
  int beg = row_ptr[node];
  int end = row_ptr[node + 1];
  float a[8] = {0.f, 0.f, 0.f, 0.f, 0.f, 0.f, 0.f, 0.f};
  int e = beg + slot;
  for (; e + 8 < end; e += 16) {               // lean 2-deep (r7-proven)
    int s0 = src_sorted[e];
    int s1 = src_sorted[e + 8];
    uint4 u0 = xt4[s0 * 8 + fl];
    uint4 u1 = xt4[s1 * 8 + fl];
    acc8(a, u0);
    acc8(a, u1);
  }
  if (e < end) {
    uint4 u0 = xt4[src_sorted[e] * 8 + fl];
    acc8(a, u0);
  }
#pragma unroll
  for (int off = 8; off <= 32; off <<= 1) {
#pragma unroll
    for (int j = 0; j < 8; ++j) a[j] += __shfl_xor(a[j], off);
  }
  if (slot == 0) {
    float ni = norm_in[node];
    const float4* b1_4 = reinterpret_cast<const float4*>(b1);
    float4 bl = b1_4[fl * 2];
    float4 bh = b1_4[fl * 2 + 1];
    float v0 = fmaxf(fmaf(a[0], ni, bl.x), 0.f);
    float v1 = fmaxf(fmaf(a[1], ni, bl.y), 0.f);
    float v2 = fmaxf(fmaf(a[2], ni, bl.z), 0.f);
    float v3 = fmaxf(fmaf(a[3], ni, bl.w), 0.f);
    float v4 = fmaxf(fmaf(a[4], ni, bh.x), 0.f);
    float v5 = fmaxf(fmaf(a[5], ni, bh.y), 0.f);
    float v6 = fmaxf(fmaf(a[6], ni, bh.z), 0.f);
    float v7 = fmaxf(fmaf(a[7], ni, bh.w), 0.f);
    uint4 o;
    o.x = (unsigned)f2bf(v0) | ((unsigned)f2bf(v1) << 16);
    o.y = (unsigned)f2bf(v2) | ((unsigned)f2bf(v3) << 16);
    o.z = (unsigned)f2bf(v4) | ((unsigned)f2bf(v5) << 16);
    o.w = (unsigned)f2bf(v6) | ((unsigned)f2bf(v7) << 16);
    h1_b4[node * 8 + fl] = o;                  // 128B/node coalesced
  }
}

// -- GEMM2b: h1t_b[n][0:32] = bf16(norm_out[n]*(h1_b[n] @ W2)); bf16 in -----
__global__ __launch_bounds__(TPB) void k_gemm2b(const uint4* __restrict__ h1b4,
                                                const float* __restrict__ W2,
                                                const float* __restrict__ norm_out,
                                                unsigned short* __restrict__ h1t_b) {
  int lane = threadIdx.x & 63;
  int wid = (blockIdx.x * TPB + threadIdx.x) >> 6;
  int nwaves = gridDim.x * (TPB / 64);
  int oc = lane & 31;
  float w[64];
#pragma unroll
  for (int k = 0; k < 64; ++k)
    w[k] = (oc < NOUTF) ? W2[k * NOUTF + oc] : 0.f;
  int r = lane >> 3, q = lane & 7;
  for (int grp = wid; grp < NN / 8; grp += nwaves) {
    int nbase = grp * 8;
    uint4 rv = h1b4[(nbase + r) * 8 + q];      // 1KB: 8 rows of 128B
    int v0 = (int)rv.x, v1 = (int)rv.y, v2 = (int)rv.z, v3 = (int)rv.w;
#pragma unroll
    for (int rr = 0; rr < 8; ++rr) {
      float acc0 = 0.f, acc1 = 0.f;
#pragma unroll
      for (int qq = 0; qq < 8; ++qq) {
        int sl = rr * 8 + qq;
        unsigned u0 = (unsigned)__builtin_amdgcn_readlane(v0, sl);
        unsigned u1 = (unsigned)__builtin_amdgcn_readlane(v1, sl);
        unsigned u2 = (unsigned)__builtin_amdgcn_readlane(v2, sl);
        unsigned u3 = (unsigned)__builtin_amdgcn_readlane(v3, sl);
        acc0 = fmaf(__uint_as_float(u0 << 16),          w[qq * 8 + 0], acc0);
        acc1 = fmaf(__uint_as_float(u0 & 0xFFFF0000u), w[qq * 8 + 1], acc1);
        acc0 = fmaf(__uint_as_float(u1 << 16),          w[qq * 8 + 2], acc0);
        acc1 = fmaf(__uint_as_float(u1 & 0xFFFF0000u), w[qq * 8 + 3], acc1);
        acc0 = fmaf(__uint_as_float(u2 << 16),          w[qq * 8 + 4], acc0);
        acc1 = fmaf(__uint_as_float(u2 & 0xFFFF0000u), w[qq * 8 + 5], acc1);
        acc0 = fmaf(__uint_as_float(u3 << 16),          w[qq * 8 + 6], acc0);
        acc1 = fmaf(__uint_as_float(u3 & 0xFFFF0000u), w[qq * 8 + 7], acc1);
      }
      int n = nbase + rr;
      if (lane < 32) {
        float acc = acc0 + acc1;
        unsigned short hv = (oc < NOUTF) ? f2bf(norm_out[n] * acc) : (unsigned short)0;
        h1t_b[n * 32 + oc] = hv;               // 64B/node coalesced
      }
    }
  }
}

// -- AGG2: out[n] = norm_in[n]*segsum(h1t_b[src]) + b2; bf16 in, f32 out -----
__global__ __launch_bounds__(TPB) void k_agg2(const uint4* __restrict__ h1t4,
                                              const int* __restrict__ src_sorted,
                                              const int* __restrict__ row_ptr,
                                              const float* __restrict__ norm_in,
                                              const float* __restrict__ b2,
                                              float* __restrict__ out) {
  int node = (blockIdx.x * TPB + threadIdx.x) >> 6;
  int lane = threadIdx.x & 63;
  int slot = lane >> 2;  // 0..15
  int fl = lane & 3;     // uint4 index within 64B row
  int beg = row_ptr[node];
  int end = row_ptr[node + 1];
  float a[8] = {0.f, 0.f, 0.f, 0.f, 0.f, 0.f, 0.f, 0.f};
  int e = beg + slot;
  for (; e + 16 < end; e += 32) {
    int s0 = src_sorted[e];
    int s1 = src_sorted[e + 16];
    uint4 u0 = h1t4[s0 * 4 + fl];
    uint4 u1 = h1t4[s1 * 4 + fl];
    acc8(a, u0);
    acc8(a, u1);
  }
  if (e < end) {
    uint4 u0 = h1t4[src_sorted[e] * 4 + fl];
    acc8(a, u0);
  }
#pragma unroll
  for (int off = 4; off <= 32; off <<= 1) {
#pragma unroll
    for (int j = 0; j < 8; ++j) a[j] += __shfl_xor(a[j], off);
  }
  if (slot == 0) {
    float ni = norm_in[node];
    int f0 = fl * 8;
    float2* ob = (float2*)(out + (size_t)node * NOUTF);  // rows 120B, 8B-aligned
#pragma unroll
    for (int p = 0; p < 4; ++p) {
      int f = f0 + p * 2;
      if (f < NOUTF) {
        float2 v;
        v.x = fmaf(a[p * 2], ni, b2[f]);
        v.y = fmaf(a[p * 2 + 1], ni, b2[f + 1]);
        ob[f >> 1] = v;
      }
    }
  }
}

extern "C" void kernel_launch(void* const* d_in, const int* in_sizes, int n_in,
                              void* d_out, int out_size, void* d_ws, size_t ws_size,
                              hipStream_t stream) {
  (void)in_sizes; (void)n_in; (void)out_size; (void)ws_size;
  const float* x = (const float*)d_in[0];
  const int* src = (const int*)d_in[1];
  const int* dst = (const int*)d_in[2];
  const float* W1 = (const float*)d_in[3];
  const float* b1 = (const float*)d_in[4];
  const float* W2 = (const float*)d_in[5];
  const float* b2 = (const float*)d_in[6];
  float* out = (float*)d_out;

  // Workspace layout (bytes); offsets 16B-aligned (identical to r17).
  // packed (12.8MB) dead after k_fine -> h1_b (12.8MB bf16) aliases it.
  // xt_b (12.8MB) dead after k_agg1 -> h1t_b (6.4MB bf16) aliases its base.
  char* ws = (char*)d_ws;
  int* row_ptr = (int*)(ws + 0);                           //    400,128
  float* norm_out = (float*)(ws + 400128);                 //    400,000
  float* norm_in = (float*)(ws + 800128);                  //    400,000
  int* H = (int*)(ws + 1200128);                           //  1,834,572 used
  int* bsums = (int*)(ws + 3100128);                       //      1,792 (NSC ints)
  unsigned char* ss = (unsigned char*)(ws + 3101952);      //  3,200,000
  int* src_sorted = (int*)(ws + 8365696);                  // 12,800,000
  int* packed = (int*)(ws + 21165696);                     // 12,800,000
  uint4* h1_b4 = (uint4*)(ws + 21165696);                  // 12,800,000 (aliases packed)
  unsigned short* xt_b = (unsigned short*)(ws + 46765696); // 12,800,000
  unsigned short* h1t_b = (unsigned short*)(ws + 46765696);// 6,400,000 (aliases xt_b)

  k_hist<<<NBLK, TPBW, 0, stream>>>(src, dst, H);
  g_scan1<<<NSC, TPB, 0, stream>>>(H, bsums);
  g_scan3<<<NSC, TPB, 0, stream>>>(H, bsums);
  k_scatter<<<NBLK, TPBS, 0, stream>>>(src, dst, H, packed, ss);
  k_fine<<<DNB + SNB, TPB, 0, stream>>>(H, packed, ss, src_sorted, row_ptr, norm_in, norm_out);
  k_gemm1<<<1024, TPB, 0, stream>>>((const float4*)x, W1, norm_out, xt_b);
  k_agg1<<<NN / 4, TPB, 0, stream>>>((const uint4*)xt_b, src_sorted, row_ptr,
                                     norm_in, b1, h1_b4);
  k_gemm2b<<<1024, TPB, 0, stream>>>((const uint4*)h1_b4, W2, norm_out, h1t_b);
  k_agg2<<<NN / 4, TPB, 0, stream>>>((const uint4*)h1t_b, src_sorted, row_ptr, norm_in, b2, out);
}